// Round 10
// baseline (6065.605 us; speedup 1.0000x reference)
//
#include <hip/hip_runtime.h>
#include <cstdint>
#include <cstddef>

#define NN 50000
#define EE 1600000
#define GG 512
#define FIN 1273
#define NB 13        // source buckets: 4096 nodes x 512 B = 2 MB (< 4 MB XCD L2)
#define NBP1 14
#define BSHIFT 12

typedef unsigned short u16;
typedef unsigned int u32;
typedef __attribute__((ext_vector_type(8))) short short8;
typedef __attribute__((ext_vector_type(4))) float f32x4;

__device__ __forceinline__ float sigmf(float x) { return 1.f / (1.f + expf(-x)); }

// truncation split: v == hi + rem exactly; lo = bf16(rem); |v-(hi+lo)| <= 2^-16 |v|
__device__ __forceinline__ void splitbf(float v, u16& hi, u16& lo) {
    const u32 u = __float_as_uint(v);
    hi = (u16)(u >> 16);
    const float rem = v - __uint_as_float(u & 0xffff0000u);
    lo = (u16)(__float_as_uint(rem) >> 16);
}

__device__ __forceinline__ void gload_lds16(const void* g, void* l) {
    __builtin_amdgcn_global_load_lds(
        (const __attribute__((address_space(1))) void*)g,
        (__attribute__((address_space(3))) void*)l, 16, 0, 0);
}

// XCD-aware triplet remap: put the 3 mats of one row tile on the same XCD.
__device__ __forceinline__ bool remap3(int f, int nRow, int& mat, int& rt) {
    const int g = f / 24, w = f - g * 24;
    rt = g * 8 + (w & 7);
    mat = w >> 3;
    return rt < nRow;
}

// ===== layer-0 GEMM: split-bf16 MFMA, A = fp32 x staged via LDS ================
__global__ __launch_bounds__(256) void gemm_l0(
    const float* __restrict__ A, int lda, int K, int Kreal,
    const u16* __restrict__ Bhi, const u16* __restrict__ Blo, size_t strideB,
    float* __restrict__ C, int ldc, int coffStep, int M, int nRow)
{
    __shared__ u16 lsAhi[128 * 64];
    __shared__ u16 lsAlo[128 * 64];
    __shared__ u16 lsBhi[128 * 64];
    __shared__ u16 lsBlo[128 * 64];
    int mat, rt;
    if (!remap3(blockIdx.x, nRow, mat, rt)) return;
    const int tid = threadIdx.x;
    const int wave = tid >> 6, lane = tid & 63;
    const int row0 = rt * 128;
    const int coff = mat * coffStep;
    const u16* Bh = Bhi + (size_t)mat * strideB;
    const u16* Bl = Blo + (size_t)mat * strideB;
    const int wm = wave >> 1, wn = wave & 1;
    f32x4 acc[4][4] = {};

    for (int k0 = 0; k0 < K; k0 += 64) {
        if (k0) __syncthreads();
        #pragma unroll
        for (int i = 0; i < 4; ++i) {
            const int slot = i * 256 + tid;
            const int r = slot >> 3, ch = tid & 7;
            int gr = row0 + r; if (gr >= M) gr = M - 1;
            const int kb = k0 + ch * 8;
            u16 th[8], tl[8];
            const float* src = A + (size_t)gr * lda + kb;
            if (kb + 8 <= Kreal) {
                const float4 v0 = *(const float4*)(src);
                const float4 v1 = *(const float4*)(src + 4);
                const float va[8] = {v0.x, v0.y, v0.z, v0.w,
                                     v1.x, v1.y, v1.z, v1.w};
                #pragma unroll
                for (int e = 0; e < 8; ++e) splitbf(va[e], th[e], tl[e]);
            } else {
                #pragma unroll
                for (int e = 0; e < 8; ++e) {
                    const float v = (kb + e < Kreal) ? src[e] : 0.f;
                    splitbf(v, th[e], tl[e]);
                }
            }
            const int off = (r << 6) + ((ch ^ (r & 7)) << 3);
            *(short8*)&lsAhi[off] = *(const short8*)th;
            *(short8*)&lsAlo[off] = *(const short8*)tl;
        }
        #pragma unroll
        for (int i = 0; i < 4; ++i) {
            const int slot = i * 256 + wave * 64 + lane;
            const int r = slot >> 3, ch = slot & 7;
            const int sch = ch ^ (r & 7);
            const size_t goff = (size_t)r * K + k0 + sch * 8;
            const int lbase = (i * 256 + wave * 64) * 8;
            gload_lds16(Bh + goff, &lsBhi[lbase]);
            gload_lds16(Bl + goff, &lsBlo[lbase]);
        }
        __syncthreads();
        #pragma unroll
        for (int ks = 0; ks < 2; ++ks) {
            short8 ah[4], al[4], bh[4], bl[4];
            const int kch = ks * 4 + (lane >> 4);
            #pragma unroll
            for (int m = 0; m < 4; ++m) {
                const int r = wm * 64 + m * 16 + (lane & 15);
                const int off = (r << 6) + ((kch ^ (r & 7)) << 3);
                ah[m] = *(const short8*)&lsAhi[off];
                al[m] = *(const short8*)&lsAlo[off];
            }
            #pragma unroll
            for (int n = 0; n < 4; ++n) {
                const int c = wn * 64 + n * 16 + (lane & 15);
                const int off = (c << 6) + ((kch ^ (c & 7)) << 3);
                bh[n] = *(const short8*)&lsBhi[off];
                bl[n] = *(const short8*)&lsBlo[off];
            }
            #pragma unroll
            for (int m = 0; m < 4; ++m)
                #pragma unroll
                for (int n = 0; n < 4; ++n) {
                    acc[m][n] = __builtin_amdgcn_mfma_f32_16x16x32_bf16(
                        ah[m], bh[n], acc[m][n], 0, 0, 0);
                    acc[m][n] = __builtin_amdgcn_mfma_f32_16x16x32_bf16(
                        ah[m], bl[n], acc[m][n], 0, 0, 0);
                    acc[m][n] = __builtin_amdgcn_mfma_f32_16x16x32_bf16(
                        al[m], bh[n], acc[m][n], 0, 0, 0);
                }
        }
    }
    #pragma unroll
    for (int n = 0; n < 4; ++n) {
        const int c = wn * 64 + n * 16 + (lane & 15);
        #pragma unroll
        for (int m = 0; m < 4; ++m) {
            #pragma unroll
            for (int j = 0; j < 4; ++j) {
                const int gr = row0 + wm * 64 + m * 16 + ((lane >> 4) << 2) + j;
                if (gr < M)
                    C[(size_t)gr * ldc + coff + c] = acc[m][n][j];
            }
        }
    }
}

// ===== direct-A GEMM: A fp32 from global (no A LDS) ============================
template <int ABN>
__global__ __launch_bounds__(256) void gemm_dir(
    const float* __restrict__ A, size_t strideA, int lda, int K,
    const float* __restrict__ st, int stSlice, int stMat,
    const float* __restrict__ ga, const float* __restrict__ be,
    int gbSlice, int gbMat,
    const u16* __restrict__ Bhi, const u16* __restrict__ Blo, size_t strideB,
    const float* __restrict__ bias, int biasMat,
    float* __restrict__ C, int ldc, int coffStep,
    int M, int do_stats, float* __restrict__ stats_out, int ostatMat,
    int nMat, int nRow)
{
    __shared__ u16 lsBhi[128 * 64];
    __shared__ u16 lsBlo[128 * 64];
    int mat, rt;
    if (nMat == 3) {
        if (!remap3(blockIdx.x, nRow, mat, rt)) return;
    } else { mat = 0; rt = blockIdx.x; }
    const int tid = threadIdx.x;
    const int wave = tid >> 6, lane = tid & 63;
    const int row0 = rt * 128;
    const int wm = wave >> 1, wn = wave & 1;
    A += (size_t)mat * strideA;
    if (ABN) { st += mat * stMat; ga += mat * gbMat; be += mat * gbMat; }
    if (bias) bias += mat * biasMat;
    if (do_stats) stats_out += mat * ostatMat;
    const u16* Bh = Bhi + (size_t)mat * strideB;
    const u16* Bl = Blo + (size_t)mat * strideB;
    const int coff = mat * coffStep;
    f32x4 acc[4][4] = {};

    int arow[4];
    #pragma unroll
    for (int m = 0; m < 4; ++m) {
        int r = row0 + wm * 64 + m * 16 + (lane & 15);
        if (r >= M) r = M - 1;
        arow[m] = r;
    }

    for (int k0 = 0; k0 < K; k0 += 64) {
        if (k0) __syncthreads();
        #pragma unroll
        for (int i = 0; i < 4; ++i) {
            const int slot = i * 256 + wave * 64 + lane;
            const int r = slot >> 3, ch = slot & 7;
            const int sch = ch ^ (r & 7);
            const size_t goff = (size_t)r * K + k0 + sch * 8;
            const int lbase = (i * 256 + wave * 64) * 8;
            gload_lds16(Bh + goff, &lsBhi[lbase]);
            gload_lds16(Bl + goff, &lsBlo[lbase]);
        }
        __syncthreads();
        #pragma unroll
        for (int ks = 0; ks < 2; ++ks) {
            const int kch = ks * 4 + (lane >> 4);
            const int kb = k0 + kch * 8;
            float scv[8], shv[8];
            if (ABN) {
                const int s = kb >> 7, d0 = kb & 127;
                const float* stS = st + s * stSlice;
                const float* gS  = ga + s * gbSlice;
                const float* beS = be + s * gbSlice;
                #pragma unroll
                for (int e = 0; e < 8; ++e) {
                    const int d = d0 + e;
                    const float mu = stS[d] * (1.f / NN);
                    const float var = fmaxf(stS[128 + d] * (1.f / NN) - mu * mu, 0.f);
                    const float sc = gS[d] * rsqrtf(var + 1e-5f);
                    scv[e] = sc;
                    shv[e] = beS[d] - sc * mu;
                }
            }
            short8 ah[4], al[4];
            #pragma unroll
            for (int m = 0; m < 4; ++m) {
                const float* src = A + (size_t)arow[m] * lda + kb;
                const float4 v0 = *(const float4*)(src);
                const float4 v1 = *(const float4*)(src + 4);
                const float va[8] = {v0.x, v0.y, v0.z, v0.w,
                                     v1.x, v1.y, v1.z, v1.w};
                u16 th[8], tl[8];
                #pragma unroll
                for (int e = 0; e < 8; ++e) {
                    const float y = ABN
                        ? fmaxf(fmaf(scv[e], va[e], shv[e]), 0.f) : va[e];
                    splitbf(y, th[e], tl[e]);
                }
                ah[m] = *(const short8*)th;
                al[m] = *(const short8*)tl;
            }
            #pragma unroll
            for (int n = 0; n < 4; ++n) {
                const int c = wn * 64 + n * 16 + (lane & 15);
                const int off = (c << 6) + ((kch ^ (c & 7)) << 3);
                const short8 bh = *(const short8*)&lsBhi[off];
                const short8 bl = *(const short8*)&lsBlo[off];
                #pragma unroll
                for (int m = 0; m < 4; ++m) {
                    acc[m][n] = __builtin_amdgcn_mfma_f32_16x16x32_bf16(
                        ah[m], bh, acc[m][n], 0, 0, 0);
                    acc[m][n] = __builtin_amdgcn_mfma_f32_16x16x32_bf16(
                        ah[m], bl, acc[m][n], 0, 0, 0);
                    acc[m][n] = __builtin_amdgcn_mfma_f32_16x16x32_bf16(
                        al[m], bh, acc[m][n], 0, 0, 0);
                }
            }
        }
    }

    float colsum[4] = {0.f, 0.f, 0.f, 0.f}, colsq[4] = {0.f, 0.f, 0.f, 0.f};
    #pragma unroll
    for (int n = 0; n < 4; ++n) {
        const int c = wn * 64 + n * 16 + (lane & 15);
        const float bv = bias ? bias[c] : 0.f;
        #pragma unroll
        for (int m = 0; m < 4; ++m) {
            #pragma unroll
            for (int j = 0; j < 4; ++j) {
                const int gr = row0 + wm * 64 + m * 16 + ((lane >> 4) << 2) + j;
                if (gr < M) {
                    const float v = acc[m][n][j] + bv;
                    C[(size_t)gr * ldc + coff + c] = v;
                    colsum[n] += v; colsq[n] += v * v;
                }
            }
        }
    }
    if (do_stats) {
        float* ssum = (float*)lsBhi;
        float* ssq  = ssum + 128;
        __syncthreads();
        if (tid < 128) { ssum[tid] = 0.f; ssq[tid] = 0.f; }
        __syncthreads();
        #pragma unroll
        for (int n = 0; n < 4; ++n) {
            const int c = wn * 64 + n * 16 + (lane & 15);
            atomicAdd(&ssum[c], colsum[n]);
            atomicAdd(&ssq[c], colsq[n]);
        }
        __syncthreads();
        if (tid < 128) {
            atomicAdd(&stats_out[tid],       ssum[tid]);
            atomicAdd(&stats_out[128 + tid], ssq[tid]);
        }
    }
}

// ------ weight transpose+split: W[nmat][K][128] -> Whi/Wlo[nmat][128][Kpad] ----
__global__ __launch_bounds__(256) void wt_cast2(const float* __restrict__ W,
                                                u16* __restrict__ Whi,
                                                u16* __restrict__ Wlo,
                                                int total, int K, int Kpad) {
    const int idx = blockIdx.x * 256 + threadIdx.x;
    if (idx >= total) return;
    const int perm = 128 * Kpad;
    const int m = idx / perm, rem = idx - m * perm;
    const int n = rem / Kpad, k = rem - n * Kpad;
    const float v = (k < K) ? W[(size_t)m * K * 128 + (size_t)k * 128 + n] : 0.f;
    u16 hi, lo;
    splitbf(v, hi, lo);
    Whi[idx] = hi; Wlo[idx] = lo;
}

// ---------------- fp32 tiled GEMM (LSTM gates only) ----------------------------
template <bool BT>
__global__ __launch_bounds__(256) void gemm_f32(
    const float* __restrict__ A, const float* __restrict__ B,
    const float* __restrict__ bias, float* __restrict__ C,
    int M, int K, int Nc)
{
    __shared__ float As[32][68];
    __shared__ float Bs[32][132];
    const int tid = threadIdx.x;
    const int tx = tid & 15, ty = tid >> 4;
    const int row0 = blockIdx.x * 64, col0 = blockIdx.y * 128;
    float acc[4][8] = {};
    for (int k0 = 0; k0 < K; k0 += 32) {
        {
            const int kk = tid & 31, rb = tid >> 5;
            #pragma unroll
            for (int i = 0; i < 8; ++i) {
                const int r = rb + i * 8, gr = row0 + r, gk = k0 + kk;
                As[kk][r] = (gr < M && gk < K) ? A[(size_t)gr * K + gk] : 0.f;
            }
        }
        if (!BT) {
            const int c = tid & 127, kb = tid >> 7;
            #pragma unroll
            for (int i = 0; i < 16; ++i) {
                const int kk = kb + i * 2, gk = k0 + kk;
                Bs[kk][c] = (gk < K) ? B[(size_t)gk * Nc + col0 + c] : 0.f;
            }
        } else {
            const int kk = tid & 31, cb = tid >> 5;
            #pragma unroll
            for (int i = 0; i < 16; ++i) {
                const int c = cb + i * 8, gk = k0 + kk;
                Bs[kk][c] = (gk < K) ? B[(size_t)(col0 + c) * K + gk] : 0.f;
            }
        }
        __syncthreads();
        #pragma unroll 8
        for (int kk = 0; kk < 32; ++kk) {
            const float4 av  = *(const float4*)&As[kk][ty * 4];
            const float4 bv0 = *(const float4*)&Bs[kk][tx * 8];
            const float4 bv1 = *(const float4*)&Bs[kk][tx * 8 + 4];
            const float a[4] = {av.x, av.y, av.z, av.w};
            const float b[8] = {bv0.x, bv0.y, bv0.z, bv0.w, bv1.x, bv1.y, bv1.z, bv1.w};
            #pragma unroll
            for (int i = 0; i < 4; ++i)
                #pragma unroll
                for (int j = 0; j < 8; ++j)
                    acc[i][j] = fmaf(a[i], b[j], acc[i][j]);
        }
        __syncthreads();
    }
    #pragma unroll
    for (int j = 0; j < 8; ++j) {
        const float bv = bias ? bias[col0 + tx * 8 + j] : 0.f;
        #pragma unroll
        for (int i = 0; i < 4; ++i) acc[i][j] += bv;
    }
    #pragma unroll
    for (int i = 0; i < 4; ++i) {
        const int gr = row0 + ty * 4 + i;
        if (gr < M) {
            *(float4*)&C[(size_t)gr * Nc + col0 + tx * 8] =
                make_float4(acc[i][0], acc[i][1], acc[i][2], acc[i][3]);
            *(float4*)&C[(size_t)gr * Nc + col0 + tx * 8 + 4] =
                make_float4(acc[i][4], acc[i][5], acc[i][6], acc[i][7]);
        }
    }
}

// ---------------- bucketed CSR build (counting sort by dst, src-bucket) --------
__global__ __launch_bounds__(256) void count_both(const int* __restrict__ src,
                                                  const int* __restrict__ dst,
                                                  int* __restrict__ deg,
                                                  int* __restrict__ cnt) {
    const int e = blockIdx.x * 256 + threadIdx.x;
    if (e < EE) {
        const int d = dst[e];
        atomicAdd(&deg[d], 1);
        atomicAdd(&cnt[d * NB + (src[e] >> BSHIFT)], 1);
    }
}

__global__ __launch_bounds__(512) void scan1(const int* __restrict__ deg,
                                             int* __restrict__ scanned,
                                             int* __restrict__ bsum) {
    __shared__ int s[512];
    const int t = threadIdx.x;
    const int i = blockIdx.x * 512 + t;
    const int v = (i < NN) ? deg[i] : 0;
    s[t] = v; __syncthreads();
    for (int o = 1; o < 512; o <<= 1) {
        const int tv = (t >= o) ? s[t - o] : 0;
        __syncthreads();
        s[t] += tv;
        __syncthreads();
    }
    if (i < NN) scanned[i] = s[t];
    if (t == 511) bsum[blockIdx.x] = s[511];
}

__global__ __launch_bounds__(128) void scan2(int* __restrict__ bsum, int nb) {
    __shared__ int s[128];
    const int t = threadIdx.x;
    const int v = (t < nb) ? bsum[t] : 0;
    s[t] = v; __syncthreads();
    for (int o = 1; o < 128; o <<= 1) {
        const int tv = (t >= o) ? s[t - o] : 0;
        __syncthreads();
        s[t] += tv;
        __syncthreads();
    }
    if (t < nb) bsum[t] = s[t] - v;  // exclusive
}

// per-dst base -> bucket offsets boff[dst][0..NB] + cursor init
__global__ __launch_bounds__(256) void mk_boff(const int* __restrict__ deg,
                                               const int* __restrict__ scanned,
                                               const int* __restrict__ bsum,
                                               const int* __restrict__ cnt,
                                               int* __restrict__ boff,
                                               int* __restrict__ cursorB) {
    const int d = blockIdx.x * 256 + threadIdx.x;
    if (d >= NN) return;
    int base = bsum[d >> 9] + scanned[d] - deg[d];   // exclusive row start
    #pragma unroll
    for (int b = 0; b < NB; ++b) {
        boff[(size_t)d * NBP1 + b] = base;
        cursorB[(size_t)d * NB + b] = base;
        base += cnt[(size_t)d * NB + b];
    }
    boff[(size_t)d * NBP1 + NB] = base;
}

__global__ __launch_bounds__(256) void fillB(const int* __restrict__ src,
                                             const int* __restrict__ dst,
                                             int* __restrict__ cursorB,
                                             int* __restrict__ csrc) {
    const int e = blockIdx.x * 256 + threadIdx.x;
    if (e < EE) {
        const int s = src[e];
        const int pos = atomicAdd(&cursorB[(size_t)dst[e] * NB + (s >> BSHIFT)], 1);
        csrc[pos] = s;
    }
}

// ==== fused aggregate + combine, bucket-swept for L2 residency =================
// Edges per dst are sorted by src-bucket; all waves sweep buckets 0..NB-1 in
// near-lockstep so the instantaneous gather working set is ~2 MB (L2-resident).
// L0=1: gather proj slice k of X; z_k = (1+eps)self + agg + b1, column stats.
// L0=0: gather SHARED zm2 applying h = relu(bn(v)) on the fly.
template <int L0>
__global__ __launch_bounds__(256) void agg_combine(
    const float* __restrict__ X, int ldp4,
    const int* __restrict__ boffB, const int* __restrict__ csrcB,
    const float* __restrict__ b1B,
    const float* __restrict__ stF2, const float* __restrict__ gam,
    const float* __restrict__ bet,
    const float* __restrict__ eps_arr, int epsBase,
    float* __restrict__ zB, float* __restrict__ statsB)
{
    __shared__ float red[256];
    const int k = blockIdx.y;
    const int* boff = boffB + (size_t)k * NN * NBP1;
    const int* csrc = csrcB + (size_t)k * EE;
    float* z        = zB + (size_t)k * NN * 128;
    const int tid = threadIdx.x, lane = tid & 63, wave = tid >> 6;
    const float e1 = 1.f + eps_arr[epsBase + k];
    const int half = lane >> 5;
    const int l32 = lane & 31;
    const float4* p4 = (const float4*)X + (L0 ? k * 32 : 0);
    float4 bv = make_float4(0.f, 0.f, 0.f, 0.f);
    float sc[4], sh[4];
    if (L0) {
        if (lane < 32) bv = ((const float4*)(b1B + k * 128))[l32];
    } else {
        #pragma unroll
        for (int c = 0; c < 4; ++c) {
            const int d = l32 * 4 + c;
            const float mu = stF2[d] * (1.f / NN);
            const float var = fmaxf(stF2[128 + d] * (1.f / NN) - mu * mu, 0.f);
            const float s_ = gam[d] * rsqrtf(var + 1e-5f);
            sc[c] = s_;
            sh[c] = bet[d] - s_ * mu;
        }
    }
    auto bnv = [&](float4 v) -> float4 {
        if (L0) return v;
        v.x = fmaxf(fmaf(sc[0], v.x, sh[0]), 0.f);
        v.y = fmaxf(fmaf(sc[1], v.y, sh[1]), 0.f);
        v.z = fmaxf(fmaf(sc[2], v.z, sh[2]), 0.f);
        v.w = fmaxf(fmaf(sc[3], v.w, sh[3]), 0.f);
        return v;
    };
    if (L0) { red[tid] = 0.f; __syncthreads(); }
    const int nbase = blockIdx.x * 16 + wave * 4;

    float ac[4][4] = {};             // persistent accumulators [dst][comp]
    int prevOff[4];
    #pragma unroll
    for (int t = 0; t < 4; ++t)
        prevOff[t] = boff[(size_t)(nbase + t) * NBP1];

    for (int b = 0; b < NB; ++b) {
        #pragma unroll
        for (int t = 0; t < 4; ++t) {
            const int s0 = prevOff[t];
            const int s1 = boff[(size_t)(nbase + t) * NBP1 + b + 1];
            prevOff[t] = s1;
            float ax = 0.f, ay = 0.f, az = 0.f, aw = 0.f;
            int j = s0;
            for (; j + 3 < s1; j += 4) {
                const float4 v0 = bnv(p4[(size_t)csrc[j + half] * ldp4 + l32]);
                const float4 v1 = bnv(p4[(size_t)csrc[j + 2 + half] * ldp4 + l32]);
                ax += v0.x + v1.x; ay += v0.y + v1.y;
                az += v0.z + v1.z; aw += v0.w + v1.w;
            }
            for (; j + 1 < s1; j += 2) {
                const float4 v0 = bnv(p4[(size_t)csrc[j + half] * ldp4 + l32]);
                ax += v0.x; ay += v0.y; az += v0.z; aw += v0.w;
            }
            if (j < s1 && half == 0) {
                const float4 v0 = bnv(p4[(size_t)csrc[j] * ldp4 + l32]);
                ax += v0.x; ay += v0.y; az += v0.z; aw += v0.w;
            }
            ac[t][0] += ax; ac[t][1] += ay; ac[t][2] += az; ac[t][3] += aw;
        }
    }

    float s_[4] = {0.f, 0.f, 0.f, 0.f}, q_[4] = {0.f, 0.f, 0.f, 0.f};
    #pragma unroll
    for (int t = 0; t < 4; ++t) {
        const int wid = nbase + t;
        float ax = ac[t][0], ay = ac[t][1], az = ac[t][2], aw = ac[t][3];
        ax += __shfl_down(ax, 32, 64);
        ay += __shfl_down(ay, 32, 64);
        az += __shfl_down(az, 32, 64);
        aw += __shfl_down(aw, 32, 64);
        if (lane < 32) {
            const float4 self = bnv(p4[(size_t)wid * ldp4 + l32]);
            float4 zv;
            zv.x = fmaf(e1, self.x, ax + bv.x);
            zv.y = fmaf(e1, self.y, ay + bv.y);
            zv.z = fmaf(e1, self.z, az + bv.z);
            zv.w = fmaf(e1, self.w, aw + bv.w);
            ((float4*)z)[(size_t)wid * 32 + l32] = zv;
            if (L0) {
                s_[0] += zv.x; s_[1] += zv.y; s_[2] += zv.z; s_[3] += zv.w;
                q_[0] += zv.x * zv.x; q_[1] += zv.y * zv.y;
                q_[2] += zv.z * zv.z; q_[3] += zv.w * zv.w;
            }
        }
    }
    if (L0) {
        if (lane < 32) {
            const int d = l32 * 4;
            #pragma unroll
            for (int c = 0; c < 4; ++c) {
                atomicAdd(&red[d + c], s_[c]);
                atomicAdd(&red[128 + d + c], q_[c]);
            }
        }
        __syncthreads();
        atomicAdd(&statsB[(size_t)k * 512 + tid], red[tid]);
    }
}

// ------- BN + ReLU -> fp32 (final h only) --------------------------------------
__global__ __launch_bounds__(256) void bn_relu_f32(
    const float* __restrict__ xin, const float* __restrict__ stats,
    const float* __restrict__ gamma, const float* __restrict__ beta,
    float* __restrict__ out)
{
    const size_t i = (size_t)blockIdx.x * 256 + threadIdx.x;  // pair index
    if (i >= (size_t)NN * 64) return;
    const int d = (int)(i & 63) * 2;
    const float inv_n = 1.f / NN;
    const float mu0 = stats[d] * inv_n,     mu1 = stats[d + 1] * inv_n;
    const float v0 = fmaxf(stats[128 + d] * inv_n - mu0 * mu0, 0.f);
    const float v1 = fmaxf(stats[129 + d] * inv_n - mu1 * mu1, 0.f);
    const float s0 = gamma[d] * rsqrtf(v0 + 1e-5f);
    const float s1 = gamma[d + 1] * rsqrtf(v1 + 1e-5f);
    const float2 xv = ((const float2*)xin)[i];
    const float y0 = fmaxf(fmaf(s0, xv.x - mu0, beta[d]), 0.f);
    const float y1 = fmaxf(fmaf(s1, xv.y - mu1, beta[d + 1]), 0.f);
    ((float2*)out)[i] = make_float2(y0, y1);
}

// ---------------- per-graph segment starts (batch is sorted) -------------------
__global__ __launch_bounds__(256) void seg_starts(const int* __restrict__ batch,
                                                  int* __restrict__ gstart) {
    const int i = blockIdx.x * 256 + threadIdx.x;
    if (i >= NN) return;
    const int b = batch[i];
    if (i == 0) { for (int g = 0; g <= b; ++g) gstart[g] = 0; }
    else {
        const int pb = batch[i - 1];
        for (int g = pb + 1; g <= b; ++g) gstart[g] = i;
    }
    if (i == NN - 1) { for (int g = b + 1; g <= GG; ++g) gstart[g] = NN; }
}

// ---------------- Set2Set ------------------------------------------------------
__global__ __launch_bounds__(256) void pack_wcat(const float* __restrict__ Wih,
                                                 const float* __restrict__ Whh,
                                                 float* __restrict__ Wcat) {
    const int i = blockIdx.x * 256 + threadIdx.x;
    if (i >= 512 * 384) return;
    const int j = i / 384, k = i - j * 384;
    Wcat[i] = (k < 256) ? Wih[j * 256 + k] : Whh[j * 128 + (k - 256)];
}

__global__ __launch_bounds__(256) void lstm_kernel(
    const float* __restrict__ gates, const float* __restrict__ bih,
    const float* __restrict__ bhh, float* __restrict__ cc, float* __restrict__ S)
{
    const int i = blockIdx.x * 256 + threadIdx.x;
    if (i >= GG * 128) return;
    const int g = i >> 7, d = i & 127;
    const float* gr = gates + (size_t)g * 512;
    const float ig = gr[d]       + bih[d]       + bhh[d];
    const float fg = gr[128 + d] + bih[128 + d] + bhh[128 + d];
    const float gv = gr[256 + d] + bih[256 + d] + bhh[256 + d];
    const float og = gr[384 + d] + bih[384 + d] + bhh[384 + d];
    const float c  = sigmf(fg) * cc[i] + sigmf(ig) * tanhf(gv);
    const float hv = sigmf(og) * tanhf(c);
    cc[i] = c;
    S[(size_t)g * 384 + d] = hv;
    S[(size_t)g * 384 + 256 + d] = hv;
}

__global__ __launch_bounds__(256) void attend_kernel(
    const float* __restrict__ h, float* __restrict__ S,
    float* __restrict__ ews, const int* __restrict__ gstart)
{
    const int g = blockIdx.x;
    const int rs = gstart[g], re = gstart[g + 1];
    const int tid = threadIdx.x, lane = tid & 63, w = tid >> 6;
    __shared__ float q[128];
    __shared__ float red[8];
    if (tid < 128) q[tid] = S[(size_t)g * 384 + 256 + tid];
    __syncthreads();
    const float2* h2 = (const float2*)h;
    float lmax = -1e30f;
    for (int n = rs + w; n < re; n += 4) {
        const float2 hv = h2[(size_t)n * 64 + lane];
        float p = hv.x * q[2 * lane] + hv.y * q[2 * lane + 1];
        #pragma unroll
        for (int o = 32; o; o >>= 1) p += __shfl_down(p, o, 64);
        if (lane == 0) { ews[n] = p; lmax = fmaxf(lmax, p); }
    }
    if (lane == 0) red[w] = lmax;
    __syncthreads();
    const float m = fmaxf(fmaxf(red[0], red[1]), fmaxf(red[2], red[3]));
    __syncthreads();
    float lsum = 0.f;
    for (int n = rs + tid; n < re; n += 256) {
        const float ex = expf(ews[n] - m);
        ews[n] = ex; lsum += ex;
    }
    #pragma unroll
    for (int o = 32; o; o >>= 1) lsum += __shfl_down(lsum, o, 64);
    if (lane == 0) red[w] = lsum;
    __syncthreads();
    const float denom = red[0] + red[1] + red[2] + red[3];
    if (tid < 128) {
        float acc = 0.f;
        for (int n = rs; n < re; ++n)
            acc = fmaf(ews[n], h[(size_t)n * 128 + tid], acc);
        S[(size_t)g * 384 + 128 + tid] = (denom > 0.f) ? acc / denom : 0.f;
    }
}

__global__ __launch_bounds__(128) void fc1_kernel(const float* __restrict__ S,
                                                  const float* __restrict__ W,
                                                  const float* __restrict__ b,
                                                  float* __restrict__ out1) {
    const int g = blockIdx.x, d = threadIdx.x;
    __shared__ float qs[256];
    qs[d] = S[(size_t)g * 384 + d];
    qs[128 + d] = S[(size_t)g * 384 + 128 + d];
    __syncthreads();
    float acc = b[d];
    for (int k = 0; k < 256; ++k) acc = fmaf(qs[k], W[k * 128 + d], acc);
    out1[(size_t)g * 128 + d] = fmaxf(acc, 0.f);
}

__global__ __launch_bounds__(256) void fc4_kernel(const float* __restrict__ out1,
                                                  const float* __restrict__ W,
                                                  const float* __restrict__ b,
                                                  float* __restrict__ out) {
    const int i = blockIdx.x * 256 + threadIdx.x;
    if (i >= GG * 12) return;
    const int g = i / 12, j = i - g * 12;
    float acc = b[j];
    for (int d = 0; d < 128; ++d)
        acc = fmaf(out1[(size_t)g * 128 + d], W[d * 12 + j], acc);
    out[i] = acc;
}

// ================================================================================
extern "C" void kernel_launch(void* const* d_in, const int* in_sizes, int n_in,
                              void* d_out, int out_size, void* d_ws, size_t ws_size,
                              hipStream_t stream)
{
    const float* x        = (const float*)d_in[0];
    const int*   eidx[3]  = {(const int*)d_in[1], (const int*)d_in[2], (const int*)d_in[3]};
    const int*   batch    = (const int*)d_in[4];
    const float* conv1_W1     = (const float*)d_in[5];
    const float* conv1_b1     = (const float*)d_in[6];
    const float* conv_rest_W1 = (const float*)d_in[7];
    const float* conv_rest_b1 = (const float*)d_in[8];
    const float* conv_W2      = (const float*)d_in[9];
    const float* conv_b2      = (const float*)d_in[10];
    const float* conv_bn1_g   = (const float*)d_in[11];
    const float* conv_bn1_b   = (const float*)d_in[12];
    const float* conv_bn2_g   = (const float*)d_in[13];
    const float* conv_bn2_b   = (const float*)d_in[14];
    const float* conv_eps     = (const float*)d_in[15];
    const float* mlp_W1       = (const float*)d_in[16];
    const float* mlp_b1       = (const float*)d_in[17];
    const float* mlp_bn1_g    = (const float*)d_in[18];
    const float* mlp_bn1_b    = (const float*)d_in[19];
    const float* mlp_W2       = (const float*)d_in[20];
    const float* mlp_b2       = (const float*)d_in[21];
    const float* mlp_bn2_g    = (const float*)d_in[22];
    const float* mlp_bn2_b    = (const float*)d_in[23];
    const float* lstm_Wih     = (const float*)d_in[24];
    const float* lstm_Whh     = (const float*)d_in[25];
    const float* lstm_bih     = (const float*)d_in[26];
    const float* lstm_bhh     = (const float*)d_in[27];
    const float* fc1_W        = (const float*)d_in[28];
    const float* fc1_b        = (const float*)d_in[29];
    const float* fc4_W        = (const float*)d_in[30];
    const float* fc4_b        = (const float*)d_in[31];
    float* outp = (float*)d_out;

    // ---- workspace layout ----
    float* f = (float*)d_ws;
    size_t fo = 0;
    float* X     = f + fo; fo += (size_t)NN * 384;  // proj / z (l>=1) / mlp1-out / final h
    float* sb    = f + fo; fo += (size_t)NN * 384;  // agg out (stacked) / W2 out (l>=1)
    float* zm2   = f + fo; fo += (size_t)NN * 128;  // mlp2 out (layer state)
    float* ews   = f + fo; fo += NN;
    float* stats = f + fo; fo += 48 * 256;
    float* S     = f + fo; fo += (size_t)GG * 384;
    float* ccb   = f + fo; fo += (size_t)GG * 128;
    float* gates = f + fo; fo += (size_t)GG * 512;  // reused as fc1 output
    float* Wcat  = f + fo; fo += (size_t)512 * 384;
    fo = (fo + 7) & ~(size_t)7;   // 16B-align bf16 region
    u16* b = (u16*)(f + fo);
    size_t bo = 0;
    u16* c1_hi   = b + bo; bo += (size_t)3 * 128 * 1280;
    u16* c1_lo   = b + bo; bo += (size_t)3 * 128 * 1280;
    u16* rw1_hi  = b + bo; bo += (size_t)15 * 128 * 128;
    u16* rw1_lo  = b + bo; bo += (size_t)15 * 128 * 128;
    u16* w2_hi   = b + bo; bo += (size_t)18 * 128 * 128;
    u16* w2_lo   = b + bo; bo += (size_t)18 * 128 * 128;
    u16* mw1_hi  = b + bo; bo += (size_t)6 * 128 * 384;
    u16* mw1_lo  = b + bo; bo += (size_t)6 * 128 * 384;
    u16* mw2_hi  = b + bo; bo += (size_t)6 * 128 * 128;
    u16* mw2_lo  = b + bo; bo += (size_t)6 * 128 * 128;
    int* ip = (int*)(b + bo);
    size_t io = 0;
    int* boff0   = ip + io; io += (size_t)3 * NN * NBP1;
    int* csrc0   = ip + io; io += (size_t)3 * EE;
    int* deg     = ip + io; io += NN;
    int* scanned = ip + io; io += NN;
    int* bsum    = ip + io; io += 128;
    int* gstart  = ip + io; io += GG + 1;
    const size_t need = fo * 4 + bo * 2 + io * 4;
    if (ws_size < need) return;

    // CSR-build scratch aliased into sb (dead until first agg/GEMM writes it)
    int* cnt     = (int*)sb;                       // NN*NB ints
    int* cursorB = (int*)sb + (size_t)NN * NB;     // NN*NB ints

    const int NBLK_SCAN = (NN + 511) / 512;

    // ---- weight transpose+split (K padded to x64) ----
    {
        int t;
        t = 3 * 128 * 1280;
        wt_cast2<<<(t + 255) / 256, 256, 0, stream>>>(conv1_W1, c1_hi, c1_lo, t, FIN, 1280);
        t = 15 * 128 * 128;
        wt_cast2<<<(t + 255) / 256, 256, 0, stream>>>(conv_rest_W1, rw1_hi, rw1_lo, t, 128, 128);
        t = 18 * 128 * 128;
        wt_cast2<<<(t + 255) / 256, 256, 0, stream>>>(conv_W2, w2_hi, w2_lo, t, 128, 128);
        t = 6 * 128 * 384;
        wt_cast2<<<(t + 255) / 256, 256, 0, stream>>>(mlp_W1, mw1_hi, mw1_lo, t, 384, 384);
        t = 6 * 128 * 128;
        wt_cast2<<<(t + 255) / 256, 256, 0, stream>>>(mlp_W2, mw2_hi, mw2_lo, t, 128, 128);
    }

    // ---- bucketed CSR build for the 3 edge sets ----
    for (int s = 0; s < 3; ++s) {
        int* boff = boff0 + (size_t)s * NN * NBP1;
        int* csrc = csrc0 + (size_t)s * EE;
        hipMemsetAsync(deg, 0, NN * sizeof(int), stream);
        hipMemsetAsync(cnt, 0, (size_t)NN * NB * sizeof(int), stream);
        count_both<<<(EE + 255) / 256, 256, 0, stream>>>(eidx[s], eidx[s] + EE, deg, cnt);
        scan1<<<NBLK_SCAN, 512, 0, stream>>>(deg, scanned, bsum);
        scan2<<<1, 128, 0, stream>>>(bsum, NBLK_SCAN);
        mk_boff<<<(NN + 255) / 256, 256, 0, stream>>>(deg, scanned, bsum, cnt, boff, cursorB);
        fillB<<<(EE + 255) / 256, 256, 0, stream>>>(eidx[s], eidx[s] + EE, cursorB, csrc);
    }
    seg_starts<<<(NN + 255) / 256, 256, 0, stream>>>(batch, gstart);
    hipMemsetAsync(stats, 0, 48 * 256 * sizeof(float), stream);
    hipMemsetAsync(S, 0, (size_t)GG * 384 * sizeof(float), stream);
    hipMemsetAsync(ccb, 0, (size_t)GG * 128 * sizeof(float), stream);

    const int G128 = (NN + 127) / 128;                 // 391 row tiles
    const int G3   = 24 * ((G128 + 7) / 8);            // 1176 (triplet remap grid)
    const int AGG_GRID = NN / 16;                      // 3125 x-blocks

    // ---- 6 GIN layers ----
    for (int l = 0; l < 6; ++l) {
        float* stL    = stats + (size_t)l * 8 * 256;
        float* slotF1 = stL + 6 * 256;
        float* slotF2 = stL + 7 * 256;
        float* mlp1in  = (l == 0) ? X : sb;     // [NN][384] W2 outputs
        float* mlp1out = (l == 0) ? sb : X;     // [NN][128] compact

        if (l == 0) {
            // proj-first: X[:, k*128..] = x @ W1_k
            gemm_l0<<<G3, 256, 0, stream>>>(
                x, FIN, 1280, FIN, c1_hi, c1_lo, (size_t)128 * 1280,
                X, 384, 128, NN, G128);
            // z_k = (1+eps)proj + agg + b1 (stats -> slots 0/2/4)
            agg_combine<1><<<dim3(AGG_GRID, 3), 256, 0, stream>>>(
                X, 96, boff0, csrc0, conv1_b1,
                nullptr, nullptr, nullptr, conv_eps, 0, sb, stL);
            // W2: X[:, k*128..] = BN1(z_k) @ W2_k + b2 (stats -> slots 1/3/5)
            gemm_dir<1><<<G3, 256, 0, stream>>>(
                sb, (size_t)NN * 128, 128, 128,
                stL, 0, 512,
                conv_bn1_g + l * 3 * 128, conv_bn1_b + l * 3 * 128, 0, 128,
                w2_hi + (size_t)l * 3 * 128 * 128,
                w2_lo + (size_t)l * 3 * 128 * 128, (size_t)128 * 128,
                conv_b2 + l * 3 * 128, 128,
                X, 384, 128, NN, 1, stL + 256, 512, 3, G128);
        } else {
            // agg-first on SHARED h = relu(bn(zm2)) computed on the fly
            agg_combine<0><<<dim3(AGG_GRID, 3), 256, 0, stream>>>(
                zm2, 32, boff0, csrc0, nullptr,
                stats + (size_t)((l - 1) * 8 + 7) * 256,
                mlp_bn2_g + (l - 1) * 128, mlp_bn2_b + (l - 1) * 128,
                conv_eps, l * 3, sb, nullptr);
            // W1: X[:, k*128..] = sb_k @ W1_k + b1 (raw A; stats -> slots 0/2/4)
            gemm_dir<0><<<G3, 256, 0, stream>>>(
                sb, (size_t)NN * 128, 128, 128,
                nullptr, 0, 0, nullptr, nullptr, 0, 0,
                rw1_hi + (size_t)(l - 1) * 3 * 128 * 128,
                rw1_lo + (size_t)(l - 1) * 3 * 128 * 128, (size_t)128 * 128,
                conv_rest_b1 + (l - 1) * 3 * 128, 128,
                X, 384, 128, NN, 1, stL, 512, 3, G128);
            // W2: sb[:, k*128..] = BN1(X slice k) @ W2_k + b2 (stats -> 1/3/5)
            gemm_dir<1><<<G3, 256, 0, stream>>>(
                X, 128, 384, 128,
                stL, 0, 512,
                conv_bn1_g + l * 3 * 128, conv_bn1_b + l * 3 * 128, 0, 128,
                w2_hi + (size_t)l * 3 * 128 * 128,
                w2_lo + (size_t)l * 3 * 128 * 128, (size_t)128 * 128,
                conv_b2 + l * 3 * 128, 128,
                sb, 384, 128, NN, 1, stL + 256, 512, 3, G128);
        }

        // fusion MLP layer 1: BN2(3 slices) @ mlp_W1 -> mlp1out (compact 128)
        gemm_dir<1><<<G128, 256, 0, stream>>>(
            mlp1in, 0, 384, 384,
            stL + 256, 512, 0,
            conv_bn2_g + l * 3 * 128, conv_bn2_b + l * 3 * 128, 128, 0,
            mw1_hi + (size_t)l * 128 * 384, mw1_lo + (size_t)l * 128 * 384, 0,
            mlp_b1 + l * 128, 0, mlp1out, 128, 0, NN, 1, slotF1, 0, 1, G128);

        // fusion MLP layer 2: BN(mlp1out) @ mlp_W2 -> zm2
        gemm_dir<1><<<G128, 256, 0, stream>>>(
            mlp1out, 0, 128, 128,
            slotF1, 0, 0,
            mlp_bn1_g + l * 128, mlp_bn1_b + l * 128, 0, 0,
            mw2_hi + (size_t)l * 128 * 128, mw2_lo + (size_t)l * 128 * 128, 0,
            mlp_b2 + l * 128, 0, zm2, 128, 0, NN, 1, slotF2, 0, 1, G128);
    }
    // final h = bn_relu(zm2, layer-5 F2 stats) -> X (compact [NN][128])
    bn_relu_f32<<<(NN * 64 + 255) / 256, 256, 0, stream>>>(
        zm2, stats + (size_t)(5 * 8 + 7) * 256,
        mlp_bn2_g + 5 * 128, mlp_bn2_b + 5 * 128, X);

    // ---- Set2Set readout (fp32) ----
    pack_wcat<<<(512 * 384 + 255) / 256, 256, 0, stream>>>(lstm_Wih, lstm_Whh, Wcat);
    for (int t = 0; t < 6; ++t) {
        gemm_f32<true><<<dim3(8, 4), 256, 0, stream>>>(
            S, Wcat, nullptr, gates, GG, 384, 512);
        lstm_kernel<<<(GG * 128 + 255) / 256, 256, 0, stream>>>(
            gates, lstm_bih, lstm_bhh, ccb, S);
        attend_kernel<<<GG, 256, 0, stream>>>(X, S, ews, gstart);
    }
    fc1_kernel<<<GG, 128, 0, stream>>>(S, fc1_W, fc1_b, gates);
    fc4_kernel<<<(GG * 12 + 255) / 256, 256, 0, stream>>>(gates, fc4_W, fc4_b, outp);
}

// Round 11
// 4996.415 us; speedup vs baseline: 1.2140x; 1.2140x over previous
//
#include <hip/hip_runtime.h>
#include <cstdint>
#include <cstddef>

#define NN 50000
#define EE 1600000
#define GG 512
#define FIN 1273

typedef unsigned short u16;
typedef unsigned int u32;
typedef __attribute__((ext_vector_type(8))) short short8;
typedef __attribute__((ext_vector_type(4))) float f32x4;

__device__ __forceinline__ float sigmf(float x) { return 1.f / (1.f + expf(-x)); }

// truncation split: v == hi + rem exactly; lo = bf16(rem); |v-(hi+lo)| <= 2^-16 |v|
__device__ __forceinline__ void splitbf(float v, u16& hi, u16& lo) {
    const u32 u = __float_as_uint(v);
    hi = (u16)(u >> 16);
    const float rem = v - __uint_as_float(u & 0xffff0000u);
    lo = (u16)(__float_as_uint(rem) >> 16);
}

__device__ __forceinline__ void gload_lds16(const void* g, void* l) {
    __builtin_amdgcn_global_load_lds(
        (const __attribute__((address_space(1))) void*)g,
        (__attribute__((address_space(3))) void*)l, 16, 0, 0);
}

// XCD-aware triplet remap: put the 3 mats of one row tile on the same XCD.
__device__ __forceinline__ bool remap3(int f, int nRow, int& mat, int& rt) {
    const int g = f / 24, w = f - g * 24;
    rt = g * 8 + (w & 7);
    mat = w >> 3;
    return rt < nRow;
}

// ===== layer-0 GEMM: split-bf16 MFMA, A = fp32 x staged via LDS ================
__global__ __launch_bounds__(256) void gemm_l0(
    const float* __restrict__ A, int lda, int K, int Kreal,
    const u16* __restrict__ Bhi, const u16* __restrict__ Blo, size_t strideB,
    float* __restrict__ C, int ldc, int coffStep, int M, int nRow)
{
    __shared__ u16 lsAhi[128 * 64];
    __shared__ u16 lsAlo[128 * 64];
    __shared__ u16 lsBhi[128 * 64];
    __shared__ u16 lsBlo[128 * 64];
    int mat, rt;
    if (!remap3(blockIdx.x, nRow, mat, rt)) return;
    const int tid = threadIdx.x;
    const int wave = tid >> 6, lane = tid & 63;
    const int row0 = rt * 128;
    const int coff = mat * coffStep;
    const u16* Bh = Bhi + (size_t)mat * strideB;
    const u16* Bl = Blo + (size_t)mat * strideB;
    const int wm = wave >> 1, wn = wave & 1;
    f32x4 acc[4][4] = {};

    for (int k0 = 0; k0 < K; k0 += 64) {
        if (k0) __syncthreads();
        #pragma unroll
        for (int i = 0; i < 4; ++i) {
            const int slot = i * 256 + tid;
            const int r = slot >> 3, ch = tid & 7;
            int gr = row0 + r; if (gr >= M) gr = M - 1;
            const int kb = k0 + ch * 8;
            u16 th[8], tl[8];
            const float* src = A + (size_t)gr * lda + kb;
            if (kb + 8 <= Kreal) {
                const float4 v0 = *(const float4*)(src);
                const float4 v1 = *(const float4*)(src + 4);
                const float va[8] = {v0.x, v0.y, v0.z, v0.w,
                                     v1.x, v1.y, v1.z, v1.w};
                #pragma unroll
                for (int e = 0; e < 8; ++e) splitbf(va[e], th[e], tl[e]);
            } else {
                #pragma unroll
                for (int e = 0; e < 8; ++e) {
                    const float v = (kb + e < Kreal) ? src[e] : 0.f;
                    splitbf(v, th[e], tl[e]);
                }
            }
            const int off = (r << 6) + ((ch ^ (r & 7)) << 3);
            *(short8*)&lsAhi[off] = *(const short8*)th;
            *(short8*)&lsAlo[off] = *(const short8*)tl;
        }
        #pragma unroll
        for (int i = 0; i < 4; ++i) {
            const int slot = i * 256 + wave * 64 + lane;
            const int r = slot >> 3, ch = slot & 7;
            const int sch = ch ^ (r & 7);
            const size_t goff = (size_t)r * K + k0 + sch * 8;
            const int lbase = (i * 256 + wave * 64) * 8;
            gload_lds16(Bh + goff, &lsBhi[lbase]);
            gload_lds16(Bl + goff, &lsBlo[lbase]);
        }
        __syncthreads();
        #pragma unroll
        for (int ks = 0; ks < 2; ++ks) {
            short8 ah[4], al[4], bh[4], bl[4];
            const int kch = ks * 4 + (lane >> 4);
            #pragma unroll
            for (int m = 0; m < 4; ++m) {
                const int r = wm * 64 + m * 16 + (lane & 15);
                const int off = (r << 6) + ((kch ^ (r & 7)) << 3);
                ah[m] = *(const short8*)&lsAhi[off];
                al[m] = *(const short8*)&lsAlo[off];
            }
            #pragma unroll
            for (int n = 0; n < 4; ++n) {
                const int c = wn * 64 + n * 16 + (lane & 15);
                const int off = (c << 6) + ((kch ^ (c & 7)) << 3);
                bh[n] = *(const short8*)&lsBhi[off];
                bl[n] = *(const short8*)&lsBlo[off];
            }
            #pragma unroll
            for (int m = 0; m < 4; ++m)
                #pragma unroll
                for (int n = 0; n < 4; ++n) {
                    acc[m][n] = __builtin_amdgcn_mfma_f32_16x16x32_bf16(
                        ah[m], bh[n], acc[m][n], 0, 0, 0);
                    acc[m][n] = __builtin_amdgcn_mfma_f32_16x16x32_bf16(
                        ah[m], bl[n], acc[m][n], 0, 0, 0);
                    acc[m][n] = __builtin_amdgcn_mfma_f32_16x16x32_bf16(
                        al[m], bh[n], acc[m][n], 0, 0, 0);
                }
        }
    }
    #pragma unroll
    for (int n = 0; n < 4; ++n) {
        const int c = wn * 64 + n * 16 + (lane & 15);
        #pragma unroll
        for (int m = 0; m < 4; ++m) {
            #pragma unroll
            for (int j = 0; j < 4; ++j) {
                const int gr = row0 + wm * 64 + m * 16 + ((lane >> 4) << 2) + j;
                if (gr < M)
                    C[(size_t)gr * ldc + coff + c] = acc[m][n][j];
            }
        }
    }
}

// ===== direct-A GEMM: A fp32 from global (no A LDS) ============================
template <int ABN>
__global__ __launch_bounds__(256) void gemm_dir(
    const float* __restrict__ A, size_t strideA, int lda, int K,
    const float* __restrict__ st, int stSlice, int stMat,
    const float* __restrict__ ga, const float* __restrict__ be,
    int gbSlice, int gbMat,
    const u16* __restrict__ Bhi, const u16* __restrict__ Blo, size_t strideB,
    const float* __restrict__ bias, int biasMat,
    float* __restrict__ C, int ldc, int coffStep,
    int M, int do_stats, float* __restrict__ stats_out, int ostatMat,
    int nMat, int nRow)
{
    __shared__ u16 lsBhi[128 * 64];
    __shared__ u16 lsBlo[128 * 64];
    int mat, rt;
    if (nMat == 3) {
        if (!remap3(blockIdx.x, nRow, mat, rt)) return;
    } else { mat = 0; rt = blockIdx.x; }
    const int tid = threadIdx.x;
    const int wave = tid >> 6, lane = tid & 63;
    const int row0 = rt * 128;
    const int wm = wave >> 1, wn = wave & 1;
    A += (size_t)mat * strideA;
    if (ABN) { st += mat * stMat; ga += mat * gbMat; be += mat * gbMat; }
    if (bias) bias += mat * biasMat;
    if (do_stats) stats_out += mat * ostatMat;
    const u16* Bh = Bhi + (size_t)mat * strideB;
    const u16* Bl = Blo + (size_t)mat * strideB;
    const int coff = mat * coffStep;
    f32x4 acc[4][4] = {};

    int arow[4];
    #pragma unroll
    for (int m = 0; m < 4; ++m) {
        int r = row0 + wm * 64 + m * 16 + (lane & 15);
        if (r >= M) r = M - 1;
        arow[m] = r;
    }

    for (int k0 = 0; k0 < K; k0 += 64) {
        if (k0) __syncthreads();
        #pragma unroll
        for (int i = 0; i < 4; ++i) {
            const int slot = i * 256 + wave * 64 + lane;
            const int r = slot >> 3, ch = slot & 7;
            const int sch = ch ^ (r & 7);
            const size_t goff = (size_t)r * K + k0 + sch * 8;
            const int lbase = (i * 256 + wave * 64) * 8;
            gload_lds16(Bh + goff, &lsBhi[lbase]);
            gload_lds16(Bl + goff, &lsBlo[lbase]);
        }
        __syncthreads();
        #pragma unroll
        for (int ks = 0; ks < 2; ++ks) {
            const int kch = ks * 4 + (lane >> 4);
            const int kb = k0 + kch * 8;
            float scv[8], shv[8];
            if (ABN) {
                const int s = kb >> 7, d0 = kb & 127;
                const float* stS = st + s * stSlice;
                const float* gS  = ga + s * gbSlice;
                const float* beS = be + s * gbSlice;
                #pragma unroll
                for (int e = 0; e < 8; ++e) {
                    const int d = d0 + e;
                    const float mu = stS[d] * (1.f / NN);
                    const float var = fmaxf(stS[128 + d] * (1.f / NN) - mu * mu, 0.f);
                    const float sc = gS[d] * rsqrtf(var + 1e-5f);
                    scv[e] = sc;
                    shv[e] = beS[d] - sc * mu;
                }
            }
            short8 ah[4], al[4];
            #pragma unroll
            for (int m = 0; m < 4; ++m) {
                const float* src = A + (size_t)arow[m] * lda + kb;
                const float4 v0 = *(const float4*)(src);
                const float4 v1 = *(const float4*)(src + 4);
                const float va[8] = {v0.x, v0.y, v0.z, v0.w,
                                     v1.x, v1.y, v1.z, v1.w};
                u16 th[8], tl[8];
                #pragma unroll
                for (int e = 0; e < 8; ++e) {
                    const float y = ABN
                        ? fmaxf(fmaf(scv[e], va[e], shv[e]), 0.f) : va[e];
                    splitbf(y, th[e], tl[e]);
                }
                ah[m] = *(const short8*)th;
                al[m] = *(const short8*)tl;
            }
            #pragma unroll
            for (int n = 0; n < 4; ++n) {
                const int c = wn * 64 + n * 16 + (lane & 15);
                const int off = (c << 6) + ((kch ^ (c & 7)) << 3);
                const short8 bh = *(const short8*)&lsBhi[off];
                const short8 bl = *(const short8*)&lsBlo[off];
                #pragma unroll
                for (int m = 0; m < 4; ++m) {
                    acc[m][n] = __builtin_amdgcn_mfma_f32_16x16x32_bf16(
                        ah[m], bh, acc[m][n], 0, 0, 0);
                    acc[m][n] = __builtin_amdgcn_mfma_f32_16x16x32_bf16(
                        ah[m], bl, acc[m][n], 0, 0, 0);
                    acc[m][n] = __builtin_amdgcn_mfma_f32_16x16x32_bf16(
                        al[m], bh, acc[m][n], 0, 0, 0);
                }
            }
        }
    }

    float colsum[4] = {0.f, 0.f, 0.f, 0.f}, colsq[4] = {0.f, 0.f, 0.f, 0.f};
    #pragma unroll
    for (int n = 0; n < 4; ++n) {
        const int c = wn * 64 + n * 16 + (lane & 15);
        const float bv = bias ? bias[c] : 0.f;
        #pragma unroll
        for (int m = 0; m < 4; ++m) {
            #pragma unroll
            for (int j = 0; j < 4; ++j) {
                const int gr = row0 + wm * 64 + m * 16 + ((lane >> 4) << 2) + j;
                if (gr < M) {
                    const float v = acc[m][n][j] + bv;
                    C[(size_t)gr * ldc + coff + c] = v;
                    colsum[n] += v; colsq[n] += v * v;
                }
            }
        }
    }
    if (do_stats) {
        float* ssum = (float*)lsBhi;
        float* ssq  = ssum + 128;
        __syncthreads();
        if (tid < 128) { ssum[tid] = 0.f; ssq[tid] = 0.f; }
        __syncthreads();
        #pragma unroll
        for (int n = 0; n < 4; ++n) {
            const int c = wn * 64 + n * 16 + (lane & 15);
            atomicAdd(&ssum[c], colsum[n]);
            atomicAdd(&ssq[c], colsq[n]);
        }
        __syncthreads();
        if (tid < 128) {
            atomicAdd(&stats_out[tid],       ssum[tid]);
            atomicAdd(&stats_out[128 + tid], ssq[tid]);
        }
    }
}

// ------ weight transpose+split: W[nmat][K][128] -> Whi/Wlo[nmat][128][Kpad] ----
__global__ __launch_bounds__(256) void wt_cast2(const float* __restrict__ W,
                                                u16* __restrict__ Whi,
                                                u16* __restrict__ Wlo,
                                                int total, int K, int Kpad) {
    const int idx = blockIdx.x * 256 + threadIdx.x;
    if (idx >= total) return;
    const int perm = 128 * Kpad;
    const int m = idx / perm, rem = idx - m * perm;
    const int n = rem / Kpad, k = rem - n * Kpad;
    const float v = (k < K) ? W[(size_t)m * K * 128 + (size_t)k * 128 + n] : 0.f;
    u16 hi, lo;
    splitbf(v, hi, lo);
    Whi[idx] = hi; Wlo[idx] = lo;
}

// ---------------- fp32 tiled GEMM (LSTM gates only) ----------------------------
template <bool BT>
__global__ __launch_bounds__(256) void gemm_f32(
    const float* __restrict__ A, const float* __restrict__ B,
    const float* __restrict__ bias, float* __restrict__ C,
    int M, int K, int Nc)
{
    __shared__ float As[32][68];
    __shared__ float Bs[32][132];
    const int tid = threadIdx.x;
    const int tx = tid & 15, ty = tid >> 4;
    const int row0 = blockIdx.x * 64, col0 = blockIdx.y * 128;
    float acc[4][8] = {};
    for (int k0 = 0; k0 < K; k0 += 32) {
        {
            const int kk = tid & 31, rb = tid >> 5;
            #pragma unroll
            for (int i = 0; i < 8; ++i) {
                const int r = rb + i * 8, gr = row0 + r, gk = k0 + kk;
                As[kk][r] = (gr < M && gk < K) ? A[(size_t)gr * K + gk] : 0.f;
            }
        }
        if (!BT) {
            const int c = tid & 127, kb = tid >> 7;
            #pragma unroll
            for (int i = 0; i < 16; ++i) {
                const int kk = kb + i * 2, gk = k0 + kk;
                Bs[kk][c] = (gk < K) ? B[(size_t)gk * Nc + col0 + c] : 0.f;
            }
        } else {
            const int kk = tid & 31, cb = tid >> 5;
            #pragma unroll
            for (int i = 0; i < 16; ++i) {
                const int c = cb + i * 8, gk = k0 + kk;
                Bs[kk][c] = (gk < K) ? B[(size_t)(col0 + c) * K + gk] : 0.f;
            }
        }
        __syncthreads();
        #pragma unroll 8
        for (int kk = 0; kk < 32; ++kk) {
            const float4 av  = *(const float4*)&As[kk][ty * 4];
            const float4 bv0 = *(const float4*)&Bs[kk][tx * 8];
            const float4 bv1 = *(const float4*)&Bs[kk][tx * 8 + 4];
            const float a[4] = {av.x, av.y, av.z, av.w};
            const float b[8] = {bv0.x, bv0.y, bv0.z, bv0.w, bv1.x, bv1.y, bv1.z, bv1.w};
            #pragma unroll
            for (int i = 0; i < 4; ++i)
                #pragma unroll
                for (int j = 0; j < 8; ++j)
                    acc[i][j] = fmaf(a[i], b[j], acc[i][j]);
        }
        __syncthreads();
    }
    #pragma unroll
    for (int j = 0; j < 8; ++j) {
        const float bv = bias ? bias[col0 + tx * 8 + j] : 0.f;
        #pragma unroll
        for (int i = 0; i < 4; ++i) acc[i][j] += bv;
    }
    #pragma unroll
    for (int i = 0; i < 4; ++i) {
        const int gr = row0 + ty * 4 + i;
        if (gr < M) {
            *(float4*)&C[(size_t)gr * Nc + col0 + tx * 8] =
                make_float4(acc[i][0], acc[i][1], acc[i][2], acc[i][3]);
            *(float4*)&C[(size_t)gr * Nc + col0 + tx * 8 + 4] =
                make_float4(acc[i][4], acc[i][5], acc[i][6], acc[i][7]);
        }
    }
}

// ---------------- CSR build (counting sort by destination) ---------------------
__global__ __launch_bounds__(256) void count_deg(const int* __restrict__ dst,
                                                 int* __restrict__ deg) {
    const int e = blockIdx.x * 256 + threadIdx.x;
    if (e < EE) atomicAdd(&deg[dst[e]], 1);
}

__global__ __launch_bounds__(512) void scan1(const int* __restrict__ deg,
                                             int* __restrict__ scanned,
                                             int* __restrict__ bsum) {
    __shared__ int s[512];
    const int t = threadIdx.x;
    const int i = blockIdx.x * 512 + t;
    const int v = (i < NN) ? deg[i] : 0;
    s[t] = v; __syncthreads();
    for (int o = 1; o < 512; o <<= 1) {
        const int tv = (t >= o) ? s[t - o] : 0;
        __syncthreads();
        s[t] += tv;
        __syncthreads();
    }
    if (i < NN) scanned[i] = s[t];
    if (t == 511) bsum[blockIdx.x] = s[511];
}

__global__ __launch_bounds__(128) void scan2(int* __restrict__ bsum, int nb) {
    __shared__ int s[128];
    const int t = threadIdx.x;
    const int v = (t < nb) ? bsum[t] : 0;
    s[t] = v; __syncthreads();
    for (int o = 1; o < 128; o <<= 1) {
        const int tv = (t >= o) ? s[t - o] : 0;
        __syncthreads();
        s[t] += tv;
        __syncthreads();
    }
    if (t < nb) bsum[t] = s[t] - v;  // exclusive
}

__global__ __launch_bounds__(256) void scan3(const int* __restrict__ deg,
                                             const int* __restrict__ scanned,
                                             const int* __restrict__ bsum,
                                             int* __restrict__ rowptr,
                                             int* __restrict__ cursor) {
    const int i = blockIdx.x * 256 + threadIdx.x;
    if (i < NN) {
        const int v = bsum[i >> 9] + scanned[i] - deg[i];
        rowptr[i] = v; cursor[i] = v;
    }
    if (i == 0) rowptr[NN] = EE;
}

__global__ __launch_bounds__(256) void fill_csr(const int* __restrict__ src,
                                                const int* __restrict__ dst,
                                                int* __restrict__ cursor,
                                                int* __restrict__ csrc) {
    const int e = blockIdx.x * 256 + threadIdx.x;
    if (e < EE) {
        const int pos = atomicAdd(&cursor[dst[e]], 1);
        csrc[pos] = src[e];
    }
}

// ==== fused aggregate + combine (3 edge sets in one launch) ====================
// L0=1: gather proj slice k of X; z_k = (1+eps)self + agg + b1, column stats.
// L0=0: gather SHARED zm2 applying h = relu(bn(v)) on the fly.
// One wave per dst node slot (4 nodes/wave); 32-edge main loop -> 16 float4
// gathers in flight per lane (2 rows per load batch via lane-half split).
template <int L0>
__global__ __launch_bounds__(256) void agg_combine(
    const float* __restrict__ X, int ldp4,
    const int* __restrict__ rowptrB, const int* __restrict__ csrcB,
    const float* __restrict__ b1B,
    const float* __restrict__ stF2, const float* __restrict__ gam,
    const float* __restrict__ bet,
    const float* __restrict__ eps_arr, int epsBase,
    float* __restrict__ zB, float* __restrict__ statsB)
{
    __shared__ float red[256];
    const int k = blockIdx.y;
    const int* rowptr = rowptrB + (size_t)k * (NN + 1);
    const int* csrc   = csrcB + (size_t)k * EE;
    float* z          = zB + (size_t)k * NN * 128;
    const int tid = threadIdx.x, lane = tid & 63, wave = tid >> 6;
    const float e1 = 1.f + eps_arr[epsBase + k];
    const int half = lane >> 5;
    const int l32 = lane & 31;
    const float4* p4 = (const float4*)X + (L0 ? k * 32 : 0);
    float s[4] = {0.f, 0.f, 0.f, 0.f}, q[4] = {0.f, 0.f, 0.f, 0.f};
    float4 bv = make_float4(0.f, 0.f, 0.f, 0.f);
    float sc[4], sh[4];
    if (L0) {
        if (lane < 32) bv = ((const float4*)(b1B + k * 128))[l32];
    } else {
        #pragma unroll
        for (int c = 0; c < 4; ++c) {
            const int d = l32 * 4 + c;
            const float mu = stF2[d] * (1.f / NN);
            const float var = fmaxf(stF2[128 + d] * (1.f / NN) - mu * mu, 0.f);
            const float s_ = gam[d] * rsqrtf(var + 1e-5f);
            sc[c] = s_;
            sh[c] = bet[d] - s_ * mu;
        }
    }
    auto bnv = [&](float4 v) -> float4 {
        if (L0) return v;
        v.x = fmaxf(fmaf(sc[0], v.x, sh[0]), 0.f);
        v.y = fmaxf(fmaf(sc[1], v.y, sh[1]), 0.f);
        v.z = fmaxf(fmaf(sc[2], v.z, sh[2]), 0.f);
        v.w = fmaxf(fmaf(sc[3], v.w, sh[3]), 0.f);
        return v;
    };
    if (L0) { red[tid] = 0.f; __syncthreads(); }
    const int nbase = blockIdx.x * 16 + wave * 4;
    for (int t = 0; t < 4; ++t) {
        const int wid = nbase + t;
        const int s0 = rowptr[wid], s1 = rowptr[wid + 1];
        float ax = 0.f, ay = 0.f, az = 0.f, aw = 0.f;
        int j = s0;
        for (; j + 31 < s1; j += 32) {
            float4 v[16];
            #pragma unroll
            for (int u = 0; u < 16; ++u)
                v[u] = p4[(size_t)csrc[j + 2 * u + half] * ldp4 + l32];
            #pragma unroll
            for (int u = 0; u < 16; ++u) {
                const float4 b_ = bnv(v[u]);
                ax += b_.x; ay += b_.y; az += b_.z; aw += b_.w;
            }
        }
        for (; j + 15 < s1; j += 16) {
            float4 v[8];
            #pragma unroll
            for (int u = 0; u < 8; ++u)
                v[u] = p4[(size_t)csrc[j + 2 * u + half] * ldp4 + l32];
            #pragma unroll
            for (int u = 0; u < 8; ++u) {
                const float4 b_ = bnv(v[u]);
                ax += b_.x; ay += b_.y; az += b_.z; aw += b_.w;
            }
        }
        for (; j + 7 < s1; j += 8) {
            float4 v[4];
            #pragma unroll
            for (int u = 0; u < 4; ++u)
                v[u] = p4[(size_t)csrc[j + 2 * u + half] * ldp4 + l32];
            #pragma unroll
            for (int u = 0; u < 4; ++u) {
                const float4 b_ = bnv(v[u]);
                ax += b_.x; ay += b_.y; az += b_.z; aw += b_.w;
            }
        }
        for (; j + 3 < s1; j += 4) {
            const float4 v0 = bnv(p4[(size_t)csrc[j + half] * ldp4 + l32]);
            const float4 v1 = bnv(p4[(size_t)csrc[j + 2 + half] * ldp4 + l32]);
            ax += v0.x + v1.x; ay += v0.y + v1.y;
            az += v0.z + v1.z; aw += v0.w + v1.w;
        }
        for (; j + 1 < s1; j += 2) {
            const float4 v0 = bnv(p4[(size_t)csrc[j + half] * ldp4 + l32]);
            ax += v0.x; ay += v0.y; az += v0.z; aw += v0.w;
        }
        if (j < s1 && half == 0) {
            const float4 v0 = bnv(p4[(size_t)csrc[j] * ldp4 + l32]);
            ax += v0.x; ay += v0.y; az += v0.z; aw += v0.w;
        }
        ax += __shfl_down(ax, 32, 64);
        ay += __shfl_down(ay, 32, 64);
        az += __shfl_down(az, 32, 64);
        aw += __shfl_down(aw, 32, 64);
        if (lane < 32) {
            const float4 self = bnv(p4[(size_t)wid * ldp4 + l32]);
            float4 zv;
            zv.x = fmaf(e1, self.x, ax + bv.x);
            zv.y = fmaf(e1, self.y, ay + bv.y);
            zv.z = fmaf(e1, self.z, az + bv.z);
            zv.w = fmaf(e1, self.w, aw + bv.w);
            ((float4*)z)[(size_t)wid * 32 + l32] = zv;
            if (L0) {
                s[0] += zv.x; s[1] += zv.y; s[2] += zv.z; s[3] += zv.w;
                q[0] += zv.x * zv.x; q[1] += zv.y * zv.y;
                q[2] += zv.z * zv.z; q[3] += zv.w * zv.w;
            }
        }
    }
    if (L0) {
        if (lane < 32) {
            const int d = l32 * 4;
            #pragma unroll
            for (int c = 0; c < 4; ++c) {
                atomicAdd(&red[d + c], s[c]);
                atomicAdd(&red[128 + d + c], q[c]);
            }
        }
        __syncthreads();
        atomicAdd(&statsB[(size_t)k * 512 + tid], red[tid]);
    }
}

// ------- BN + ReLU -> fp32 (final h only) --------------------------------------
__global__ __launch_bounds__(256) void bn_relu_f32(
    const float* __restrict__ xin, const float* __restrict__ stats,
    const float* __restrict__ gamma, const float* __restrict__ beta,
    float* __restrict__ out)
{
    const size_t i = (size_t)blockIdx.x * 256 + threadIdx.x;  // pair index
    if (i >= (size_t)NN * 64) return;
    const int d = (int)(i & 63) * 2;
    const float inv_n = 1.f / NN;
    const float mu0 = stats[d] * inv_n,     mu1 = stats[d + 1] * inv_n;
    const float v0 = fmaxf(stats[128 + d] * inv_n - mu0 * mu0, 0.f);
    const float v1 = fmaxf(stats[129 + d] * inv_n - mu1 * mu1, 0.f);
    const float s0 = gamma[d] * rsqrtf(v0 + 1e-5f);
    const float s1 = gamma[d + 1] * rsqrtf(v1 + 1e-5f);
    const float2 xv = ((const float2*)xin)[i];
    const float y0 = fmaxf(fmaf(s0, xv.x - mu0, beta[d]), 0.f);
    const float y1 = fmaxf(fmaf(s1, xv.y - mu1, beta[d + 1]), 0.f);
    ((float2*)out)[i] = make_float2(y0, y1);
}

// ---------------- per-graph segment starts (batch is sorted) -------------------
__global__ __launch_bounds__(256) void seg_starts(const int* __restrict__ batch,
                                                  int* __restrict__ gstart) {
    const int i = blockIdx.x * 256 + threadIdx.x;
    if (i >= NN) return;
    const int b = batch[i];
    if (i == 0) { for (int g = 0; g <= b; ++g) gstart[g] = 0; }
    else {
        const int pb = batch[i - 1];
        for (int g = pb + 1; g <= b; ++g) gstart[g] = i;
    }
    if (i == NN - 1) { for (int g = b + 1; g <= GG; ++g) gstart[g] = NN; }
}

// ---------------- Set2Set ------------------------------------------------------
__global__ __launch_bounds__(256) void pack_wcat(const float* __restrict__ Wih,
                                                 const float* __restrict__ Whh,
                                                 float* __restrict__ Wcat) {
    const int i = blockIdx.x * 256 + threadIdx.x;
    if (i >= 512 * 384) return;
    const int j = i / 384, k = i - j * 384;
    Wcat[i] = (k < 256) ? Wih[j * 256 + k] : Whh[j * 128 + (k - 256)];
}

__global__ __launch_bounds__(256) void lstm_kernel(
    const float* __restrict__ gates, const float* __restrict__ bih,
    const float* __restrict__ bhh, float* __restrict__ cc, float* __restrict__ S)
{
    const int i = blockIdx.x * 256 + threadIdx.x;
    if (i >= GG * 128) return;
    const int g = i >> 7, d = i & 127;
    const float* gr = gates + (size_t)g * 512;
    const float ig = gr[d]       + bih[d]       + bhh[d];
    const float fg = gr[128 + d] + bih[128 + d] + bhh[128 + d];
    const float gv = gr[256 + d] + bih[256 + d] + bhh[256 + d];
    const float og = gr[384 + d] + bih[384 + d] + bhh[384 + d];
    const float c  = sigmf(fg) * cc[i] + sigmf(ig) * tanhf(gv);
    const float hv = sigmf(og) * tanhf(c);
    cc[i] = c;
    S[(size_t)g * 384 + d] = hv;
    S[(size_t)g * 384 + 256 + d] = hv;
}

__global__ __launch_bounds__(256) void attend_kernel(
    const float* __restrict__ h, float* __restrict__ S,
    float* __restrict__ ews, const int* __restrict__ gstart)
{
    const int g = blockIdx.x;
    const int rs = gstart[g], re = gstart[g + 1];
    const int tid = threadIdx.x, lane = tid & 63, w = tid >> 6;
    __shared__ float q[128];
    __shared__ float red[8];
    if (tid < 128) q[tid] = S[(size_t)g * 384 + 256 + tid];
    __syncthreads();
    const float2* h2 = (const float2*)h;
    float lmax = -1e30f;
    for (int n = rs + w; n < re; n += 4) {
        const float2 hv = h2[(size_t)n * 64 + lane];
        float p = hv.x * q[2 * lane] + hv.y * q[2 * lane + 1];
        #pragma unroll
        for (int o = 32; o; o >>= 1) p += __shfl_down(p, o, 64);
        if (lane == 0) { ews[n] = p; lmax = fmaxf(lmax, p); }
    }
    if (lane == 0) red[w] = lmax;
    __syncthreads();
    const float m = fmaxf(fmaxf(red[0], red[1]), fmaxf(red[2], red[3]));
    __syncthreads();
    float lsum = 0.f;
    for (int n = rs + tid; n < re; n += 256) {
        const float ex = expf(ews[n] - m);
        ews[n] = ex; lsum += ex;
    }
    #pragma unroll
    for (int o = 32; o; o >>= 1) lsum += __shfl_down(lsum, o, 64);
    if (lane == 0) red[w] = lsum;
    __syncthreads();
    const float denom = red[0] + red[1] + red[2] + red[3];
    if (tid < 128) {
        float acc = 0.f;
        for (int n = rs; n < re; ++n)
            acc = fmaf(ews[n], h[(size_t)n * 128 + tid], acc);
        S[(size_t)g * 384 + 128 + tid] = (denom > 0.f) ? acc / denom : 0.f;
    }
}

__global__ __launch_bounds__(128) void fc1_kernel(const float* __restrict__ S,
                                                  const float* __restrict__ W,
                                                  const float* __restrict__ b,
                                                  float* __restrict__ out1) {
    const int g = blockIdx.x, d = threadIdx.x;
    __shared__ float qs[256];
    qs[d] = S[(size_t)g * 384 + d];
    qs[128 + d] = S[(size_t)g * 384 + 128 + d];
    __syncthreads();
    float acc = b[d];
    for (int k = 0; k < 256; ++k) acc = fmaf(qs[k], W[k * 128 + d], acc);
    out1[(size_t)g * 128 + d] = fmaxf(acc, 0.f);
}

__global__ __launch_bounds__(256) void fc4_kernel(const float* __restrict__ out1,
                                                  const float* __restrict__ W,
                                                  const float* __restrict__ b,
                                                  float* __restrict__ out) {
    const int i = blockIdx.x * 256 + threadIdx.x;
    if (i >= GG * 12) return;
    const int g = i / 12, j = i - g * 12;
    float acc = b[j];
    for (int d = 0; d < 128; ++d)
        acc = fmaf(out1[(size_t)g * 128 + d], W[d * 12 + j], acc);
    out[i] = acc;
}

// ================================================================================
extern "C" void kernel_launch(void* const* d_in, const int* in_sizes, int n_in,
                              void* d_out, int out_size, void* d_ws, size_t ws_size,
                              hipStream_t stream)
{
    const float* x        = (const float*)d_in[0];
    const int*   eidx[3]  = {(const int*)d_in[1], (const int*)d_in[2], (const int*)d_in[3]};
    const int*   batch    = (const int*)d_in[4];
    const float* conv1_W1     = (const float*)d_in[5];
    const float* conv1_b1     = (const float*)d_in[6];
    const float* conv_rest_W1 = (const float*)d_in[7];
    const float* conv_rest_b1 = (const float*)d_in[8];
    const float* conv_W2      = (const float*)d_in[9];
    const float* conv_b2      = (const float*)d_in[10];
    const float* conv_bn1_g   = (const float*)d_in[11];
    const float* conv_bn1_b   = (const float*)d_in[12];
    const float* conv_bn2_g   = (const float*)d_in[13];
    const float* conv_bn2_b   = (const float*)d_in[14];
    const float* conv_eps     = (const float*)d_in[15];
    const float* mlp_W1       = (const float*)d_in[16];
    const float* mlp_b1       = (const float*)d_in[17];
    const float* mlp_bn1_g    = (const float*)d_in[18];
    const float* mlp_bn1_b    = (const float*)d_in[19];
    const float* mlp_W2       = (const float*)d_in[20];
    const float* mlp_b2       = (const float*)d_in[21];
    const float* mlp_bn2_g    = (const float*)d_in[22];
    const float* mlp_bn2_b    = (const float*)d_in[23];
    const float* lstm_Wih     = (const float*)d_in[24];
    const float* lstm_Whh     = (const float*)d_in[25];
    const float* lstm_bih     = (const float*)d_in[26];
    const float* lstm_bhh     = (const float*)d_in[27];
    const float* fc1_W        = (const float*)d_in[28];
    const float* fc1_b        = (const float*)d_in[29];
    const float* fc4_W        = (const float*)d_in[30];
    const float* fc4_b        = (const float*)d_in[31];
    float* outp = (float*)d_out;

    // ---- workspace layout ----
    float* f = (float*)d_ws;
    size_t fo = 0;
    float* X     = f + fo; fo += (size_t)NN * 384;  // proj / z (l>=1) / mlp1-out / final h
    float* sb    = f + fo; fo += (size_t)NN * 384;  // agg out (stacked) / W2 out (l>=1)
    float* zm2   = f + fo; fo += (size_t)NN * 128;  // mlp2 out (layer state)
    float* ews   = f + fo; fo += NN;
    float* stats = f + fo; fo += 48 * 256;
    float* S     = f + fo; fo += (size_t)GG * 384;
    float* ccb   = f + fo; fo += (size_t)GG * 128;
    float* gates = f + fo; fo += (size_t)GG * 512;  // reused as fc1 output
    float* Wcat  = f + fo; fo += (size_t)512 * 384;
    fo = (fo + 7) & ~(size_t)7;   // 16B-align bf16 region
    u16* b = (u16*)(f + fo);
    size_t bo = 0;
    u16* c1_hi   = b + bo; bo += (size_t)3 * 128 * 1280;
    u16* c1_lo   = b + bo; bo += (size_t)3 * 128 * 1280;
    u16* rw1_hi  = b + bo; bo += (size_t)15 * 128 * 128;
    u16* rw1_lo  = b + bo; bo += (size_t)15 * 128 * 128;
    u16* w2_hi   = b + bo; bo += (size_t)18 * 128 * 128;
    u16* w2_lo   = b + bo; bo += (size_t)18 * 128 * 128;
    u16* mw1_hi  = b + bo; bo += (size_t)6 * 128 * 384;
    u16* mw1_lo  = b + bo; bo += (size_t)6 * 128 * 384;
    u16* mw2_hi  = b + bo; bo += (size_t)6 * 128 * 128;
    u16* mw2_lo  = b + bo; bo += (size_t)6 * 128 * 128;
    int* ip = (int*)(b + bo);
    size_t io = 0;
    int* rowptr0 = ip + io; io += (size_t)3 * (NN + 1);
    int* csrc0   = ip + io; io += (size_t)3 * EE;
    int* deg     = ip + io; io += NN;
    int* cursor  = ip + io; io += NN;
    int* scanned = ip + io; io += NN;
    int* bsum    = ip + io; io += 128;
    int* gstart  = ip + io; io += GG + 1;
    const size_t need = fo * 4 + bo * 2 + io * 4;
    if (ws_size < need) return;

    const int NBLK_SCAN = (NN + 511) / 512;

    // ---- weight transpose+split (K padded to x64) ----
    {
        int t;
        t = 3 * 128 * 1280;
        wt_cast2<<<(t + 255) / 256, 256, 0, stream>>>(conv1_W1, c1_hi, c1_lo, t, FIN, 1280);
        t = 15 * 128 * 128;
        wt_cast2<<<(t + 255) / 256, 256, 0, stream>>>(conv_rest_W1, rw1_hi, rw1_lo, t, 128, 128);
        t = 18 * 128 * 128;
        wt_cast2<<<(t + 255) / 256, 256, 0, stream>>>(conv_W2, w2_hi, w2_lo, t, 128, 128);
        t = 6 * 128 * 384;
        wt_cast2<<<(t + 255) / 256, 256, 0, stream>>>(mlp_W1, mw1_hi, mw1_lo, t, 384, 384);
        t = 6 * 128 * 128;
        wt_cast2<<<(t + 255) / 256, 256, 0, stream>>>(mlp_W2, mw2_hi, mw2_lo, t, 128, 128);
    }

    // ---- CSR build for the 3 edge sets ----
    for (int s = 0; s < 3; ++s) {
        int* rowptr = rowptr0 + (size_t)s * (NN + 1);
        int* csrc   = csrc0 + (size_t)s * EE;
        hipMemsetAsync(deg, 0, NN * sizeof(int), stream);
        count_deg<<<(EE + 255) / 256, 256, 0, stream>>>(eidx[s] + EE, deg);
        scan1<<<NBLK_SCAN, 512, 0, stream>>>(deg, scanned, bsum);
        scan2<<<1, 128, 0, stream>>>(bsum, NBLK_SCAN);
        scan3<<<(NN + 255) / 256, 256, 0, stream>>>(deg, scanned, bsum, rowptr, cursor);
        fill_csr<<<(EE + 255) / 256, 256, 0, stream>>>(eidx[s], eidx[s] + EE, cursor, csrc);
    }
    seg_starts<<<(NN + 255) / 256, 256, 0, stream>>>(batch, gstart);
    hipMemsetAsync(stats, 0, 48 * 256 * sizeof(float), stream);
    hipMemsetAsync(S, 0, (size_t)GG * 384 * sizeof(float), stream);
    hipMemsetAsync(ccb, 0, (size_t)GG * 128 * sizeof(float), stream);

    const int G128 = (NN + 127) / 128;                 // 391 row tiles
    const int G3   = 24 * ((G128 + 7) / 8);            // 1176 (triplet remap grid)
    const int AGG_GRID = NN / 16;                      // 3125 x-blocks

    // ---- 6 GIN layers ----
    for (int l = 0; l < 6; ++l) {
        float* stL    = stats + (size_t)l * 8 * 256;
        float* slotF1 = stL + 6 * 256;
        float* slotF2 = stL + 7 * 256;
        float* mlp1in  = (l == 0) ? X : sb;     // [NN][384] W2 outputs
        float* mlp1out = (l == 0) ? sb : X;     // [NN][128] compact

        if (l == 0) {
            // proj-first: X[:, k*128..] = x @ W1_k
            gemm_l0<<<G3, 256, 0, stream>>>(
                x, FIN, 1280, FIN, c1_hi, c1_lo, (size_t)128 * 1280,
                X, 384, 128, NN, G128);
            // z_k = (1+eps)proj + agg + b1 (stats -> slots 0/2/4)
            agg_combine<1><<<dim3(AGG_GRID, 3), 256, 0, stream>>>(
                X, 96, rowptr0, csrc0, conv1_b1,
                nullptr, nullptr, nullptr, conv_eps, 0, sb, stL);
            // W2: X[:, k*128..] = BN1(z_k) @ W2_k + b2 (stats -> slots 1/3/5)
            gemm_dir<1><<<G3, 256, 0, stream>>>(
                sb, (size_t)NN * 128, 128, 128,
                stL, 0, 512,
                conv_bn1_g + l * 3 * 128, conv_bn1_b + l * 3 * 128, 0, 128,
                w2_hi + (size_t)l * 3 * 128 * 128,
                w2_lo + (size_t)l * 3 * 128 * 128, (size_t)128 * 128,
                conv_b2 + l * 3 * 128, 128,
                X, 384, 128, NN, 1, stL + 256, 512, 3, G128);
        } else {
            // agg-first on SHARED h = relu(bn(zm2)) computed on the fly
            agg_combine<0><<<dim3(AGG_GRID, 3), 256, 0, stream>>>(
                zm2, 32, rowptr0, csrc0, nullptr,
                stats + (size_t)((l - 1) * 8 + 7) * 256,
                mlp_bn2_g + (l - 1) * 128, mlp_bn2_b + (l - 1) * 128,
                conv_eps, l * 3, sb, nullptr);
            // W1: X[:, k*128..] = sb_k @ W1_k + b1 (raw A; stats -> slots 0/2/4)
            gemm_dir<0><<<G3, 256, 0, stream>>>(
                sb, (size_t)NN * 128, 128, 128,
                nullptr, 0, 0, nullptr, nullptr, 0, 0,
                rw1_hi + (size_t)(l - 1) * 3 * 128 * 128,
                rw1_lo + (size_t)(l - 1) * 3 * 128 * 128, (size_t)128 * 128,
                conv_rest_b1 + (l - 1) * 3 * 128, 128,
                X, 384, 128, NN, 1, stL, 512, 3, G128);
            // W2: sb[:, k*128..] = BN1(X slice k) @ W2_k + b2 (stats -> 1/3/5)
            gemm_dir<1><<<G3, 256, 0, stream>>>(
                X, 128, 384, 128,
                stL, 0, 512,
                conv_bn1_g + l * 3 * 128, conv_bn1_b + l * 3 * 128, 0, 128,
                w2_hi + (size_t)l * 3 * 128 * 128,
                w2_lo + (size_t)l * 3 * 128 * 128, (size_t)128 * 128,
                conv_b2 + l * 3 * 128, 128,
                sb, 384, 128, NN, 1, stL + 256, 512, 3, G128);
        }

        // fusion MLP layer 1: BN2(3 slices) @ mlp_W1 -> mlp1out (compact 128)
        gemm_dir<1><<<G128, 256, 0, stream>>>(
            mlp1in, 0, 384, 384,
            stL + 256, 512, 0,
            conv_bn2_g + l * 3 * 128, conv_bn2_b + l * 3 * 128, 128, 0,
            mw1_hi + (size_t)l * 128 * 384, mw1_lo + (size_t)l * 128 * 384, 0,
            mlp_b1 + l * 128, 0, mlp1out, 128, 0, NN, 1, slotF1, 0, 1, G128);

        // fusion MLP layer 2: BN(mlp1out) @ mlp_W2 -> zm2
        gemm_dir<1><<<G128, 256, 0, stream>>>(
            mlp1out, 0, 128, 128,
            slotF1, 0, 0,
            mlp_bn1_g + l * 128, mlp_bn1_b + l * 128, 0, 0,
            mw2_hi + (size_t)l * 128 * 128, mw2_lo + (size_t)l * 128 * 128, 0,
            mlp_b2 + l * 128, 0, zm2, 128, 0, NN, 1, slotF2, 0, 1, G128);
    }
    // final h = bn_relu(zm2, layer-5 F2 stats) -> X (compact [NN][128])
    bn_relu_f32<<<(NN * 64 + 255) / 256, 256, 0, stream>>>(
        zm2, stats + (size_t)(5 * 8 + 7) * 256,
        mlp_bn2_g + 5 * 128, mlp_bn2_b + 5 * 128, X);

    // ---- Set2Set readout (fp32) ----
    pack_wcat<<<(512 * 384 + 255) / 256, 256, 0, stream>>>(lstm_Wih, lstm_Whh, Wcat);
    for (int t = 0; t < 6; ++t) {
        gemm_f32<true><<<dim3(8, 4), 256, 0, stream>>>(
            S, Wcat, nullptr, gates, GG, 384, 512);
        lstm_kernel<<<(GG * 128 + 255) / 256, 256, 0, stream>>>(
            gates, lstm_bih, lstm_bhh, ccb, S);
        attend_kernel<<<GG, 256, 0, stream>>>(X, S, ews, gstart);
    }
    fc1_kernel<<<GG, 128, 0, stream>>>(S, fc1_W, fc1_b, gates);
    fc4_kernel<<<(GG * 12 + 255) / 256, 256, 0, stream>>>(gates, fc4_W, fc4_b, outp);
}

// Round 13
// 4542.285 us; speedup vs baseline: 1.3354x; 1.1000x over previous
//
#include <hip/hip_runtime.h>
#include <hip/hip_fp16.h>
#include <cstdint>
#include <cstddef>

#define NN 50000
#define EE 1600000
#define GG 512
#define FIN 1273

typedef unsigned short u16;
typedef unsigned int u32;
typedef __attribute__((ext_vector_type(8))) short short8;
typedef __attribute__((ext_vector_type(4))) float f32x4;

__device__ __forceinline__ float sigmf(float x) { return 1.f / (1.f + expf(-x)); }

// truncation split: v == hi + rem exactly; lo = bf16(rem); |v-(hi+lo)| <= 2^-16 |v|
__device__ __forceinline__ void splitbf(float v, u16& hi, u16& lo) {
    const u32 u = __float_as_uint(v);
    hi = (u16)(u >> 16);
    const float rem = v - __uint_as_float(u & 0xffff0000u);
    lo = (u16)(__float_as_uint(rem) >> 16);
}

__device__ __forceinline__ void gload_lds16(const void* g, void* l) {
    __builtin_amdgcn_global_load_lds(
        (const __attribute__((address_space(1))) void*)g,
        (__attribute__((address_space(3))) void*)l, 16, 0, 0);
}

// XCD-aware triplet remap: put the 3 mats of one row tile on the same XCD.
__device__ __forceinline__ bool remap3(int f, int nRow, int& mat, int& rt) {
    const int g = f / 24, w = f - g * 24;
    rt = g * 8 + (w & 7);
    mat = w >> 3;
    return rt < nRow;
}

// ===== layer-0 GEMM: split-bf16 MFMA, A = fp32 x staged via LDS ================
__global__ __launch_bounds__(256) void gemm_l0(
    const float* __restrict__ A, int lda, int K, int Kreal,
    const u16* __restrict__ Bhi, const u16* __restrict__ Blo, size_t strideB,
    float* __restrict__ C, int ldc, int coffStep, int M, int nRow)
{
    __shared__ u16 lsAhi[128 * 64];
    __shared__ u16 lsAlo[128 * 64];
    __shared__ u16 lsBhi[128 * 64];
    __shared__ u16 lsBlo[128 * 64];
    int mat, rt;
    if (!remap3(blockIdx.x, nRow, mat, rt)) return;
    const int tid = threadIdx.x;
    const int wave = tid >> 6, lane = tid & 63;
    const int row0 = rt * 128;
    const int coff = mat * coffStep;
    const u16* Bh = Bhi + (size_t)mat * strideB;
    const u16* Bl = Blo + (size_t)mat * strideB;
    const int wm = wave >> 1, wn = wave & 1;
    f32x4 acc[4][4] = {};

    for (int k0 = 0; k0 < K; k0 += 64) {
        if (k0) __syncthreads();
        #pragma unroll
        for (int i = 0; i < 4; ++i) {
            const int slot = i * 256 + tid;
            const int r = slot >> 3, ch = tid & 7;
            int gr = row0 + r; if (gr >= M) gr = M - 1;
            const int kb = k0 + ch * 8;
            u16 th[8], tl[8];
            const float* src = A + (size_t)gr * lda + kb;
            if (kb + 8 <= Kreal) {
                const float4 v0 = *(const float4*)(src);
                const float4 v1 = *(const float4*)(src + 4);
                const float va[8] = {v0.x, v0.y, v0.z, v0.w,
                                     v1.x, v1.y, v1.z, v1.w};
                #pragma unroll
                for (int e = 0; e < 8; ++e) splitbf(va[e], th[e], tl[e]);
            } else {
                #pragma unroll
                for (int e = 0; e < 8; ++e) {
                    const float v = (kb + e < Kreal) ? src[e] : 0.f;
                    splitbf(v, th[e], tl[e]);
                }
            }
            const int off = (r << 6) + ((ch ^ (r & 7)) << 3);
            *(short8*)&lsAhi[off] = *(const short8*)th;
            *(short8*)&lsAlo[off] = *(const short8*)tl;
        }
        #pragma unroll
        for (int i = 0; i < 4; ++i) {
            const int slot = i * 256 + wave * 64 + lane;
            const int r = slot >> 3, ch = slot & 7;
            const int sch = ch ^ (r & 7);
            const size_t goff = (size_t)r * K + k0 + sch * 8;
            const int lbase = (i * 256 + wave * 64) * 8;
            gload_lds16(Bh + goff, &lsBhi[lbase]);
            gload_lds16(Bl + goff, &lsBlo[lbase]);
        }
        __syncthreads();
        #pragma unroll
        for (int ks = 0; ks < 2; ++ks) {
            short8 ah[4], al[4], bh[4], bl[4];
            const int kch = ks * 4 + (lane >> 4);
            #pragma unroll
            for (int m = 0; m < 4; ++m) {
                const int r = wm * 64 + m * 16 + (lane & 15);
                const int off = (r << 6) + ((kch ^ (r & 7)) << 3);
                ah[m] = *(const short8*)&lsAhi[off];
                al[m] = *(const short8*)&lsAlo[off];
            }
            #pragma unroll
            for (int n = 0; n < 4; ++n) {
                const int c = wn * 64 + n * 16 + (lane & 15);
                const int off = (c << 6) + ((kch ^ (c & 7)) << 3);
                bh[n] = *(const short8*)&lsBhi[off];
                bl[n] = *(const short8*)&lsBlo[off];
            }
            #pragma unroll
            for (int m = 0; m < 4; ++m)
                #pragma unroll
                for (int n = 0; n < 4; ++n) {
                    acc[m][n] = __builtin_amdgcn_mfma_f32_16x16x32_bf16(
                        ah[m], bh[n], acc[m][n], 0, 0, 0);
                    acc[m][n] = __builtin_amdgcn_mfma_f32_16x16x32_bf16(
                        ah[m], bl[n], acc[m][n], 0, 0, 0);
                    acc[m][n] = __builtin_amdgcn_mfma_f32_16x16x32_bf16(
                        al[m], bh[n], acc[m][n], 0, 0, 0);
                }
        }
    }
    #pragma unroll
    for (int n = 0; n < 4; ++n) {
        const int c = wn * 64 + n * 16 + (lane & 15);
        #pragma unroll
        for (int m = 0; m < 4; ++m) {
            #pragma unroll
            for (int j = 0; j < 4; ++j) {
                const int gr = row0 + wm * 64 + m * 16 + ((lane >> 4) << 2) + j;
                if (gr < M)
                    C[(size_t)gr * ldc + coff + c] = acc[m][n][j];
            }
        }
    }
}

// ===== direct-A GEMM: A fp32 from global (no A LDS) ============================
template <int ABN>
__global__ __launch_bounds__(256) void gemm_dir(
    const float* __restrict__ A, size_t strideA, int lda, int K,
    const float* __restrict__ st, int stSlice, int stMat,
    const float* __restrict__ ga, const float* __restrict__ be,
    int gbSlice, int gbMat,
    const u16* __restrict__ Bhi, const u16* __restrict__ Blo, size_t strideB,
    const float* __restrict__ bias, int biasMat,
    float* __restrict__ C, int ldc, int coffStep,
    int M, int do_stats, float* __restrict__ stats_out, int ostatMat,
    int nMat, int nRow)
{
    __shared__ u16 lsBhi[128 * 64];
    __shared__ u16 lsBlo[128 * 64];
    int mat, rt;
    if (nMat == 3) {
        if (!remap3(blockIdx.x, nRow, mat, rt)) return;
    } else { mat = 0; rt = blockIdx.x; }
    const int tid = threadIdx.x;
    const int wave = tid >> 6, lane = tid & 63;
    const int row0 = rt * 128;
    const int wm = wave >> 1, wn = wave & 1;
    A += (size_t)mat * strideA;
    if (ABN) { st += mat * stMat; ga += mat * gbMat; be += mat * gbMat; }
    if (bias) bias += mat * biasMat;
    if (do_stats) stats_out += mat * ostatMat;
    const u16* Bh = Bhi + (size_t)mat * strideB;
    const u16* Bl = Blo + (size_t)mat * strideB;
    const int coff = mat * coffStep;
    f32x4 acc[4][4] = {};

    int arow[4];
    #pragma unroll
    for (int m = 0; m < 4; ++m) {
        int r = row0 + wm * 64 + m * 16 + (lane & 15);
        if (r >= M) r = M - 1;
        arow[m] = r;
    }

    for (int k0 = 0; k0 < K; k0 += 64) {
        if (k0) __syncthreads();
        #pragma unroll
        for (int i = 0; i < 4; ++i) {
            const int slot = i * 256 + wave * 64 + lane;
            const int r = slot >> 3, ch = slot & 7;
            const int sch = ch ^ (r & 7);
            const size_t goff = (size_t)r * K + k0 + sch * 8;
            const int lbase = (i * 256 + wave * 64) * 8;
            gload_lds16(Bh + goff, &lsBhi[lbase]);
            gload_lds16(Bl + goff, &lsBlo[lbase]);
        }
        __syncthreads();
        #pragma unroll
        for (int ks = 0; ks < 2; ++ks) {
            const int kch = ks * 4 + (lane >> 4);
            const int kb = k0 + kch * 8;
            float scv[8], shv[8];
            if (ABN) {
                const int s = kb >> 7, d0 = kb & 127;
                const float* stS = st + s * stSlice;
                const float* gS  = ga + s * gbSlice;
                const float* beS = be + s * gbSlice;
                #pragma unroll
                for (int e = 0; e < 8; ++e) {
                    const int d = d0 + e;
                    const float mu = stS[d] * (1.f / NN);
                    const float var = fmaxf(stS[128 + d] * (1.f / NN) - mu * mu, 0.f);
                    const float sc = gS[d] * rsqrtf(var + 1e-5f);
                    scv[e] = sc;
                    shv[e] = beS[d] - sc * mu;
                }
            }
            short8 ah[4], al[4];
            #pragma unroll
            for (int m = 0; m < 4; ++m) {
                const float* src = A + (size_t)arow[m] * lda + kb;
                const float4 v0 = *(const float4*)(src);
                const float4 v1 = *(const float4*)(src + 4);
                const float va[8] = {v0.x, v0.y, v0.z, v0.w,
                                     v1.x, v1.y, v1.z, v1.w};
                u16 th[8], tl[8];
                #pragma unroll
                for (int e = 0; e < 8; ++e) {
                    const float y = ABN
                        ? fmaxf(fmaf(scv[e], va[e], shv[e]), 0.f) : va[e];
                    splitbf(y, th[e], tl[e]);
                }
                ah[m] = *(const short8*)th;
                al[m] = *(const short8*)tl;
            }
            #pragma unroll
            for (int n = 0; n < 4; ++n) {
                const int c = wn * 64 + n * 16 + (lane & 15);
                const int off = (c << 6) + ((kch ^ (c & 7)) << 3);
                const short8 bh = *(const short8*)&lsBhi[off];
                const short8 bl = *(const short8*)&lsBlo[off];
                #pragma unroll
                for (int m = 0; m < 4; ++m) {
                    acc[m][n] = __builtin_amdgcn_mfma_f32_16x16x32_bf16(
                        ah[m], bh, acc[m][n], 0, 0, 0);
                    acc[m][n] = __builtin_amdgcn_mfma_f32_16x16x32_bf16(
                        ah[m], bl, acc[m][n], 0, 0, 0);
                    acc[m][n] = __builtin_amdgcn_mfma_f32_16x16x32_bf16(
                        al[m], bh, acc[m][n], 0, 0, 0);
                }
            }
        }
    }

    float colsum[4] = {0.f, 0.f, 0.f, 0.f}, colsq[4] = {0.f, 0.f, 0.f, 0.f};
    #pragma unroll
    for (int n = 0; n < 4; ++n) {
        const int c = wn * 64 + n * 16 + (lane & 15);
        const float bv = bias ? bias[c] : 0.f;
        #pragma unroll
        for (int m = 0; m < 4; ++m) {
            #pragma unroll
            for (int j = 0; j < 4; ++j) {
                const int gr = row0 + wm * 64 + m * 16 + ((lane >> 4) << 2) + j;
                if (gr < M) {
                    const float v = acc[m][n][j] + bv;
                    C[(size_t)gr * ldc + coff + c] = v;
                    colsum[n] += v; colsq[n] += v * v;
                }
            }
        }
    }
    if (do_stats) {
        float* ssum = (float*)lsBhi;
        float* ssq  = ssum + 128;
        __syncthreads();
        if (tid < 128) { ssum[tid] = 0.f; ssq[tid] = 0.f; }
        __syncthreads();
        #pragma unroll
        for (int n = 0; n < 4; ++n) {
            const int c = wn * 64 + n * 16 + (lane & 15);
            atomicAdd(&ssum[c], colsum[n]);
            atomicAdd(&ssq[c], colsq[n]);
        }
        __syncthreads();
        if (tid < 128) {
            atomicAdd(&stats_out[tid],       ssum[tid]);
            atomicAdd(&stats_out[128 + tid], ssq[tid]);
        }
    }
}

// ------ weight transpose+split: W[nmat][K][128] -> Whi/Wlo[nmat][128][Kpad] ----
__global__ __launch_bounds__(256) void wt_cast2(const float* __restrict__ W,
                                                u16* __restrict__ Whi,
                                                u16* __restrict__ Wlo,
                                                int total, int K, int Kpad) {
    const int idx = blockIdx.x * 256 + threadIdx.x;
    if (idx >= total) return;
    const int perm = 128 * Kpad;
    const int m = idx / perm, rem = idx - m * perm;
    const int n = rem / Kpad, k = rem - n * Kpad;
    const float v = (k < K) ? W[(size_t)m * K * 128 + (size_t)k * 128 + n] : 0.f;
    u16 hi, lo;
    splitbf(v, hi, lo);
    Whi[idx] = hi; Wlo[idx] = lo;
}

// ---------------- fp32 tiled GEMM (LSTM gates only) ----------------------------
template <bool BT>
__global__ __launch_bounds__(256) void gemm_f32(
    const float* __restrict__ A, const float* __restrict__ B,
    const float* __restrict__ bias, float* __restrict__ C,
    int M, int K, int Nc)
{
    __shared__ float As[32][68];
    __shared__ float Bs[32][132];
    const int tid = threadIdx.x;
    const int tx = tid & 15, ty = tid >> 4;
    const int row0 = blockIdx.x * 64, col0 = blockIdx.y * 128;
    float acc[4][8] = {};
    for (int k0 = 0; k0 < K; k0 += 32) {
        {
            const int kk = tid & 31, rb = tid >> 5;
            #pragma unroll
            for (int i = 0; i < 8; ++i) {
                const int r = rb + i * 8, gr = row0 + r, gk = k0 + kk;
                As[kk][r] = (gr < M && gk < K) ? A[(size_t)gr * K + gk] : 0.f;
            }
        }
        if (!BT) {
            const int c = tid & 127, kb = tid >> 7;
            #pragma unroll
            for (int i = 0; i < 16; ++i) {
                const int kk = kb + i * 2, gk = k0 + kk;
                Bs[kk][c] = (gk < K) ? B[(size_t)gk * Nc + col0 + c] : 0.f;
            }
        } else {
            const int kk = tid & 31, cb = tid >> 5;
            #pragma unroll
            for (int i = 0; i < 16; ++i) {
                const int c = cb + i * 8, gk = k0 + kk;
                Bs[kk][c] = (gk < K) ? B[(size_t)(col0 + c) * K + gk] : 0.f;
            }
        }
        __syncthreads();
        #pragma unroll 8
        for (int kk = 0; kk < 32; ++kk) {
            const float4 av  = *(const float4*)&As[kk][ty * 4];
            const float4 bv0 = *(const float4*)&Bs[kk][tx * 8];
            const float4 bv1 = *(const float4*)&Bs[kk][tx * 8 + 4];
            const float a[4] = {av.x, av.y, av.z, av.w};
            const float b[8] = {bv0.x, bv0.y, bv0.z, bv0.w, bv1.x, bv1.y, bv1.z, bv1.w};
            #pragma unroll
            for (int i = 0; i < 4; ++i)
                #pragma unroll
                for (int j = 0; j < 8; ++j)
                    acc[i][j] = fmaf(a[i], b[j], acc[i][j]);
        }
        __syncthreads();
    }
    #pragma unroll
    for (int j = 0; j < 8; ++j) {
        const float bv = bias ? bias[col0 + tx * 8 + j] : 0.f;
        #pragma unroll
        for (int i = 0; i < 4; ++i) acc[i][j] += bv;
    }
    #pragma unroll
    for (int i = 0; i < 4; ++i) {
        const int gr = row0 + ty * 4 + i;
        if (gr < M) {
            *(float4*)&C[(size_t)gr * Nc + col0 + tx * 8] =
                make_float4(acc[i][0], acc[i][1], acc[i][2], acc[i][3]);
            *(float4*)&C[(size_t)gr * Nc + col0 + tx * 8 + 4] =
                make_float4(acc[i][4], acc[i][5], acc[i][6], acc[i][7]);
        }
    }
}

// ---------------- CSR build (counting sort by destination) ---------------------
__global__ __launch_bounds__(256) void count_deg(const int* __restrict__ dst,
                                                 int* __restrict__ deg) {
    const int e = blockIdx.x * 256 + threadIdx.x;
    if (e < EE) atomicAdd(&deg[dst[e]], 1);
}

__global__ __launch_bounds__(512) void scan1(const int* __restrict__ deg,
                                             int* __restrict__ scanned,
                                             int* __restrict__ bsum) {
    __shared__ int s[512];
    const int t = threadIdx.x;
    const int i = blockIdx.x * 512 + t;
    const int v = (i < NN) ? deg[i] : 0;
    s[t] = v; __syncthreads();
    for (int o = 1; o < 512; o <<= 1) {
        const int tv = (t >= o) ? s[t - o] : 0;
        __syncthreads();
        s[t] += tv;
        __syncthreads();
    }
    if (i < NN) scanned[i] = s[t];
    if (t == 511) bsum[blockIdx.x] = s[511];
}

__global__ __launch_bounds__(128) void scan2(int* __restrict__ bsum, int nb) {
    __shared__ int s[128];
    const int t = threadIdx.x;
    const int v = (t < nb) ? bsum[t] : 0;
    s[t] = v; __syncthreads();
    for (int o = 1; o < 128; o <<= 1) {
        const int tv = (t >= o) ? s[t - o] : 0;
        __syncthreads();
        s[t] += tv;
        __syncthreads();
    }
    if (t < nb) bsum[t] = s[t] - v;  // exclusive
}

__global__ __launch_bounds__(256) void scan3(const int* __restrict__ deg,
                                             const int* __restrict__ scanned,
                                             const int* __restrict__ bsum,
                                             int* __restrict__ rowptr,
                                             int* __restrict__ cursor) {
    const int i = blockIdx.x * 256 + threadIdx.x;
    if (i < NN) {
        const int v = bsum[i >> 9] + scanned[i] - deg[i];
        rowptr[i] = v; cursor[i] = v;
    }
    if (i == 0) rowptr[NN] = EE;
}

__global__ __launch_bounds__(256) void fill_csr(const int* __restrict__ src,
                                                const int* __restrict__ dst,
                                                int* __restrict__ cursor,
                                                int* __restrict__ csrc) {
    const int e = blockIdx.x * 256 + threadIdx.x;
    if (e < EE) {
        const int pos = atomicAdd(&cursor[dst[e]], 1);
        csrc[pos] = src[e];
    }
}

// ==== layer-0 fused aggregate + combine (fp32 gather, 3 edge sets) =============
__global__ __launch_bounds__(256) void agg_combine(
    const float* __restrict__ X, int ldp4,
    const int* __restrict__ rowptrB, const int* __restrict__ csrcB,
    const float* __restrict__ b1B,
    const float* __restrict__ eps_arr, int epsBase,
    float* __restrict__ zB, float* __restrict__ statsB)
{
    __shared__ float red[256];
    const int k = blockIdx.y;
    const int* rowptr = rowptrB + (size_t)k * (NN + 1);
    const int* csrc   = csrcB + (size_t)k * EE;
    float* z          = zB + (size_t)k * NN * 128;
    const int tid = threadIdx.x, lane = tid & 63, wave = tid >> 6;
    const float e1 = 1.f + eps_arr[epsBase + k];
    const int half = lane >> 5;
    const int l32 = lane & 31;
    const float4* p4 = (const float4*)X + k * 32;
    float s[4] = {0.f, 0.f, 0.f, 0.f}, q[4] = {0.f, 0.f, 0.f, 0.f};
    float4 bv = make_float4(0.f, 0.f, 0.f, 0.f);
    if (lane < 32) bv = ((const float4*)(b1B + k * 128))[l32];
    red[tid] = 0.f;
    __syncthreads();
    const int nbase = blockIdx.x * 16 + wave * 4;
    for (int t = 0; t < 4; ++t) {
        const int wid = nbase + t;
        const int s0 = rowptr[wid], s1 = rowptr[wid + 1];
        float ax = 0.f, ay = 0.f, az = 0.f, aw = 0.f;
        int j = s0;
        for (; j + 15 < s1; j += 16) {
            float4 v[8];
            #pragma unroll
            for (int u = 0; u < 8; ++u)
                v[u] = p4[(size_t)csrc[j + 2 * u + half] * ldp4 + l32];
            #pragma unroll
            for (int u = 0; u < 8; ++u) {
                ax += v[u].x; ay += v[u].y; az += v[u].z; aw += v[u].w;
            }
        }
        for (; j + 7 < s1; j += 8) {
            float4 v[4];
            #pragma unroll
            for (int u = 0; u < 4; ++u)
                v[u] = p4[(size_t)csrc[j + 2 * u + half] * ldp4 + l32];
            #pragma unroll
            for (int u = 0; u < 4; ++u) {
                ax += v[u].x; ay += v[u].y; az += v[u].z; aw += v[u].w;
            }
        }
        for (; j + 3 < s1; j += 4) {
            const float4 v0 = p4[(size_t)csrc[j + half] * ldp4 + l32];
            const float4 v1 = p4[(size_t)csrc[j + 2 + half] * ldp4 + l32];
            ax += v0.x + v1.x; ay += v0.y + v1.y;
            az += v0.z + v1.z; aw += v0.w + v1.w;
        }
        for (; j + 1 < s1; j += 2) {
            const float4 v0 = p4[(size_t)csrc[j + half] * ldp4 + l32];
            ax += v0.x; ay += v0.y; az += v0.z; aw += v0.w;
        }
        if (j < s1 && half == 0) {
            const float4 v0 = p4[(size_t)csrc[j] * ldp4 + l32];
            ax += v0.x; ay += v0.y; az += v0.z; aw += v0.w;
        }
        ax += __shfl_down(ax, 32, 64);
        ay += __shfl_down(ay, 32, 64);
        az += __shfl_down(az, 32, 64);
        aw += __shfl_down(aw, 32, 64);
        if (lane < 32) {
            const float4 self = p4[(size_t)wid * ldp4 + l32];
            float4 zv;
            zv.x = fmaf(e1, self.x, ax + bv.x);
            zv.y = fmaf(e1, self.y, ay + bv.y);
            zv.z = fmaf(e1, self.z, az + bv.z);
            zv.w = fmaf(e1, self.w, aw + bv.w);
            ((float4*)z)[(size_t)wid * 32 + l32] = zv;
            s[0] += zv.x; s[1] += zv.y; s[2] += zv.z; s[3] += zv.w;
            q[0] += zv.x * zv.x; q[1] += zv.y * zv.y;
            q[2] += zv.z * zv.z; q[3] += zv.w * zv.w;
        }
    }
    if (lane < 32) {
        const int d = l32 * 4;
        #pragma unroll
        for (int c = 0; c < 4; ++c) {
            atomicAdd(&red[d + c], s[c]);
            atomicAdd(&red[128 + d + c], q[c]);
        }
    }
    __syncthreads();
    atomicAdd(&statsB[(size_t)k * 512 + tid], red[tid]);
}

// ==== l>=1 aggregate + combine over fp16 h rows (half the gather bytes) ========
// Hh = fp16[NN][128] viewed as u32[NN][64]; each lane owns cols 2l/2l+1 of a
// full row -> no cross-lane reduce. sb_k = (1+eps_k)*h_self + sum h_neighbors.
__global__ __launch_bounds__(256) void agg_h(
    const u16* __restrict__ Hh,
    const int* __restrict__ rowptrB, const int* __restrict__ csrcB,
    const float* __restrict__ eps_arr, int epsBase,
    float* __restrict__ zB)
{
    const int k = blockIdx.y;
    const int* rowptr = rowptrB + (size_t)k * (NN + 1);
    const int* csrc   = csrcB + (size_t)k * EE;
    float* z          = zB + (size_t)k * NN * 128;
    const int tid = threadIdx.x, lane = tid & 63, wave = tid >> 6;
    const float e1 = 1.f + eps_arr[epsBase + k];
    const u32* p = (const u32*)Hh;   // [NN][64]
    const int nbase = blockIdx.x * 16 + wave * 4;
    #pragma unroll
    for (int t = 0; t < 4; ++t) {
        const int wid = nbase + t;
        const int s0 = rowptr[wid], s1 = rowptr[wid + 1];
        float ax = 0.f, ay = 0.f;
        int j = s0;
        for (; j + 15 < s1; j += 16) {
            u32 v[16];
            #pragma unroll
            for (int u = 0; u < 16; ++u)
                v[u] = p[(size_t)csrc[j + u] * 64 + lane];
            #pragma unroll
            for (int u = 0; u < 16; ++u) {
                const float2 fv = __half22float2(*(const __half2*)&v[u]);
                ax += fv.x; ay += fv.y;
            }
        }
        for (; j + 7 < s1; j += 8) {
            u32 v[8];
            #pragma unroll
            for (int u = 0; u < 8; ++u)
                v[u] = p[(size_t)csrc[j + u] * 64 + lane];
            #pragma unroll
            for (int u = 0; u < 8; ++u) {
                const float2 fv = __half22float2(*(const __half2*)&v[u]);
                ax += fv.x; ay += fv.y;
            }
        }
        for (; j < s1; ++j) {
            const u32 v = p[(size_t)csrc[j] * 64 + lane];
            const float2 fv = __half22float2(*(const __half2*)&v);
            ax += fv.x; ay += fv.y;
        }
        const u32 sv = p[(size_t)wid * 64 + lane];
        const float2 sf = __half22float2(*(const __half2*)&sv);
        float2 zv;
        zv.x = fmaf(e1, sf.x, ax);
        zv.y = fmaf(e1, sf.y, ay);
        ((float2*)z)[(size_t)wid * 64 + lane] = zv;
    }
}

// ------- BN + ReLU -> fp16 rows for the gather ---------------------------------
__global__ __launch_bounds__(256) void bn_relu_h(
    const float* __restrict__ xin, const float* __restrict__ stats,
    const float* __restrict__ gamma, const float* __restrict__ beta,
    u16* __restrict__ out)
{
    const size_t i = (size_t)blockIdx.x * 256 + threadIdx.x;  // pair index
    if (i >= (size_t)NN * 64) return;
    const int d = (int)(i & 63) * 2;
    const float inv_n = 1.f / NN;
    const float mu0 = stats[d] * inv_n,     mu1 = stats[d + 1] * inv_n;
    const float v0 = fmaxf(stats[128 + d] * inv_n - mu0 * mu0, 0.f);
    const float v1 = fmaxf(stats[129 + d] * inv_n - mu1 * mu1, 0.f);
    const float s0 = gamma[d] * rsqrtf(v0 + 1e-5f);
    const float s1 = gamma[d + 1] * rsqrtf(v1 + 1e-5f);
    const float2 xv = ((const float2*)xin)[i];
    const float y0 = fmaxf(fmaf(s0, xv.x - mu0, beta[d]), 0.f);
    const float y1 = fmaxf(fmaf(s1, xv.y - mu1, beta[d + 1]), 0.f);
    const __half2 hv = __floats2half2_rn(y0, y1);
    ((u32*)out)[i] = *(const u32*)&hv;
}

// ------- BN + ReLU -> fp32 (final h only) --------------------------------------
__global__ __launch_bounds__(256) void bn_relu_f32(
    const float* __restrict__ xin, const float* __restrict__ stats,
    const float* __restrict__ gamma, const float* __restrict__ beta,
    float* __restrict__ out)
{
    const size_t i = (size_t)blockIdx.x * 256 + threadIdx.x;  // pair index
    if (i >= (size_t)NN * 64) return;
    const int d = (int)(i & 63) * 2;
    const float inv_n = 1.f / NN;
    const float mu0 = stats[d] * inv_n,     mu1 = stats[d + 1] * inv_n;
    const float v0 = fmaxf(stats[128 + d] * inv_n - mu0 * mu0, 0.f);
    const float v1 = fmaxf(stats[129 + d] * inv_n - mu1 * mu1, 0.f);
    const float s0 = gamma[d] * rsqrtf(v0 + 1e-5f);
    const float s1 = gamma[d + 1] * rsqrtf(v1 + 1e-5f);
    const float2 xv = ((const float2*)xin)[i];
    const float y0 = fmaxf(fmaf(s0, xv.x - mu0, beta[d]), 0.f);
    const float y1 = fmaxf(fmaf(s1, xv.y - mu1, beta[d + 1]), 0.f);
    ((float2*)out)[i] = make_float2(y0, y1);
}

// ---------------- per-graph segment starts (batch is sorted) -------------------
__global__ __launch_bounds__(256) void seg_starts(const int* __restrict__ batch,
                                                  int* __restrict__ gstart) {
    const int i = blockIdx.x * 256 + threadIdx.x;
    if (i >= NN) return;
    const int b = batch[i];
    if (i == 0) { for (int g = 0; g <= b; ++g) gstart[g] = 0; }
    else {
        const int pb = batch[i - 1];
        for (int g = pb + 1; g <= b; ++g) gstart[g] = i;
    }
    if (i == NN - 1) { for (int g = b + 1; g <= GG; ++g) gstart[g] = NN; }
}

// ---------------- Set2Set ------------------------------------------------------
__global__ __launch_bounds__(256) void pack_wcat(const float* __restrict__ Wih,
                                                 const float* __restrict__ Whh,
                                                 float* __restrict__ Wcat) {
    const int i = blockIdx.x * 256 + threadIdx.x;
    if (i >= 512 * 384) return;
    const int j = i / 384, k = i - j * 384;
    Wcat[i] = (k < 256) ? Wih[j * 256 + k] : Whh[j * 128 + (k - 256)];
}

__global__ __launch_bounds__(256) void lstm_kernel(
    const float* __restrict__ gates, const float* __restrict__ bih,
    const float* __restrict__ bhh, float* __restrict__ cc, float* __restrict__ S)
{
    const int i = blockIdx.x * 256 + threadIdx.x;
    if (i >= GG * 128) return;
    const int g = i >> 7, d = i & 127;
    const float* gr = gates + (size_t)g * 512;
    const float ig = gr[d]       + bih[d]       + bhh[d];
    const float fg = gr[128 + d] + bih[128 + d] + bhh[128 + d];
    const float gv = gr[256 + d] + bih[256 + d] + bhh[256 + d];
    const float og = gr[384 + d] + bih[384 + d] + bhh[384 + d];
    const float c  = sigmf(fg) * cc[i] + sigmf(ig) * tanhf(gv);
    const float hv = sigmf(og) * tanhf(c);
    cc[i] = c;
    S[(size_t)g * 384 + d] = hv;
    S[(size_t)g * 384 + 256 + d] = hv;
}

__global__ __launch_bounds__(256) void attend_kernel(
    const float* __restrict__ h, float* __restrict__ S,
    float* __restrict__ ews, const int* __restrict__ gstart)
{
    const int g = blockIdx.x;
    const int rs = gstart[g], re = gstart[g + 1];
    const int tid = threadIdx.x, lane = tid & 63, w = tid >> 6;
    __shared__ float q[128];
    __shared__ float red[8];
    if (tid < 128) q[tid] = S[(size_t)g * 384 + 256 + tid];
    __syncthreads();
    const float2* h2 = (const float2*)h;
    float lmax = -1e30f;
    for (int n = rs + w; n < re; n += 4) {
        const float2 hv = h2[(size_t)n * 64 + lane];
        float p = hv.x * q[2 * lane] + hv.y * q[2 * lane + 1];
        #pragma unroll
        for (int o = 32; o; o >>= 1) p += __shfl_down(p, o, 64);
        if (lane == 0) { ews[n] = p; lmax = fmaxf(lmax, p); }
    }
    if (lane == 0) red[w] = lmax;
    __syncthreads();
    const float m = fmaxf(fmaxf(red[0], red[1]), fmaxf(red[2], red[3]));
    __syncthreads();
    float lsum = 0.f;
    for (int n = rs + tid; n < re; n += 256) {
        const float ex = expf(ews[n] - m);
        ews[n] = ex; lsum += ex;
    }
    #pragma unroll
    for (int o = 32; o; o >>= 1) lsum += __shfl_down(lsum, o, 64);
    if (lane == 0) red[w] = lsum;
    __syncthreads();
    const float denom = red[0] + red[1] + red[2] + red[3];
    if (tid < 128) {
        float acc = 0.f;
        for (int n = rs; n < re; ++n)
            acc = fmaf(ews[n], h[(size_t)n * 128 + tid], acc);
        S[(size_t)g * 384 + 128 + tid] = (denom > 0.f) ? acc / denom : 0.f;
    }
}

__global__ __launch_bounds__(128) void fc1_kernel(const float* __restrict__ S,
                                                  const float* __restrict__ W,
                                                  const float* __restrict__ b,
                                                  float* __restrict__ out1) {
    const int g = blockIdx.x, d = threadIdx.x;
    __shared__ float qs[256];
    qs[d] = S[(size_t)g * 384 + d];
    qs[128 + d] = S[(size_t)g * 384 + 128 + d];
    __syncthreads();
    float acc = b[d];
    for (int k = 0; k < 256; ++k) acc = fmaf(qs[k], W[k * 128 + d], acc);
    out1[(size_t)g * 128 + d] = fmaxf(acc, 0.f);
}

__global__ __launch_bounds__(256) void fc4_kernel(const float* __restrict__ out1,
                                                  const float* __restrict__ W,
                                                  const float* __restrict__ b,
                                                  float* __restrict__ out) {
    const int i = blockIdx.x * 256 + threadIdx.x;
    if (i >= GG * 12) return;
    const int g = i / 12, j = i - g * 12;
    float acc = b[j];
    for (int d = 0; d < 128; ++d)
        acc = fmaf(out1[(size_t)g * 128 + d], W[d * 12 + j], acc);
    out[i] = acc;
}

// ================================================================================
extern "C" void kernel_launch(void* const* d_in, const int* in_sizes, int n_in,
                              void* d_out, int out_size, void* d_ws, size_t ws_size,
                              hipStream_t stream)
{
    const float* x        = (const float*)d_in[0];
    const int*   eidx[3]  = {(const int*)d_in[1], (const int*)d_in[2], (const int*)d_in[3]};
    const int*   batch    = (const int*)d_in[4];
    const float* conv1_W1     = (const float*)d_in[5];
    const float* conv1_b1     = (const float*)d_in[6];
    const float* conv_rest_W1 = (const float*)d_in[7];
    const float* conv_rest_b1 = (const float*)d_in[8];
    const float* conv_W2      = (const float*)d_in[9];
    const float* conv_b2      = (const float*)d_in[10];
    const float* conv_bn1_g   = (const float*)d_in[11];
    const float* conv_bn1_b   = (const float*)d_in[12];
    const float* conv_bn2_g   = (const float*)d_in[13];
    const float* conv_bn2_b   = (const float*)d_in[14];
    const float* conv_eps     = (const float*)d_in[15];
    const float* mlp_W1       = (const float*)d_in[16];
    const float* mlp_b1       = (const float*)d_in[17];
    const float* mlp_bn1_g    = (const float*)d_in[18];
    const float* mlp_bn1_b    = (const float*)d_in[19];
    const float* mlp_W2       = (const float*)d_in[20];
    const float* mlp_b2       = (const float*)d_in[21];
    const float* mlp_bn2_g    = (const float*)d_in[22];
    const float* mlp_bn2_b    = (const float*)d_in[23];
    const float* lstm_Wih     = (const float*)d_in[24];
    const float* lstm_Whh     = (const float*)d_in[25];
    const float* lstm_bih     = (const float*)d_in[26];
    const float* lstm_bhh     = (const float*)d_in[27];
    const float* fc1_W        = (const float*)d_in[28];
    const float* fc1_b        = (const float*)d_in[29];
    const float* fc4_W        = (const float*)d_in[30];
    const float* fc4_b        = (const float*)d_in[31];
    float* outp = (float*)d_out;

    // ---- workspace layout ----
    float* f = (float*)d_ws;
    size_t fo = 0;
    float* X     = f + fo; fo += (size_t)NN * 384;  // proj / z (l>=1) / mlp1-out / final h
    float* sb    = f + fo; fo += (size_t)NN * 384;  // agg out (stacked) / W2 out (l>=1)
    float* zm2   = f + fo; fo += (size_t)NN * 128;  // mlp2 out (layer state)
    float* ews   = f + fo; fo += NN;
    float* stats = f + fo; fo += 48 * 256;
    float* S     = f + fo; fo += (size_t)GG * 384;
    float* ccb   = f + fo; fo += (size_t)GG * 128;
    float* gates = f + fo; fo += (size_t)GG * 512;  // reused as fc1 output
    float* Wcat  = f + fo; fo += (size_t)512 * 384;
    fo = (fo + 7) & ~(size_t)7;   // 16B-align bf16 region
    u16* b = (u16*)(f + fo);
    size_t bo = 0;
    u16* h_h     = b + bo; bo += (size_t)NN * 128;  // fp16 h rows for the gather
    u16* c1_hi   = b + bo; bo += (size_t)3 * 128 * 1280;
    u16* c1_lo   = b + bo; bo += (size_t)3 * 128 * 1280;
    u16* rw1_hi  = b + bo; bo += (size_t)15 * 128 * 128;
    u16* rw1_lo  = b + bo; bo += (size_t)15 * 128 * 128;
    u16* w2_hi   = b + bo; bo += (size_t)18 * 128 * 128;
    u16* w2_lo   = b + bo; bo += (size_t)18 * 128 * 128;
    u16* mw1_hi  = b + bo; bo += (size_t)6 * 128 * 384;
    u16* mw1_lo  = b + bo; bo += (size_t)6 * 128 * 384;
    u16* mw2_hi  = b + bo; bo += (size_t)6 * 128 * 128;
    u16* mw2_lo  = b + bo; bo += (size_t)6 * 128 * 128;
    int* ip = (int*)(b + bo);
    size_t io = 0;
    int* rowptr0 = ip + io; io += (size_t)3 * (NN + 1);
    int* csrc0   = ip + io; io += (size_t)3 * EE;
    int* deg     = ip + io; io += NN;
    int* cursor  = ip + io; io += NN;
    int* scanned = ip + io; io += NN;
    int* bsum    = ip + io; io += 128;
    int* gstart  = ip + io; io += GG + 1;
    const size_t need = fo * 4 + bo * 2 + io * 4;
    if (ws_size < need) return;

    const int NBLK_SCAN = (NN + 511) / 512;

    // ---- weight transpose+split (K padded to x64) ----
    {
        int t;
        t = 3 * 128 * 1280;
        wt_cast2<<<(t + 255) / 256, 256, 0, stream>>>(conv1_W1, c1_hi, c1_lo, t, FIN, 1280);
        t = 15 * 128 * 128;
        wt_cast2<<<(t + 255) / 256, 256, 0, stream>>>(conv_rest_W1, rw1_hi, rw1_lo, t, 128, 128);
        t = 18 * 128 * 128;
        wt_cast2<<<(t + 255) / 256, 256, 0, stream>>>(conv_W2, w2_hi, w2_lo, t, 128, 128);
        t = 6 * 128 * 384;
        wt_cast2<<<(t + 255) / 256, 256, 0, stream>>>(mlp_W1, mw1_hi, mw1_lo, t, 384, 384);
        t = 6 * 128 * 128;
        wt_cast2<<<(t + 255) / 256, 256, 0, stream>>>(mlp_W2, mw2_hi, mw2_lo, t, 128, 128);
    }

    // ---- CSR build for the 3 edge sets ----
    for (int s = 0; s < 3; ++s) {
        int* rowptr = rowptr0 + (size_t)s * (NN + 1);
        int* csrc   = csrc0 + (size_t)s * EE;
        hipMemsetAsync(deg, 0, NN * sizeof(int), stream);
        count_deg<<<(EE + 255) / 256, 256, 0, stream>>>(eidx[s] + EE, deg);
        scan1<<<NBLK_SCAN, 512, 0, stream>>>(deg, scanned, bsum);
        scan2<<<1, 128, 0, stream>>>(bsum, NBLK_SCAN);
        scan3<<<(NN + 255) / 256, 256, 0, stream>>>(deg, scanned, bsum, rowptr, cursor);
        fill_csr<<<(EE + 255) / 256, 256, 0, stream>>>(eidx[s], eidx[s] + EE, cursor, csrc);
    }
    seg_starts<<<(NN + 255) / 256, 256, 0, stream>>>(batch, gstart);
    hipMemsetAsync(stats, 0, 48 * 256 * sizeof(float), stream);
    hipMemsetAsync(S, 0, (size_t)GG * 384 * sizeof(float), stream);
    hipMemsetAsync(ccb, 0, (size_t)GG * 128 * sizeof(float), stream);

    const int G128 = (NN + 127) / 128;                 // 391 row tiles
    const int G3   = 24 * ((G128 + 7) / 8);            // 1176 (triplet remap grid)
    const int AGG_GRID = NN / 16;                      // 3125 x-blocks
    const int BN_GRID = (NN * 64 + 255) / 256;

    // ---- 6 GIN layers ----
    for (int l = 0; l < 6; ++l) {
        float* stL    = stats + (size_t)l * 8 * 256;
        float* slotF1 = stL + 6 * 256;
        float* slotF2 = stL + 7 * 256;
        float* mlp1in  = (l == 0) ? X : sb;     // [NN][384] W2 outputs
        float* mlp1out = (l == 0) ? sb : X;     // [NN][128] compact

        if (l == 0) {
            // proj-first: X[:, k*128..] = x @ W1_k
            gemm_l0<<<G3, 256, 0, stream>>>(
                x, FIN, 1280, FIN, c1_hi, c1_lo, (size_t)128 * 1280,
                X, 384, 128, NN, G128);
            // z_k = (1+eps)proj + agg + b1 (fp32 gather; stats -> slots 0/2/4)
            agg_combine<<<dim3(AGG_GRID, 3), 256, 0, stream>>>(
                X, 96, rowptr0, csrc0, conv1_b1, conv_eps, 0, sb, stL);
            // W2: X[:, k*128..] = BN1(z_k) @ W2_k + b2 (stats -> slots 1/3/5)
            gemm_dir<1><<<G3, 256, 0, stream>>>(
                sb, (size_t)NN * 128, 128, 128,
                stL, 0, 512,
                conv_bn1_g + l * 3 * 128, conv_bn1_b + l * 3 * 128, 0, 128,
                w2_hi + (size_t)l * 3 * 128 * 128,
                w2_lo + (size_t)l * 3 * 128 * 128, (size_t)128 * 128,
                conv_b2 + l * 3 * 128, 128,
                X, 384, 128, NN, 1, stL + 256, 512, 3, G128);
        } else {
            // h_h = fp16_rne(relu(bn(zm2)))  (12.8 MB gather table)
            bn_relu_h<<<BN_GRID, 256, 0, stream>>>(
                zm2, stats + (size_t)((l - 1) * 8 + 7) * 256,
                mlp_bn2_g + (l - 1) * 128, mlp_bn2_b + (l - 1) * 128, h_h);
            // sb_k = (1+eps_k) h + agg_k(h)   (fp16 gather, half the bytes)
            agg_h<<<dim3(AGG_GRID, 3), 256, 0, stream>>>(
                h_h, rowptr0, csrc0, conv_eps, l * 3, sb);
            // W1: X[:, k*128..] = sb_k @ W1_k + b1 (raw A; stats -> slots 0/2/4)
            gemm_dir<0><<<G3, 256, 0, stream>>>(
                sb, (size_t)NN * 128, 128, 128,
                nullptr, 0, 0, nullptr, nullptr, 0, 0,
                rw1_hi + (size_t)(l - 1) * 3 * 128 * 128,
                rw1_lo + (size_t)(l - 1) * 3 * 128 * 128, (size_t)128 * 128,
                conv_rest_b1 + (l - 1) * 3 * 128, 128,
                X, 384, 128, NN, 1, stL, 512, 3, G128);
            // W2: sb[:, k*128..] = BN1(X slice k) @ W2_k + b2 (stats -> 1/3/5)
            gemm_dir<1><<<G3, 256, 0, stream>>>(
                X, 128, 384, 128,
                stL, 0, 512,
                conv_bn1_g + l * 3 * 128, conv_bn1_b + l * 3 * 128, 0, 128,
                w2_hi + (size_t)l * 3 * 128 * 128,
                w2_lo + (size_t)l * 3 * 128 * 128, (size_t)128 * 128,
                conv_b2 + l * 3 * 128, 128,
                sb, 384, 128, NN, 1, stL + 256, 512, 3, G128);
        }

        // fusion MLP layer 1: BN2(3 slices) @ mlp_W1 -> mlp1out (compact 128)
        gemm_dir<1><<<G128, 256, 0, stream>>>(
            mlp1in, 0, 384, 384,
            stL + 256, 512, 0,
            conv_bn2_g + l * 3 * 128, conv_bn2_b + l * 3 * 128, 128, 0,
            mw1_hi + (size_t)l * 128 * 384, mw1_lo + (size_t)l * 128 * 384, 0,
            mlp_b1 + l * 128, 0, mlp1out, 128, 0, NN, 1, slotF1, 0, 1, G128);

        // fusion MLP layer 2: BN(mlp1out) @ mlp_W2 -> zm2
        gemm_dir<1><<<G128, 256, 0, stream>>>(
            mlp1out, 0, 128, 128,
            slotF1, 0, 0,
            mlp_bn1_g + l * 128, mlp_bn1_b + l * 128, 0, 0,
            mw2_hi + (size_t)l * 128 * 128, mw2_lo + (size_t)l * 128 * 128, 0,
            mlp_b2 + l * 128, 0, zm2, 128, 0, NN, 1, slotF2, 0, 1, G128);
    }
    // final h = bn_relu(zm2, layer-5 F2 stats) -> X (compact [NN][128])
    bn_relu_f32<<<BN_GRID, 256, 0, stream>>>(
        zm2, stats + (size_t)(5 * 8 + 7) * 256,
        mlp_bn2_g + 5 * 128, mlp_bn2_b + 5 * 128, X);

    // ---- Set2Set readout (fp32) ----
    pack_wcat<<<(512 * 384 + 255) / 256, 256, 0, stream>>>(lstm_Wih, lstm_Whh, Wcat);
    for (int t = 0; t < 6; ++t) {
        gemm_f32<true><<<dim3(8, 4), 256, 0, stream>>>(
            S, Wcat, nullptr, gates, GG, 384, 512);
        lstm_kernel<<<(GG * 128 + 255) / 256, 256, 0, stream>>>(
            gates, lstm_bih, lstm_bhh, ccb, S);
        attend_kernel<<<GG, 256, 0, stream>>>(X, S, ews, gstart);
    }
    fc1_kernel<<<GG, 128, 0, stream>>>(S, fc1_W, fc1_b, gates);
    fc4_kernel<<<(GG * 12 + 255) / 256, 256, 0, stream>>>(gates, fc4_W, fc4_b, outp);
}

// Round 14
// 4401.015 us; speedup vs baseline: 1.3782x; 1.0321x over previous
//
#include <hip/hip_runtime.h>
#include <hip/hip_fp16.h>
#include <cstdint>
#include <cstddef>

#define NN 50000
#define EE 1600000
#define GG 512
#define FIN 1273

typedef unsigned short u16;
typedef unsigned int u32;
typedef __attribute__((ext_vector_type(8))) short short8;
typedef __attribute__((ext_vector_type(4))) float f32x4;

__device__ __forceinline__ float sigmf(float x) { return 1.f / (1.f + expf(-x)); }

// truncation split: v == hi + rem exactly; lo = bf16(rem); |v-(hi+lo)| <= 2^-16 |v|
__device__ __forceinline__ void splitbf(float v, u16& hi, u16& lo) {
    const u32 u = __float_as_uint(v);
    hi = (u16)(u >> 16);
    const float rem = v - __uint_as_float(u & 0xffff0000u);
    lo = (u16)(__float_as_uint(rem) >> 16);
}

__device__ __forceinline__ void gload_lds16(const void* g, void* l) {
    __builtin_amdgcn_global_load_lds(
        (const __attribute__((address_space(1))) void*)g,
        (__attribute__((address_space(3))) void*)l, 16, 0, 0);
}

// XCD-aware triplet remap: put the 3 mats of one row tile on the same XCD.
__device__ __forceinline__ bool remap3(int f, int nRow, int& mat, int& rt) {
    const int g = f / 24, w = f - g * 24;
    rt = g * 8 + (w & 7);
    mat = w >> 3;
    return rt < nRow;
}

// ===== layer-0 GEMM: split-bf16 MFMA, A = fp32 x staged via LDS ================
__global__ __launch_bounds__(256) void gemm_l0(
    const float* __restrict__ A, int lda, int K, int Kreal,
    const u16* __restrict__ Bhi, const u16* __restrict__ Blo, size_t strideB,
    float* __restrict__ C, int ldc, int coffStep, int M, int nRow)
{
    __shared__ u16 lsAhi[128 * 64];
    __shared__ u16 lsAlo[128 * 64];
    __shared__ u16 lsBhi[128 * 64];
    __shared__ u16 lsBlo[128 * 64];
    int mat, rt;
    if (!remap3(blockIdx.x, nRow, mat, rt)) return;
    const int tid = threadIdx.x;
    const int wave = tid >> 6, lane = tid & 63;
    const int row0 = rt * 128;
    const int coff = mat * coffStep;
    const u16* Bh = Bhi + (size_t)mat * strideB;
    const u16* Bl = Blo + (size_t)mat * strideB;
    const int wm = wave >> 1, wn = wave & 1;
    f32x4 acc[4][4] = {};

    for (int k0 = 0; k0 < K; k0 += 64) {
        if (k0) __syncthreads();
        #pragma unroll
        for (int i = 0; i < 4; ++i) {
            const int slot = i * 256 + tid;
            const int r = slot >> 3, ch = tid & 7;
            int gr = row0 + r; if (gr >= M) gr = M - 1;
            const int kb = k0 + ch * 8;
            u16 th[8], tl[8];
            const float* src = A + (size_t)gr * lda + kb;
            if (kb + 8 <= Kreal) {
                const float4 v0 = *(const float4*)(src);
                const float4 v1 = *(const float4*)(src + 4);
                const float va[8] = {v0.x, v0.y, v0.z, v0.w,
                                     v1.x, v1.y, v1.z, v1.w};
                #pragma unroll
                for (int e = 0; e < 8; ++e) splitbf(va[e], th[e], tl[e]);
            } else {
                #pragma unroll
                for (int e = 0; e < 8; ++e) {
                    const float v = (kb + e < Kreal) ? src[e] : 0.f;
                    splitbf(v, th[e], tl[e]);
                }
            }
            const int off = (r << 6) + ((ch ^ (r & 7)) << 3);
            *(short8*)&lsAhi[off] = *(const short8*)th;
            *(short8*)&lsAlo[off] = *(const short8*)tl;
        }
        #pragma unroll
        for (int i = 0; i < 4; ++i) {
            const int slot = i * 256 + wave * 64 + lane;
            const int r = slot >> 3, ch = slot & 7;
            const int sch = ch ^ (r & 7);
            const size_t goff = (size_t)r * K + k0 + sch * 8;
            const int lbase = (i * 256 + wave * 64) * 8;
            gload_lds16(Bh + goff, &lsBhi[lbase]);
            gload_lds16(Bl + goff, &lsBlo[lbase]);
        }
        __syncthreads();
        #pragma unroll
        for (int ks = 0; ks < 2; ++ks) {
            short8 ah[4], al[4], bh[4], bl[4];
            const int kch = ks * 4 + (lane >> 4);
            #pragma unroll
            for (int m = 0; m < 4; ++m) {
                const int r = wm * 64 + m * 16 + (lane & 15);
                const int off = (r << 6) + ((kch ^ (r & 7)) << 3);
                ah[m] = *(const short8*)&lsAhi[off];
                al[m] = *(const short8*)&lsAlo[off];
            }
            #pragma unroll
            for (int n = 0; n < 4; ++n) {
                const int c = wn * 64 + n * 16 + (lane & 15);
                const int off = (c << 6) + ((kch ^ (c & 7)) << 3);
                bh[n] = *(const short8*)&lsBhi[off];
                bl[n] = *(const short8*)&lsBlo[off];
            }
            #pragma unroll
            for (int m = 0; m < 4; ++m)
                #pragma unroll
                for (int n = 0; n < 4; ++n) {
                    acc[m][n] = __builtin_amdgcn_mfma_f32_16x16x32_bf16(
                        ah[m], bh[n], acc[m][n], 0, 0, 0);
                    acc[m][n] = __builtin_amdgcn_mfma_f32_16x16x32_bf16(
                        ah[m], bl[n], acc[m][n], 0, 0, 0);
                    acc[m][n] = __builtin_amdgcn_mfma_f32_16x16x32_bf16(
                        al[m], bh[n], acc[m][n], 0, 0, 0);
                }
        }
    }
    #pragma unroll
    for (int n = 0; n < 4; ++n) {
        const int c = wn * 64 + n * 16 + (lane & 15);
        #pragma unroll
        for (int m = 0; m < 4; ++m) {
            #pragma unroll
            for (int j = 0; j < 4; ++j) {
                const int gr = row0 + wm * 64 + m * 16 + ((lane >> 4) << 2) + j;
                if (gr < M)
                    C[(size_t)gr * ldc + coff + c] = acc[m][n][j];
            }
        }
    }
}

// ===== direct-A GEMM: A fp32 from global (no A LDS) ============================
template <int ABN>
__global__ __launch_bounds__(256) void gemm_dir(
    const float* __restrict__ A, size_t strideA, int lda, int K,
    const float* __restrict__ st, int stSlice, int stMat,
    const float* __restrict__ ga, const float* __restrict__ be,
    int gbSlice, int gbMat,
    const u16* __restrict__ Bhi, const u16* __restrict__ Blo, size_t strideB,
    const float* __restrict__ bias, int biasMat,
    float* __restrict__ C, int ldc, int coffStep,
    int M, int do_stats, float* __restrict__ stats_out, int ostatMat,
    int nMat, int nRow)
{
    __shared__ u16 lsBhi[128 * 64];
    __shared__ u16 lsBlo[128 * 64];
    int mat, rt;
    if (nMat == 3) {
        if (!remap3(blockIdx.x, nRow, mat, rt)) return;
    } else { mat = 0; rt = blockIdx.x; }
    const int tid = threadIdx.x;
    const int wave = tid >> 6, lane = tid & 63;
    const int row0 = rt * 128;
    const int wm = wave >> 1, wn = wave & 1;
    A += (size_t)mat * strideA;
    if (ABN) { st += mat * stMat; ga += mat * gbMat; be += mat * gbMat; }
    if (bias) bias += mat * biasMat;
    if (do_stats) stats_out += mat * ostatMat;
    const u16* Bh = Bhi + (size_t)mat * strideB;
    const u16* Bl = Blo + (size_t)mat * strideB;
    const int coff = mat * coffStep;
    f32x4 acc[4][4] = {};

    int arow[4];
    #pragma unroll
    for (int m = 0; m < 4; ++m) {
        int r = row0 + wm * 64 + m * 16 + (lane & 15);
        if (r >= M) r = M - 1;
        arow[m] = r;
    }

    for (int k0 = 0; k0 < K; k0 += 64) {
        if (k0) __syncthreads();
        #pragma unroll
        for (int i = 0; i < 4; ++i) {
            const int slot = i * 256 + wave * 64 + lane;
            const int r = slot >> 3, ch = slot & 7;
            const int sch = ch ^ (r & 7);
            const size_t goff = (size_t)r * K + k0 + sch * 8;
            const int lbase = (i * 256 + wave * 64) * 8;
            gload_lds16(Bh + goff, &lsBhi[lbase]);
            gload_lds16(Bl + goff, &lsBlo[lbase]);
        }
        __syncthreads();
        #pragma unroll
        for (int ks = 0; ks < 2; ++ks) {
            const int kch = ks * 4 + (lane >> 4);
            const int kb = k0 + kch * 8;
            float scv[8], shv[8];
            if (ABN) {
                const int s = kb >> 7, d0 = kb & 127;
                const float* stS = st + s * stSlice;
                const float* gS  = ga + s * gbSlice;
                const float* beS = be + s * gbSlice;
                #pragma unroll
                for (int e = 0; e < 8; ++e) {
                    const int d = d0 + e;
                    const float mu = stS[d] * (1.f / NN);
                    const float var = fmaxf(stS[128 + d] * (1.f / NN) - mu * mu, 0.f);
                    const float sc = gS[d] * rsqrtf(var + 1e-5f);
                    scv[e] = sc;
                    shv[e] = beS[d] - sc * mu;
                }
            }
            short8 ah[4], al[4];
            #pragma unroll
            for (int m = 0; m < 4; ++m) {
                const float* src = A + (size_t)arow[m] * lda + kb;
                const float4 v0 = *(const float4*)(src);
                const float4 v1 = *(const float4*)(src + 4);
                const float va[8] = {v0.x, v0.y, v0.z, v0.w,
                                     v1.x, v1.y, v1.z, v1.w};
                u16 th[8], tl[8];
                #pragma unroll
                for (int e = 0; e < 8; ++e) {
                    const float y = ABN
                        ? fmaxf(fmaf(scv[e], va[e], shv[e]), 0.f) : va[e];
                    splitbf(y, th[e], tl[e]);
                }
                ah[m] = *(const short8*)th;
                al[m] = *(const short8*)tl;
            }
            #pragma unroll
            for (int n = 0; n < 4; ++n) {
                const int c = wn * 64 + n * 16 + (lane & 15);
                const int off = (c << 6) + ((kch ^ (c & 7)) << 3);
                const short8 bh = *(const short8*)&lsBhi[off];
                const short8 bl = *(const short8*)&lsBlo[off];
                #pragma unroll
                for (int m = 0; m < 4; ++m) {
                    acc[m][n] = __builtin_amdgcn_mfma_f32_16x16x32_bf16(
                        ah[m], bh, acc[m][n], 0, 0, 0);
                    acc[m][n] = __builtin_amdgcn_mfma_f32_16x16x32_bf16(
                        ah[m], bl, acc[m][n], 0, 0, 0);
                    acc[m][n] = __builtin_amdgcn_mfma_f32_16x16x32_bf16(
                        al[m], bh, acc[m][n], 0, 0, 0);
                }
            }
        }
    }

    float colsum[4] = {0.f, 0.f, 0.f, 0.f}, colsq[4] = {0.f, 0.f, 0.f, 0.f};
    #pragma unroll
    for (int n = 0; n < 4; ++n) {
        const int c = wn * 64 + n * 16 + (lane & 15);
        const float bv = bias ? bias[c] : 0.f;
        #pragma unroll
        for (int m = 0; m < 4; ++m) {
            #pragma unroll
            for (int j = 0; j < 4; ++j) {
                const int gr = row0 + wm * 64 + m * 16 + ((lane >> 4) << 2) + j;
                if (gr < M) {
                    const float v = acc[m][n][j] + bv;
                    C[(size_t)gr * ldc + coff + c] = v;
                    colsum[n] += v; colsq[n] += v * v;
                }
            }
        }
    }
    if (do_stats) {
        float* ssum = (float*)lsBhi;
        float* ssq  = ssum + 128;
        __syncthreads();
        if (tid < 128) { ssum[tid] = 0.f; ssq[tid] = 0.f; }
        __syncthreads();
        #pragma unroll
        for (int n = 0; n < 4; ++n) {
            const int c = wn * 64 + n * 16 + (lane & 15);
            atomicAdd(&ssum[c], colsum[n]);
            atomicAdd(&ssq[c], colsq[n]);
        }
        __syncthreads();
        if (tid < 128) {
            atomicAdd(&stats_out[tid],       ssum[tid]);
            atomicAdd(&stats_out[128 + tid], ssq[tid]);
        }
    }
}

// ------ weight transpose+split: W[nmat][K][128] -> Whi/Wlo[nmat][128][Kpad] ----
__global__ __launch_bounds__(256) void wt_cast2(const float* __restrict__ W,
                                                u16* __restrict__ Whi,
                                                u16* __restrict__ Wlo,
                                                int total, int K, int Kpad) {
    const int idx = blockIdx.x * 256 + threadIdx.x;
    if (idx >= total) return;
    const int perm = 128 * Kpad;
    const int m = idx / perm, rem = idx - m * perm;
    const int n = rem / Kpad, k = rem - n * Kpad;
    const float v = (k < K) ? W[(size_t)m * K * 128 + (size_t)k * 128 + n] : 0.f;
    u16 hi, lo;
    splitbf(v, hi, lo);
    Whi[idx] = hi; Wlo[idx] = lo;
}

// ---------------- fp32 tiled GEMM (LSTM gates only) ----------------------------
template <bool BT>
__global__ __launch_bounds__(256) void gemm_f32(
    const float* __restrict__ A, const float* __restrict__ B,
    const float* __restrict__ bias, float* __restrict__ C,
    int M, int K, int Nc)
{
    __shared__ float As[32][68];
    __shared__ float Bs[32][132];
    const int tid = threadIdx.x;
    const int tx = tid & 15, ty = tid >> 4;
    const int row0 = blockIdx.x * 64, col0 = blockIdx.y * 128;
    float acc[4][8] = {};
    for (int k0 = 0; k0 < K; k0 += 32) {
        {
            const int kk = tid & 31, rb = tid >> 5;
            #pragma unroll
            for (int i = 0; i < 8; ++i) {
                const int r = rb + i * 8, gr = row0 + r, gk = k0 + kk;
                As[kk][r] = (gr < M && gk < K) ? A[(size_t)gr * K + gk] : 0.f;
            }
        }
        if (!BT) {
            const int c = tid & 127, kb = tid >> 7;
            #pragma unroll
            for (int i = 0; i < 16; ++i) {
                const int kk = kb + i * 2, gk = k0 + kk;
                Bs[kk][c] = (gk < K) ? B[(size_t)gk * Nc + col0 + c] : 0.f;
            }
        } else {
            const int kk = tid & 31, cb = tid >> 5;
            #pragma unroll
            for (int i = 0; i < 16; ++i) {
                const int c = cb + i * 8, gk = k0 + kk;
                Bs[kk][c] = (gk < K) ? B[(size_t)(col0 + c) * K + gk] : 0.f;
            }
        }
        __syncthreads();
        #pragma unroll 8
        for (int kk = 0; kk < 32; ++kk) {
            const float4 av  = *(const float4*)&As[kk][ty * 4];
            const float4 bv0 = *(const float4*)&Bs[kk][tx * 8];
            const float4 bv1 = *(const float4*)&Bs[kk][tx * 8 + 4];
            const float a[4] = {av.x, av.y, av.z, av.w};
            const float b[8] = {bv0.x, bv0.y, bv0.z, bv0.w, bv1.x, bv1.y, bv1.z, bv1.w};
            #pragma unroll
            for (int i = 0; i < 4; ++i)
                #pragma unroll
                for (int j = 0; j < 8; ++j)
                    acc[i][j] = fmaf(a[i], b[j], acc[i][j]);
        }
        __syncthreads();
    }
    #pragma unroll
    for (int j = 0; j < 8; ++j) {
        const float bv = bias ? bias[col0 + tx * 8 + j] : 0.f;
        #pragma unroll
        for (int i = 0; i < 4; ++i) acc[i][j] += bv;
    }
    #pragma unroll
    for (int i = 0; i < 4; ++i) {
        const int gr = row0 + ty * 4 + i;
        if (gr < M) {
            *(float4*)&C[(size_t)gr * Nc + col0 + tx * 8] =
                make_float4(acc[i][0], acc[i][1], acc[i][2], acc[i][3]);
            *(float4*)&C[(size_t)gr * Nc + col0 + tx * 8 + 4] =
                make_float4(acc[i][4], acc[i][5], acc[i][6], acc[i][7]);
        }
    }
}

// ---------------- batched CSR build (3 edge sets via blockIdx.y) ---------------
__global__ __launch_bounds__(256) void count_deg3(
    const int* __restrict__ e0, const int* __restrict__ e1,
    const int* __restrict__ e2, int* __restrict__ deg3)
{
    const int k = blockIdx.y;
    const int* ei = (k == 0) ? e0 : (k == 1 ? e1 : e2);
    const int e = blockIdx.x * 256 + threadIdx.x;
    if (e < EE) atomicAdd(&deg3[(size_t)k * NN + ei[EE + e]], 1);
}

__global__ __launch_bounds__(512) void scan1(const int* __restrict__ deg3,
                                             int* __restrict__ scanned3,
                                             int* __restrict__ bsum3) {
    __shared__ int s[512];
    const int k = blockIdx.y;
    const int* deg = deg3 + (size_t)k * NN;
    int* scanned   = scanned3 + (size_t)k * NN;
    int* bsum      = bsum3 + (size_t)k * 128;
    const int t = threadIdx.x;
    const int i = blockIdx.x * 512 + t;
    const int v = (i < NN) ? deg[i] : 0;
    s[t] = v; __syncthreads();
    for (int o = 1; o < 512; o <<= 1) {
        const int tv = (t >= o) ? s[t - o] : 0;
        __syncthreads();
        s[t] += tv;
        __syncthreads();
    }
    if (i < NN) scanned[i] = s[t];
    if (t == 511) bsum[blockIdx.x] = s[511];
}

__global__ __launch_bounds__(128) void scan2(int* __restrict__ bsum3, int nb) {
    __shared__ int s[128];
    int* bsum = bsum3 + (size_t)blockIdx.y * 128;
    const int t = threadIdx.x;
    const int v = (t < nb) ? bsum[t] : 0;
    s[t] = v; __syncthreads();
    for (int o = 1; o < 128; o <<= 1) {
        const int tv = (t >= o) ? s[t - o] : 0;
        __syncthreads();
        s[t] += tv;
        __syncthreads();
    }
    if (t < nb) bsum[t] = s[t] - v;  // exclusive
}

__global__ __launch_bounds__(256) void scan3(const int* __restrict__ deg3,
                                             const int* __restrict__ scanned3,
                                             const int* __restrict__ bsum3,
                                             int* __restrict__ rowptr0,
                                             int* __restrict__ cursor3) {
    const int k = blockIdx.y;
    const int* deg = deg3 + (size_t)k * NN;
    const int* scanned = scanned3 + (size_t)k * NN;
    const int* bsum = bsum3 + (size_t)k * 128;
    int* rowptr = rowptr0 + (size_t)k * (NN + 1);
    int* cursor = cursor3 + (size_t)k * NN;
    const int i = blockIdx.x * 256 + threadIdx.x;
    if (i < NN) {
        const int v = bsum[i >> 9] + scanned[i] - deg[i];
        rowptr[i] = v; cursor[i] = v;
    }
    if (i == 0) rowptr[NN] = EE;
}

__global__ __launch_bounds__(256) void fill_csr3(
    const int* __restrict__ e0, const int* __restrict__ e1,
    const int* __restrict__ e2, int* __restrict__ cursor3,
    int* __restrict__ csrc0)
{
    const int k = blockIdx.y;
    const int* ei = (k == 0) ? e0 : (k == 1 ? e1 : e2);
    const int e = blockIdx.x * 256 + threadIdx.x;
    if (e < EE) {
        const int s = ei[e];
        const int pos = atomicAdd(&cursor3[(size_t)k * NN + ei[EE + e]], 1);
        csrc0[(size_t)k * EE + pos] = s;
    }
}

// ==== layer-0 fused aggregate + combine (fp32 gather, 3 edge sets) =============
__global__ __launch_bounds__(256) void agg_combine(
    const float* __restrict__ X, int ldp4,
    const int* __restrict__ rowptrB, const int* __restrict__ csrcB,
    const float* __restrict__ b1B,
    const float* __restrict__ eps_arr, int epsBase,
    float* __restrict__ zB, float* __restrict__ statsB)
{
    __shared__ float red[256];
    const int k = blockIdx.y;
    const int* rowptr = rowptrB + (size_t)k * (NN + 1);
    const int* csrc   = csrcB + (size_t)k * EE;
    float* z          = zB + (size_t)k * NN * 128;
    const int tid = threadIdx.x, lane = tid & 63, wave = tid >> 6;
    const float e1 = 1.f + eps_arr[epsBase + k];
    const int half = lane >> 5;
    const int l32 = lane & 31;
    const float4* p4 = (const float4*)X + k * 32;
    float s[4] = {0.f, 0.f, 0.f, 0.f}, q[4] = {0.f, 0.f, 0.f, 0.f};
    float4 bv = make_float4(0.f, 0.f, 0.f, 0.f);
    if (lane < 32) bv = ((const float4*)(b1B + k * 128))[l32];
    red[tid] = 0.f;
    __syncthreads();
    const int nbase = blockIdx.x * 16 + wave * 4;
    for (int t = 0; t < 4; ++t) {
        const int wid = nbase + t;
        const int s0 = rowptr[wid], s1 = rowptr[wid + 1];
        float ax = 0.f, ay = 0.f, az = 0.f, aw = 0.f;
        int j = s0;
        for (; j + 15 < s1; j += 16) {
            float4 v[8];
            #pragma unroll
            for (int u = 0; u < 8; ++u)
                v[u] = p4[(size_t)csrc[j + 2 * u + half] * ldp4 + l32];
            #pragma unroll
            for (int u = 0; u < 8; ++u) {
                ax += v[u].x; ay += v[u].y; az += v[u].z; aw += v[u].w;
            }
        }
        for (; j + 7 < s1; j += 8) {
            float4 v[4];
            #pragma unroll
            for (int u = 0; u < 4; ++u)
                v[u] = p4[(size_t)csrc[j + 2 * u + half] * ldp4 + l32];
            #pragma unroll
            for (int u = 0; u < 4; ++u) {
                ax += v[u].x; ay += v[u].y; az += v[u].z; aw += v[u].w;
            }
        }
        for (; j + 3 < s1; j += 4) {
            const float4 v0 = p4[(size_t)csrc[j + half] * ldp4 + l32];
            const float4 v1 = p4[(size_t)csrc[j + 2 + half] * ldp4 + l32];
            ax += v0.x + v1.x; ay += v0.y + v1.y;
            az += v0.z + v1.z; aw += v0.w + v1.w;
        }
        for (; j + 1 < s1; j += 2) {
            const float4 v0 = p4[(size_t)csrc[j + half] * ldp4 + l32];
            ax += v0.x; ay += v0.y; az += v0.z; aw += v0.w;
        }
        if (j < s1 && half == 0) {
            const float4 v0 = p4[(size_t)csrc[j] * ldp4 + l32];
            ax += v0.x; ay += v0.y; az += v0.z; aw += v0.w;
        }
        ax += __shfl_down(ax, 32, 64);
        ay += __shfl_down(ay, 32, 64);
        az += __shfl_down(az, 32, 64);
        aw += __shfl_down(aw, 32, 64);
        if (lane < 32) {
            const float4 self = p4[(size_t)wid * ldp4 + l32];
            float4 zv;
            zv.x = fmaf(e1, self.x, ax + bv.x);
            zv.y = fmaf(e1, self.y, ay + bv.y);
            zv.z = fmaf(e1, self.z, az + bv.z);
            zv.w = fmaf(e1, self.w, aw + bv.w);
            ((float4*)z)[(size_t)wid * 32 + l32] = zv;
            s[0] += zv.x; s[1] += zv.y; s[2] += zv.z; s[3] += zv.w;
            q[0] += zv.x * zv.x; q[1] += zv.y * zv.y;
            q[2] += zv.z * zv.z; q[3] += zv.w * zv.w;
        }
    }
    if (lane < 32) {
        const int d = l32 * 4;
        #pragma unroll
        for (int c = 0; c < 4; ++c) {
            atomicAdd(&red[d + c], s[c]);
            atomicAdd(&red[128 + d + c], q[c]);
        }
    }
    __syncthreads();
    atomicAdd(&statsB[(size_t)k * 512 + tid], red[tid]);
}

// ==== l>=1 aggregate + combine over fp16 h rows (half the gather bytes) ========
__global__ __launch_bounds__(256) void agg_h(
    const u16* __restrict__ Hh,
    const int* __restrict__ rowptrB, const int* __restrict__ csrcB,
    const float* __restrict__ eps_arr, int epsBase,
    float* __restrict__ zB)
{
    const int k = blockIdx.y;
    const int* rowptr = rowptrB + (size_t)k * (NN + 1);
    const int* csrc   = csrcB + (size_t)k * EE;
    float* z          = zB + (size_t)k * NN * 128;
    const int tid = threadIdx.x, lane = tid & 63, wave = tid >> 6;
    const float e1 = 1.f + eps_arr[epsBase + k];
    const u32* p = (const u32*)Hh;   // [NN][64]
    const int nbase = blockIdx.x * 16 + wave * 4;
    #pragma unroll
    for (int t = 0; t < 4; ++t) {
        const int wid = nbase + t;
        const int s0 = rowptr[wid], s1 = rowptr[wid + 1];
        float ax = 0.f, ay = 0.f;
        int j = s0;
        for (; j + 15 < s1; j += 16) {
            u32 v[16];
            #pragma unroll
            for (int u = 0; u < 16; ++u)
                v[u] = p[(size_t)csrc[j + u] * 64 + lane];
            #pragma unroll
            for (int u = 0; u < 16; ++u) {
                const float2 fv = __half22float2(*(const __half2*)&v[u]);
                ax += fv.x; ay += fv.y;
            }
        }
        for (; j + 7 < s1; j += 8) {
            u32 v[8];
            #pragma unroll
            for (int u = 0; u < 8; ++u)
                v[u] = p[(size_t)csrc[j + u] * 64 + lane];
            #pragma unroll
            for (int u = 0; u < 8; ++u) {
                const float2 fv = __half22float2(*(const __half2*)&v[u]);
                ax += fv.x; ay += fv.y;
            }
        }
        for (; j < s1; ++j) {
            const u32 v = p[(size_t)csrc[j] * 64 + lane];
            const float2 fv = __half22float2(*(const __half2*)&v);
            ax += fv.x; ay += fv.y;
        }
        const u32 sv = p[(size_t)wid * 64 + lane];
        const float2 sf = __half22float2(*(const __half2*)&sv);
        float2 zv;
        zv.x = fmaf(e1, sf.x, ax);
        zv.y = fmaf(e1, sf.y, ay);
        ((float2*)z)[(size_t)wid * 64 + lane] = zv;
    }
}

// ------- BN + ReLU -> fp16 rows for the gather ---------------------------------
__global__ __launch_bounds__(256) void bn_relu_h(
    const float* __restrict__ xin, const float* __restrict__ stats,
    const float* __restrict__ gamma, const float* __restrict__ beta,
    u16* __restrict__ out)
{
    const size_t i = (size_t)blockIdx.x * 256 + threadIdx.x;  // pair index
    if (i >= (size_t)NN * 64) return;
    const int d = (int)(i & 63) * 2;
    const float inv_n = 1.f / NN;
    const float mu0 = stats[d] * inv_n,     mu1 = stats[d + 1] * inv_n;
    const float v0 = fmaxf(stats[128 + d] * inv_n - mu0 * mu0, 0.f);
    const float v1 = fmaxf(stats[129 + d] * inv_n - mu1 * mu1, 0.f);
    const float s0 = gamma[d] * rsqrtf(v0 + 1e-5f);
    const float s1 = gamma[d + 1] * rsqrtf(v1 + 1e-5f);
    const float2 xv = ((const float2*)xin)[i];
    const float y0 = fmaxf(fmaf(s0, xv.x - mu0, beta[d]), 0.f);
    const float y1 = fmaxf(fmaf(s1, xv.y - mu1, beta[d + 1]), 0.f);
    const __half2 hv = __floats2half2_rn(y0, y1);
    ((u32*)out)[i] = *(const u32*)&hv;
}

// ------- BN + ReLU -> fp32 (final h only) --------------------------------------
__global__ __launch_bounds__(256) void bn_relu_f32(
    const float* __restrict__ xin, const float* __restrict__ stats,
    const float* __restrict__ gamma, const float* __restrict__ beta,
    float* __restrict__ out)
{
    const size_t i = (size_t)blockIdx.x * 256 + threadIdx.x;  // pair index
    if (i >= (size_t)NN * 64) return;
    const int d = (int)(i & 63) * 2;
    const float inv_n = 1.f / NN;
    const float mu0 = stats[d] * inv_n,     mu1 = stats[d + 1] * inv_n;
    const float v0 = fmaxf(stats[128 + d] * inv_n - mu0 * mu0, 0.f);
    const float v1 = fmaxf(stats[129 + d] * inv_n - mu1 * mu1, 0.f);
    const float s0 = gamma[d] * rsqrtf(v0 + 1e-5f);
    const float s1 = gamma[d + 1] * rsqrtf(v1 + 1e-5f);
    const float2 xv = ((const float2*)xin)[i];
    const float y0 = fmaxf(fmaf(s0, xv.x - mu0, beta[d]), 0.f);
    const float y1 = fmaxf(fmaf(s1, xv.y - mu1, beta[d + 1]), 0.f);
    ((float2*)out)[i] = make_float2(y0, y1);
}

// ---------------- per-graph segment starts (batch is sorted) -------------------
__global__ __launch_bounds__(256) void seg_starts(const int* __restrict__ batch,
                                                  int* __restrict__ gstart) {
    const int i = blockIdx.x * 256 + threadIdx.x;
    if (i >= NN) return;
    const int b = batch[i];
    if (i == 0) { for (int g = 0; g <= b; ++g) gstart[g] = 0; }
    else {
        const int pb = batch[i - 1];
        for (int g = pb + 1; g <= b; ++g) gstart[g] = i;
    }
    if (i == NN - 1) { for (int g = b + 1; g <= GG; ++g) gstart[g] = NN; }
}

// ---------------- Set2Set ------------------------------------------------------
__global__ __launch_bounds__(256) void pack_wcat(const float* __restrict__ Wih,
                                                 const float* __restrict__ Whh,
                                                 float* __restrict__ Wcat) {
    const int i = blockIdx.x * 256 + threadIdx.x;
    if (i >= 512 * 384) return;
    const int j = i / 384, k = i - j * 384;
    Wcat[i] = (k < 256) ? Wih[j * 256 + k] : Whh[j * 128 + (k - 256)];
}

__global__ __launch_bounds__(256) void lstm_kernel(
    const float* __restrict__ gates, const float* __restrict__ bih,
    const float* __restrict__ bhh, float* __restrict__ cc, float* __restrict__ S)
{
    const int i = blockIdx.x * 256 + threadIdx.x;
    if (i >= GG * 128) return;
    const int g = i >> 7, d = i & 127;
    const float* gr = gates + (size_t)g * 512;
    const float ig = gr[d]       + bih[d]       + bhh[d];
    const float fg = gr[128 + d] + bih[128 + d] + bhh[128 + d];
    const float gv = gr[256 + d] + bih[256 + d] + bhh[256 + d];
    const float og = gr[384 + d] + bih[384 + d] + bhh[384 + d];
    const float c  = sigmf(fg) * cc[i] + sigmf(ig) * tanhf(gv);
    const float hv = sigmf(og) * tanhf(c);
    cc[i] = c;
    S[(size_t)g * 384 + d] = hv;
    S[(size_t)g * 384 + 256 + d] = hv;
}

__global__ __launch_bounds__(256) void attend_kernel(
    const float* __restrict__ h, float* __restrict__ S,
    float* __restrict__ ews, const int* __restrict__ gstart)
{
    const int g = blockIdx.x;
    const int rs = gstart[g], re = gstart[g + 1];
    const int tid = threadIdx.x, lane = tid & 63, w = tid >> 6;
    __shared__ float q[128];
    __shared__ float red[8];
    __shared__ float racc[4][128];
    if (tid < 128) q[tid] = S[(size_t)g * 384 + 256 + tid];
    __syncthreads();
    const float2* h2 = (const float2*)h;
    float lmax = -1e30f;
    for (int n = rs + w; n < re; n += 4) {
        const float2 hv = h2[(size_t)n * 64 + lane];
        float p = hv.x * q[2 * lane] + hv.y * q[2 * lane + 1];
        #pragma unroll
        for (int o = 32; o; o >>= 1) p += __shfl_down(p, o, 64);
        if (lane == 0) { ews[n] = p; lmax = fmaxf(lmax, p); }
    }
    if (lane == 0) red[w] = lmax;
    __syncthreads();
    const float m = fmaxf(fmaxf(red[0], red[1]), fmaxf(red[2], red[3]));
    __syncthreads();
    float lsum = 0.f;
    for (int n = rs + tid; n < re; n += 256) {
        const float ex = expf(ews[n] - m);
        ews[n] = ex; lsum += ex;
    }
    #pragma unroll
    for (int o = 32; o; o >>= 1) lsum += __shfl_down(lsum, o, 64);
    if (lane == 0) red[w] = lsum;
    __syncthreads();
    const float denom = red[0] + red[1] + red[2] + red[3];
    // ---- r phase: all 4 waves accumulate partial weighted sums ----
    float rx = 0.f, ry = 0.f;
    for (int n = rs + w; n < re; n += 4) {
        const float a = ews[n];
        const float2 hv = h2[(size_t)n * 64 + lane];
        rx = fmaf(a, hv.x, rx);
        ry = fmaf(a, hv.y, ry);
    }
    racc[w][2 * lane] = rx;
    racc[w][2 * lane + 1] = ry;
    __syncthreads();
    if (tid < 128) {
        const float rsum = racc[0][tid] + racc[1][tid] + racc[2][tid] + racc[3][tid];
        S[(size_t)g * 384 + 128 + tid] = (denom > 0.f) ? rsum / denom : 0.f;
    }
}

__global__ __launch_bounds__(128) void fc1_kernel(const float* __restrict__ S,
                                                  const float* __restrict__ W,
                                                  const float* __restrict__ b,
                                                  float* __restrict__ out1) {
    const int g = blockIdx.x, d = threadIdx.x;
    __shared__ float qs[256];
    qs[d] = S[(size_t)g * 384 + d];
    qs[128 + d] = S[(size_t)g * 384 + 128 + d];
    __syncthreads();
    float acc = b[d];
    for (int k = 0; k < 256; ++k) acc = fmaf(qs[k], W[k * 128 + d], acc);
    out1[(size_t)g * 128 + d] = fmaxf(acc, 0.f);
}

__global__ __launch_bounds__(256) void fc4_kernel(const float* __restrict__ out1,
                                                  const float* __restrict__ W,
                                                  const float* __restrict__ b,
                                                  float* __restrict__ out) {
    const int i = blockIdx.x * 256 + threadIdx.x;
    if (i >= GG * 12) return;
    const int g = i / 12, j = i - g * 12;
    float acc = b[j];
    for (int d = 0; d < 128; ++d)
        acc = fmaf(out1[(size_t)g * 128 + d], W[d * 12 + j], acc);
    out[i] = acc;
}

// ================================================================================
extern "C" void kernel_launch(void* const* d_in, const int* in_sizes, int n_in,
                              void* d_out, int out_size, void* d_ws, size_t ws_size,
                              hipStream_t stream)
{
    const float* x        = (const float*)d_in[0];
    const int*   eidx[3]  = {(const int*)d_in[1], (const int*)d_in[2], (const int*)d_in[3]};
    const int*   batch    = (const int*)d_in[4];
    const float* conv1_W1     = (const float*)d_in[5];
    const float* conv1_b1     = (const float*)d_in[6];
    const float* conv_rest_W1 = (const float*)d_in[7];
    const float* conv_rest_b1 = (const float*)d_in[8];
    const float* conv_W2      = (const float*)d_in[9];
    const float* conv_b2      = (const float*)d_in[10];
    const float* conv_bn1_g   = (const float*)d_in[11];
    const float* conv_bn1_b   = (const float*)d_in[12];
    const float* conv_bn2_g   = (const float*)d_in[13];
    const float* conv_bn2_b   = (const float*)d_in[14];
    const float* conv_eps     = (const float*)d_in[15];
    const float* mlp_W1       = (const float*)d_in[16];
    const float* mlp_b1       = (const float*)d_in[17];
    const float* mlp_bn1_g    = (const float*)d_in[18];
    const float* mlp_bn1_b    = (const float*)d_in[19];
    const float* mlp_W2       = (const float*)d_in[20];
    const float* mlp_b2       = (const float*)d_in[21];
    const float* mlp_bn2_g    = (const float*)d_in[22];
    const float* mlp_bn2_b    = (const float*)d_in[23];
    const float* lstm_Wih     = (const float*)d_in[24];
    const float* lstm_Whh     = (const float*)d_in[25];
    const float* lstm_bih     = (const float*)d_in[26];
    const float* lstm_bhh     = (const float*)d_in[27];
    const float* fc1_W        = (const float*)d_in[28];
    const float* fc1_b        = (const float*)d_in[29];
    const float* fc4_W        = (const float*)d_in[30];
    const float* fc4_b        = (const float*)d_in[31];
    float* outp = (float*)d_out;

    // ---- workspace layout ----
    float* f = (float*)d_ws;
    size_t fo = 0;
    float* X     = f + fo; fo += (size_t)NN * 384;  // proj / z (l>=1) / mlp1-out / final h
    float* sb    = f + fo; fo += (size_t)NN * 384;  // agg out (stacked) / W2 out (l>=1)
    float* zm2   = f + fo; fo += (size_t)NN * 128;  // mlp2 out (layer state)
    float* ews   = f + fo; fo += NN;
    float* stats = f + fo; fo += 48 * 256;
    float* S     = f + fo; fo += (size_t)GG * 384;
    float* ccb   = f + fo; fo += (size_t)GG * 128;
    float* gates = f + fo; fo += (size_t)GG * 512;  // reused as fc1 output
    float* Wcat  = f + fo; fo += (size_t)512 * 384;
    fo = (fo + 7) & ~(size_t)7;   // 16B-align bf16 region
    u16* b = (u16*)(f + fo);
    size_t bo = 0;
    u16* h_h     = b + bo; bo += (size_t)NN * 128;  // fp16 h rows for the gather
    u16* c1_hi   = b + bo; bo += (size_t)3 * 128 * 1280;
    u16* c1_lo   = b + bo; bo += (size_t)3 * 128 * 1280;
    u16* rw1_hi  = b + bo; bo += (size_t)15 * 128 * 128;
    u16* rw1_lo  = b + bo; bo += (size_t)15 * 128 * 128;
    u16* w2_hi   = b + bo; bo += (size_t)18 * 128 * 128;
    u16* w2_lo   = b + bo; bo += (size_t)18 * 128 * 128;
    u16* mw1_hi  = b + bo; bo += (size_t)6 * 128 * 384;
    u16* mw1_lo  = b + bo; bo += (size_t)6 * 128 * 384;
    u16* mw2_hi  = b + bo; bo += (size_t)6 * 128 * 128;
    u16* mw2_lo  = b + bo; bo += (size_t)6 * 128 * 128;
    int* ip = (int*)(b + bo);
    size_t io = 0;
    int* rowptr0 = ip + io; io += (size_t)3 * (NN + 1);
    int* csrc0   = ip + io; io += (size_t)3 * EE;
    int* deg3    = ip + io; io += (size_t)3 * NN;
    int* cursor3 = ip + io; io += (size_t)3 * NN;
    int* scan3d  = ip + io; io += (size_t)3 * NN;
    int* bsum3   = ip + io; io += 3 * 128;
    int* gstart  = ip + io; io += GG + 1;
    const size_t need = fo * 4 + bo * 2 + io * 4;
    if (ws_size < need) return;

    const int NBLK_SCAN = (NN + 511) / 512;

    // ---- weight transpose+split (K padded to x64) ----
    {
        int t;
        t = 3 * 128 * 1280;
        wt_cast2<<<(t + 255) / 256, 256, 0, stream>>>(conv1_W1, c1_hi, c1_lo, t, FIN, 1280);
        t = 15 * 128 * 128;
        wt_cast2<<<(t + 255) / 256, 256, 0, stream>>>(conv_rest_W1, rw1_hi, rw1_lo, t, 128, 128);
        t = 18 * 128 * 128;
        wt_cast2<<<(t + 255) / 256, 256, 0, stream>>>(conv_W2, w2_hi, w2_lo, t, 128, 128);
        t = 6 * 128 * 384;
        wt_cast2<<<(t + 255) / 256, 256, 0, stream>>>(mlp_W1, mw1_hi, mw1_lo, t, 384, 384);
        t = 6 * 128 * 128;
        wt_cast2<<<(t + 255) / 256, 256, 0, stream>>>(mlp_W2, mw2_hi, mw2_lo, t, 128, 128);
    }

    // ---- batched CSR build for the 3 edge sets ----
    hipMemsetAsync(deg3, 0, (size_t)3 * NN * sizeof(int), stream);
    count_deg3<<<dim3((EE + 255) / 256, 3), 256, 0, stream>>>(
        eidx[0], eidx[1], eidx[2], deg3);
    scan1<<<dim3(NBLK_SCAN, 3), 512, 0, stream>>>(deg3, scan3d, bsum3);
    scan2<<<dim3(1, 3), 128, 0, stream>>>(bsum3, NBLK_SCAN);
    scan3<<<dim3((NN + 255) / 256, 3), 256, 0, stream>>>(
        deg3, scan3d, bsum3, rowptr0, cursor3);
    fill_csr3<<<dim3((EE + 255) / 256, 3), 256, 0, stream>>>(
        eidx[0], eidx[1], eidx[2], cursor3, csrc0);

    seg_starts<<<(NN + 255) / 256, 256, 0, stream>>>(batch, gstart);
    hipMemsetAsync(stats, 0, 48 * 256 * sizeof(float), stream);
    hipMemsetAsync(S, 0, (size_t)GG * 384 * sizeof(float), stream);
    hipMemsetAsync(ccb, 0, (size_t)GG * 128 * sizeof(float), stream);

    const int G128 = (NN + 127) / 128;                 // 391 row tiles
    const int G3   = 24 * ((G128 + 7) / 8);            // 1176 (triplet remap grid)
    const int AGG_GRID = NN / 16;                      // 3125 x-blocks
    const int BN_GRID = (NN * 64 + 255) / 256;

    // ---- 6 GIN layers ----
    for (int l = 0; l < 6; ++l) {
        float* stL    = stats + (size_t)l * 8 * 256;
        float* slotF1 = stL + 6 * 256;
        float* slotF2 = stL + 7 * 256;
        float* mlp1in  = (l == 0) ? X : sb;     // [NN][384] W2 outputs
        float* mlp1out = (l == 0) ? sb : X;     // [NN][128] compact

        if (l == 0) {
            // proj-first: X[:, k*128..] = x @ W1_k
            gemm_l0<<<G3, 256, 0, stream>>>(
                x, FIN, 1280, FIN, c1_hi, c1_lo, (size_t)128 * 1280,
                X, 384, 128, NN, G128);
            // z_k = (1+eps)proj + agg + b1 (fp32 gather; stats -> slots 0/2/4)
            agg_combine<<<dim3(AGG_GRID, 3), 256, 0, stream>>>(
                X, 96, rowptr0, csrc0, conv1_b1, conv_eps, 0, sb, stL);
            // W2: X[:, k*128..] = BN1(z_k) @ W2_k + b2 (stats -> slots 1/3/5)
            gemm_dir<1><<<G3, 256, 0, stream>>>(
                sb, (size_t)NN * 128, 128, 128,
                stL, 0, 512,
                conv_bn1_g + l * 3 * 128, conv_bn1_b + l * 3 * 128, 0, 128,
                w2_hi + (size_t)l * 3 * 128 * 128,
                w2_lo + (size_t)l * 3 * 128 * 128, (size_t)128 * 128,
                conv_b2 + l * 3 * 128, 128,
                X, 384, 128, NN, 1, stL + 256, 512, 3, G128);
        } else {
            // h_h = fp16_rne(relu(bn(zm2)))  (12.8 MB gather table)
            bn_relu_h<<<BN_GRID, 256, 0, stream>>>(
                zm2, stats + (size_t)((l - 1) * 8 + 7) * 256,
                mlp_bn2_g + (l - 1) * 128, mlp_bn2_b + (l - 1) * 128, h_h);
            // sb_k = (1+eps_k) h + agg_k(h)   (fp16 gather, half the bytes)
            agg_h<<<dim3(AGG_GRID, 3), 256, 0, stream>>>(
                h_h, rowptr0, csrc0, conv_eps, l * 3, sb);
            // W1: X[:, k*128..] = sb_k @ W1_k + b1 (raw A; stats -> slots 0/2/4)
            gemm_dir<0><<<G3, 256, 0, stream>>>(
                sb, (size_t)NN * 128, 128, 128,
                nullptr, 0, 0, nullptr, nullptr, 0, 0,
                rw1_hi + (size_t)(l - 1) * 3 * 128 * 128,
                rw1_lo + (size_t)(l - 1) * 3 * 128 * 128, (size_t)128 * 128,
                conv_rest_b1 + (l - 1) * 3 * 128, 128,
                X, 384, 128, NN, 1, stL, 512, 3, G128);
            // W2: sb[:, k*128..] = BN1(X slice k) @ W2_k + b2 (stats -> 1/3/5)
            gemm_dir<1><<<G3, 256, 0, stream>>>(
                X, 128, 384, 128,
                stL, 0, 512,
                conv_bn1_g + l * 3 * 128, conv_bn1_b + l * 3 * 128, 0, 128,
                w2_hi + (size_t)l * 3 * 128 * 128,
                w2_lo + (size_t)l * 3 * 128 * 128, (size_t)128 * 128,
                conv_b2 + l * 3 * 128, 128,
                sb, 384, 128, NN, 1, stL + 256, 512, 3, G128);
        }

        // fusion MLP layer 1: BN2(3 slices) @ mlp_W1 -> mlp1out (compact 128)
        gemm_dir<1><<<G128, 256, 0, stream>>>(
            mlp1in, 0, 384, 384,
            stL + 256, 512, 0,
            conv_bn2_g + l * 3 * 128, conv_bn2_b + l * 3 * 128, 128, 0,
            mw1_hi + (size_t)l * 128 * 384, mw1_lo + (size_t)l * 128 * 384, 0,
            mlp_b1 + l * 128, 0, mlp1out, 128, 0, NN, 1, slotF1, 0, 1, G128);

        // fusion MLP layer 2: BN(mlp1out) @ mlp_W2 -> zm2
        gemm_dir<1><<<G128, 256, 0, stream>>>(
            mlp1out, 0, 128, 128,
            slotF1, 0, 0,
            mlp_bn1_g + l * 128, mlp_bn1_b + l * 128, 0, 0,
            mw2_hi + (size_t)l * 128 * 128, mw2_lo + (size_t)l * 128 * 128, 0,
            mlp_b2 + l * 128, 0, zm2, 128, 0, NN, 1, slotF2, 0, 1, G128);
    }
    // final h = bn_relu(zm2, layer-5 F2 stats) -> X (compact [NN][128])
    bn_relu_f32<<<BN_GRID, 256, 0, stream>>>(
        zm2, stats + (size_t)(5 * 8 + 7) * 256,
        mlp_bn2_g + 5 * 128, mlp_bn2_b + 5 * 128, X);

    // ---- Set2Set readout (fp32) ----
    pack_wcat<<<(512 * 384 + 255) / 256, 256, 0, stream>>>(lstm_Wih, lstm_Whh, Wcat);
    for (int t = 0; t < 6; ++t) {
        gemm_f32<true><<<dim3(8, 4), 256, 0, stream>>>(
            S, Wcat, nullptr, gates, GG, 384, 512);
        lstm_kernel<<<(GG * 128 + 255) / 256, 256, 0, stream>>>(
            gates, lstm_bih, lstm_bhh, ccb, S);
        attend_kernel<<<GG, 256, 0, stream>>>(X, S, ews, gstart);
    }
    fc1_kernel<<<GG, 128, 0, stream>>>(S, fc1_W, fc1_b, gates);
    fc4_kernel<<<(GG * 12 + 255) / 256, 256, 0, stream>>>(gates, fc4_W, fc4_b, outp);
}

// Round 15
// 4395.643 us; speedup vs baseline: 1.3799x; 1.0012x over previous
//
#include <hip/hip_runtime.h>
#include <hip/hip_fp16.h>
#include <cstdint>
#include <cstddef>

#define NN 50000
#define EE 1600000
#define GG 512
#define FIN 1273

typedef unsigned short u16;
typedef unsigned int u32;
typedef __attribute__((ext_vector_type(8))) short short8;
typedef __attribute__((ext_vector_type(4))) float f32x4;

__device__ __forceinline__ float sigmf(float x) { return 1.f / (1.f + expf(-x)); }

// truncation split: v == hi + rem exactly; lo = bf16(rem); |v-(hi+lo)| <= 2^-16 |v|
__device__ __forceinline__ void splitbf(float v, u16& hi, u16& lo) {
    const u32 u = __float_as_uint(v);
    hi = (u16)(u >> 16);
    const float rem = v - __uint_as_float(u & 0xffff0000u);
    lo = (u16)(__float_as_uint(rem) >> 16);
}

__device__ __forceinline__ void gload_lds16(const void* g, void* l) {
    __builtin_amdgcn_global_load_lds(
        (const __attribute__((address_space(1))) void*)g,
        (__attribute__((address_space(3))) void*)l, 16, 0, 0);
}

// XCD-aware triplet remap: put the 3 mats of one row tile on the same XCD.
__device__ __forceinline__ bool remap3(int f, int nRow, int& mat, int& rt) {
    const int g = f / 24, w = f - g * 24;
    rt = g * 8 + (w & 7);
    mat = w >> 3;
    return rt < nRow;
}

// ===== layer-0 GEMM: split-bf16 MFMA, A = fp32 x staged via LDS ================
__global__ __launch_bounds__(256) void gemm_l0(
    const float* __restrict__ A, int lda, int K, int Kreal,
    const u16* __restrict__ Bhi, const u16* __restrict__ Blo, size_t strideB,
    float* __restrict__ C, int ldc, int coffStep, int M, int nRow)
{
    __shared__ u16 lsAhi[128 * 64];
    __shared__ u16 lsAlo[128 * 64];
    __shared__ u16 lsBhi[128 * 64];
    __shared__ u16 lsBlo[128 * 64];
    int mat, rt;
    if (!remap3(blockIdx.x, nRow, mat, rt)) return;
    const int tid = threadIdx.x;
    const int wave = tid >> 6, lane = tid & 63;
    const int row0 = rt * 128;
    const int coff = mat * coffStep;
    const u16* Bh = Bhi + (size_t)mat * strideB;
    const u16* Bl = Blo + (size_t)mat * strideB;
    const int wm = wave >> 1, wn = wave & 1;
    f32x4 acc[4][4] = {};

    for (int k0 = 0; k0 < K; k0 += 64) {
        if (k0) __syncthreads();
        #pragma unroll
        for (int i = 0; i < 4; ++i) {
            const int slot = i * 256 + tid;
            const int r = slot >> 3, ch = tid & 7;
            int gr = row0 + r; if (gr >= M) gr = M - 1;
            const int kb = k0 + ch * 8;
            u16 th[8], tl[8];
            const float* src = A + (size_t)gr * lda + kb;
            if (kb + 8 <= Kreal) {
                const float4 v0 = *(const float4*)(src);
                const float4 v1 = *(const float4*)(src + 4);
                const float va[8] = {v0.x, v0.y, v0.z, v0.w,
                                     v1.x, v1.y, v1.z, v1.w};
                #pragma unroll
                for (int e = 0; e < 8; ++e) splitbf(va[e], th[e], tl[e]);
            } else {
                #pragma unroll
                for (int e = 0; e < 8; ++e) {
                    const float v = (kb + e < Kreal) ? src[e] : 0.f;
                    splitbf(v, th[e], tl[e]);
                }
            }
            const int off = (r << 6) + ((ch ^ (r & 7)) << 3);
            *(short8*)&lsAhi[off] = *(const short8*)th;
            *(short8*)&lsAlo[off] = *(const short8*)tl;
        }
        #pragma unroll
        for (int i = 0; i < 4; ++i) {
            const int slot = i * 256 + wave * 64 + lane;
            const int r = slot >> 3, ch = slot & 7;
            const int sch = ch ^ (r & 7);
            const size_t goff = (size_t)r * K + k0 + sch * 8;
            const int lbase = (i * 256 + wave * 64) * 8;
            gload_lds16(Bh + goff, &lsBhi[lbase]);
            gload_lds16(Bl + goff, &lsBlo[lbase]);
        }
        __syncthreads();
        #pragma unroll
        for (int ks = 0; ks < 2; ++ks) {
            short8 ah[4], al[4], bh[4], bl[4];
            const int kch = ks * 4 + (lane >> 4);
            #pragma unroll
            for (int m = 0; m < 4; ++m) {
                const int r = wm * 64 + m * 16 + (lane & 15);
                const int off = (r << 6) + ((kch ^ (r & 7)) << 3);
                ah[m] = *(const short8*)&lsAhi[off];
                al[m] = *(const short8*)&lsAlo[off];
            }
            #pragma unroll
            for (int n = 0; n < 4; ++n) {
                const int c = wn * 64 + n * 16 + (lane & 15);
                const int off = (c << 6) + ((kch ^ (c & 7)) << 3);
                bh[n] = *(const short8*)&lsBhi[off];
                bl[n] = *(const short8*)&lsBlo[off];
            }
            #pragma unroll
            for (int m = 0; m < 4; ++m)
                #pragma unroll
                for (int n = 0; n < 4; ++n) {
                    acc[m][n] = __builtin_amdgcn_mfma_f32_16x16x32_bf16(
                        ah[m], bh[n], acc[m][n], 0, 0, 0);
                    acc[m][n] = __builtin_amdgcn_mfma_f32_16x16x32_bf16(
                        ah[m], bl[n], acc[m][n], 0, 0, 0);
                    acc[m][n] = __builtin_amdgcn_mfma_f32_16x16x32_bf16(
                        al[m], bh[n], acc[m][n], 0, 0, 0);
                }
        }
    }
    #pragma unroll
    for (int n = 0; n < 4; ++n) {
        const int c = wn * 64 + n * 16 + (lane & 15);
        #pragma unroll
        for (int m = 0; m < 4; ++m) {
            #pragma unroll
            for (int j = 0; j < 4; ++j) {
                const int gr = row0 + wm * 64 + m * 16 + ((lane >> 4) << 2) + j;
                if (gr < M)
                    C[(size_t)gr * ldc + coff + c] = acc[m][n][j];
            }
        }
    }
}

// ===== direct-A GEMM: A fp32 from global (no A LDS) ============================
template <int ABN>
__global__ __launch_bounds__(256) void gemm_dir(
    const float* __restrict__ A, size_t strideA, int lda, int K,
    const float* __restrict__ st, int stSlice, int stMat,
    const float* __restrict__ ga, const float* __restrict__ be,
    int gbSlice, int gbMat,
    const u16* __restrict__ Bhi, const u16* __restrict__ Blo, size_t strideB,
    const float* __restrict__ bias, int biasMat,
    float* __restrict__ C, int ldc, int coffStep,
    int M, int do_stats, float* __restrict__ stats_out, int ostatMat,
    int nMat, int nRow)
{
    __shared__ u16 lsBhi[128 * 64];
    __shared__ u16 lsBlo[128 * 64];
    int mat, rt;
    if (nMat == 3) {
        if (!remap3(blockIdx.x, nRow, mat, rt)) return;
    } else { mat = 0; rt = blockIdx.x; }
    const int tid = threadIdx.x;
    const int wave = tid >> 6, lane = tid & 63;
    const int row0 = rt * 128;
    const int wm = wave >> 1, wn = wave & 1;
    A += (size_t)mat * strideA;
    if (ABN) { st += mat * stMat; ga += mat * gbMat; be += mat * gbMat; }
    if (bias) bias += mat * biasMat;
    if (do_stats) stats_out += mat * ostatMat;
    const u16* Bh = Bhi + (size_t)mat * strideB;
    const u16* Bl = Blo + (size_t)mat * strideB;
    const int coff = mat * coffStep;
    f32x4 acc[4][4] = {};

    int arow[4];
    #pragma unroll
    for (int m = 0; m < 4; ++m) {
        int r = row0 + wm * 64 + m * 16 + (lane & 15);
        if (r >= M) r = M - 1;
        arow[m] = r;
    }

    for (int k0 = 0; k0 < K; k0 += 64) {
        if (k0) __syncthreads();
        #pragma unroll
        for (int i = 0; i < 4; ++i) {
            const int slot = i * 256 + wave * 64 + lane;
            const int r = slot >> 3, ch = slot & 7;
            const int sch = ch ^ (r & 7);
            const size_t goff = (size_t)r * K + k0 + sch * 8;
            const int lbase = (i * 256 + wave * 64) * 8;
            gload_lds16(Bh + goff, &lsBhi[lbase]);
            gload_lds16(Bl + goff, &lsBlo[lbase]);
        }
        __syncthreads();
        #pragma unroll
        for (int ks = 0; ks < 2; ++ks) {
            const int kch = ks * 4 + (lane >> 4);
            const int kb = k0 + kch * 8;
            float scv[8], shv[8];
            if (ABN) {
                const int s = kb >> 7, d0 = kb & 127;
                const float* stS = st + s * stSlice;
                const float* gS  = ga + s * gbSlice;
                const float* beS = be + s * gbSlice;
                #pragma unroll
                for (int e = 0; e < 8; ++e) {
                    const int d = d0 + e;
                    const float mu = stS[d] * (1.f / NN);
                    const float var = fmaxf(stS[128 + d] * (1.f / NN) - mu * mu, 0.f);
                    const float sc = gS[d] * rsqrtf(var + 1e-5f);
                    scv[e] = sc;
                    shv[e] = beS[d] - sc * mu;
                }
            }
            short8 ah[4], al[4];
            #pragma unroll
            for (int m = 0; m < 4; ++m) {
                const float* src = A + (size_t)arow[m] * lda + kb;
                const float4 v0 = *(const float4*)(src);
                const float4 v1 = *(const float4*)(src + 4);
                const float va[8] = {v0.x, v0.y, v0.z, v0.w,
                                     v1.x, v1.y, v1.z, v1.w};
                u16 th[8], tl[8];
                #pragma unroll
                for (int e = 0; e < 8; ++e) {
                    const float y = ABN
                        ? fmaxf(fmaf(scv[e], va[e], shv[e]), 0.f) : va[e];
                    splitbf(y, th[e], tl[e]);
                }
                ah[m] = *(const short8*)th;
                al[m] = *(const short8*)tl;
            }
            #pragma unroll
            for (int n = 0; n < 4; ++n) {
                const int c = wn * 64 + n * 16 + (lane & 15);
                const int off = (c << 6) + ((kch ^ (c & 7)) << 3);
                const short8 bh = *(const short8*)&lsBhi[off];
                const short8 bl = *(const short8*)&lsBlo[off];
                #pragma unroll
                for (int m = 0; m < 4; ++m) {
                    acc[m][n] = __builtin_amdgcn_mfma_f32_16x16x32_bf16(
                        ah[m], bh, acc[m][n], 0, 0, 0);
                    acc[m][n] = __builtin_amdgcn_mfma_f32_16x16x32_bf16(
                        ah[m], bl, acc[m][n], 0, 0, 0);
                    acc[m][n] = __builtin_amdgcn_mfma_f32_16x16x32_bf16(
                        al[m], bh, acc[m][n], 0, 0, 0);
                }
            }
        }
    }

    float colsum[4] = {0.f, 0.f, 0.f, 0.f}, colsq[4] = {0.f, 0.f, 0.f, 0.f};
    #pragma unroll
    for (int n = 0; n < 4; ++n) {
        const int c = wn * 64 + n * 16 + (lane & 15);
        const float bv = bias ? bias[c] : 0.f;
        #pragma unroll
        for (int m = 0; m < 4; ++m) {
            #pragma unroll
            for (int j = 0; j < 4; ++j) {
                const int gr = row0 + wm * 64 + m * 16 + ((lane >> 4) << 2) + j;
                if (gr < M) {
                    const float v = acc[m][n][j] + bv;
                    C[(size_t)gr * ldc + coff + c] = v;
                    colsum[n] += v; colsq[n] += v * v;
                }
            }
        }
    }
    if (do_stats) {
        float* ssum = (float*)lsBhi;
        float* ssq  = ssum + 128;
        __syncthreads();
        if (tid < 128) { ssum[tid] = 0.f; ssq[tid] = 0.f; }
        __syncthreads();
        #pragma unroll
        for (int n = 0; n < 4; ++n) {
            const int c = wn * 64 + n * 16 + (lane & 15);
            atomicAdd(&ssum[c], colsum[n]);
            atomicAdd(&ssq[c], colsq[n]);
        }
        __syncthreads();
        if (tid < 128) {
            atomicAdd(&stats_out[tid],       ssum[tid]);
            atomicAdd(&stats_out[128 + tid], ssq[tid]);
        }
    }
}

// ------ weight transpose+split: W[nmat][K][128] -> Whi/Wlo[nmat][128][Kpad] ----
__global__ __launch_bounds__(256) void wt_cast2(const float* __restrict__ W,
                                                u16* __restrict__ Whi,
                                                u16* __restrict__ Wlo,
                                                int total, int K, int Kpad) {
    const int idx = blockIdx.x * 256 + threadIdx.x;
    if (idx >= total) return;
    const int perm = 128 * Kpad;
    const int m = idx / perm, rem = idx - m * perm;
    const int n = rem / Kpad, k = rem - n * Kpad;
    const float v = (k < K) ? W[(size_t)m * K * 128 + (size_t)k * 128 + n] : 0.f;
    u16 hi, lo;
    splitbf(v, hi, lo);
    Whi[idx] = hi; Wlo[idx] = lo;
}

// ---------------- fp32 tiled GEMM (LSTM gates only) ----------------------------
template <bool BT>
__global__ __launch_bounds__(256) void gemm_f32(
    const float* __restrict__ A, const float* __restrict__ B,
    const float* __restrict__ bias, float* __restrict__ C,
    int M, int K, int Nc)
{
    __shared__ float As[32][68];
    __shared__ float Bs[32][132];
    const int tid = threadIdx.x;
    const int tx = tid & 15, ty = tid >> 4;
    const int row0 = blockIdx.x * 64, col0 = blockIdx.y * 128;
    float acc[4][8] = {};
    for (int k0 = 0; k0 < K; k0 += 32) {
        {
            const int kk = tid & 31, rb = tid >> 5;
            #pragma unroll
            for (int i = 0; i < 8; ++i) {
                const int r = rb + i * 8, gr = row0 + r, gk = k0 + kk;
                As[kk][r] = (gr < M && gk < K) ? A[(size_t)gr * K + gk] : 0.f;
            }
        }
        if (!BT) {
            const int c = tid & 127, kb = tid >> 7;
            #pragma unroll
            for (int i = 0; i < 16; ++i) {
                const int kk = kb + i * 2, gk = k0 + kk;
                Bs[kk][c] = (gk < K) ? B[(size_t)gk * Nc + col0 + c] : 0.f;
            }
        } else {
            const int kk = tid & 31, cb = tid >> 5;
            #pragma unroll
            for (int i = 0; i < 16; ++i) {
                const int c = cb + i * 8, gk = k0 + kk;
                Bs[kk][c] = (gk < K) ? B[(size_t)(col0 + c) * K + gk] : 0.f;
            }
        }
        __syncthreads();
        #pragma unroll 8
        for (int kk = 0; kk < 32; ++kk) {
            const float4 av  = *(const float4*)&As[kk][ty * 4];
            const float4 bv0 = *(const float4*)&Bs[kk][tx * 8];
            const float4 bv1 = *(const float4*)&Bs[kk][tx * 8 + 4];
            const float a[4] = {av.x, av.y, av.z, av.w};
            const float b[8] = {bv0.x, bv0.y, bv0.z, bv0.w, bv1.x, bv1.y, bv1.z, bv1.w};
            #pragma unroll
            for (int i = 0; i < 4; ++i)
                #pragma unroll
                for (int j = 0; j < 8; ++j)
                    acc[i][j] = fmaf(a[i], b[j], acc[i][j]);
        }
        __syncthreads();
    }
    #pragma unroll
    for (int j = 0; j < 8; ++j) {
        const float bv = bias ? bias[col0 + tx * 8 + j] : 0.f;
        #pragma unroll
        for (int i = 0; i < 4; ++i) acc[i][j] += bv;
    }
    #pragma unroll
    for (int i = 0; i < 4; ++i) {
        const int gr = row0 + ty * 4 + i;
        if (gr < M) {
            *(float4*)&C[(size_t)gr * Nc + col0 + tx * 8] =
                make_float4(acc[i][0], acc[i][1], acc[i][2], acc[i][3]);
            *(float4*)&C[(size_t)gr * Nc + col0 + tx * 8 + 4] =
                make_float4(acc[i][4], acc[i][5], acc[i][6], acc[i][7]);
        }
    }
}

// ---------------- batched CSR build (3 edge sets via blockIdx.y) ---------------
__global__ __launch_bounds__(256) void count_deg3(
    const int* __restrict__ e0, const int* __restrict__ e1,
    const int* __restrict__ e2, int* __restrict__ deg3)
{
    const int k = blockIdx.y;
    const int* ei = (k == 0) ? e0 : (k == 1 ? e1 : e2);
    const int e = blockIdx.x * 256 + threadIdx.x;
    if (e < EE) atomicAdd(&deg3[(size_t)k * NN + ei[EE + e]], 1);
}

__global__ __launch_bounds__(512) void scan1(const int* __restrict__ deg3,
                                             int* __restrict__ scanned3,
                                             int* __restrict__ bsum3) {
    __shared__ int s[512];
    const int k = blockIdx.y;
    const int* deg = deg3 + (size_t)k * NN;
    int* scanned   = scanned3 + (size_t)k * NN;
    int* bsum      = bsum3 + (size_t)k * 128;
    const int t = threadIdx.x;
    const int i = blockIdx.x * 512 + t;
    const int v = (i < NN) ? deg[i] : 0;
    s[t] = v; __syncthreads();
    for (int o = 1; o < 512; o <<= 1) {
        const int tv = (t >= o) ? s[t - o] : 0;
        __syncthreads();
        s[t] += tv;
        __syncthreads();
    }
    if (i < NN) scanned[i] = s[t];
    if (t == 511) bsum[blockIdx.x] = s[511];
}

__global__ __launch_bounds__(128) void scan2(int* __restrict__ bsum3, int nb) {
    __shared__ int s[128];
    int* bsum = bsum3 + (size_t)blockIdx.y * 128;
    const int t = threadIdx.x;
    const int v = (t < nb) ? bsum[t] : 0;
    s[t] = v; __syncthreads();
    for (int o = 1; o < 128; o <<= 1) {
        const int tv = (t >= o) ? s[t - o] : 0;
        __syncthreads();
        s[t] += tv;
        __syncthreads();
    }
    if (t < nb) bsum[t] = s[t] - v;  // exclusive
}

__global__ __launch_bounds__(256) void scan3(const int* __restrict__ deg3,
                                             const int* __restrict__ scanned3,
                                             const int* __restrict__ bsum3,
                                             int* __restrict__ rowptr0,
                                             int* __restrict__ cursor3) {
    const int k = blockIdx.y;
    const int* deg = deg3 + (size_t)k * NN;
    const int* scanned = scanned3 + (size_t)k * NN;
    const int* bsum = bsum3 + (size_t)k * 128;
    int* rowptr = rowptr0 + (size_t)k * (NN + 1);
    int* cursor = cursor3 + (size_t)k * NN;
    const int i = blockIdx.x * 256 + threadIdx.x;
    if (i < NN) {
        const int v = bsum[i >> 9] + scanned[i] - deg[i];
        rowptr[i] = v; cursor[i] = v;
    }
    if (i == 0) rowptr[NN] = EE;
}

__global__ __launch_bounds__(256) void fill_csr3(
    const int* __restrict__ e0, const int* __restrict__ e1,
    const int* __restrict__ e2, int* __restrict__ cursor3,
    u16* __restrict__ csrc0)
{
    const int k = blockIdx.y;
    const int* ei = (k == 0) ? e0 : (k == 1 ? e1 : e2);
    const int e = blockIdx.x * 256 + threadIdx.x;
    if (e < EE) {
        const int s = ei[e];
        const int pos = atomicAdd(&cursor3[(size_t)k * NN + ei[EE + e]], 1);
        csrc0[(size_t)k * EE + pos] = (u16)s;
    }
}

// ==== layer-0 fused aggregate + combine (fp32 gather, 3 edge sets) =============
__global__ __launch_bounds__(256) void agg_combine(
    const float* __restrict__ X, int ldp4,
    const int* __restrict__ rowptrB, const u16* __restrict__ csrcB,
    const float* __restrict__ b1B,
    const float* __restrict__ eps_arr, int epsBase,
    float* __restrict__ zB, float* __restrict__ statsB)
{
    __shared__ float red[256];
    const int k = blockIdx.y;
    const int* rowptr = rowptrB + (size_t)k * (NN + 1);
    const u16* csrc   = csrcB + (size_t)k * EE;
    float* z          = zB + (size_t)k * NN * 128;
    const int tid = threadIdx.x, lane = tid & 63, wave = tid >> 6;
    const float e1 = 1.f + eps_arr[epsBase + k];
    const int half = lane >> 5;
    const int l32 = lane & 31;
    const float4* p4 = (const float4*)X + k * 32;
    float s[4] = {0.f, 0.f, 0.f, 0.f}, q[4] = {0.f, 0.f, 0.f, 0.f};
    float4 bv = make_float4(0.f, 0.f, 0.f, 0.f);
    if (lane < 32) bv = ((const float4*)(b1B + k * 128))[l32];
    red[tid] = 0.f;
    __syncthreads();
    const int nbase = blockIdx.x * 16 + wave * 4;
    for (int t = 0; t < 4; ++t) {
        const int wid = nbase + t;
        const int s0 = rowptr[wid], s1 = rowptr[wid + 1];
        float ax = 0.f, ay = 0.f, az = 0.f, aw = 0.f;
        int j = s0;
        for (; j + 15 < s1; j += 16) {
            float4 v[8];
            #pragma unroll
            for (int u = 0; u < 8; ++u)
                v[u] = p4[(size_t)csrc[j + 2 * u + half] * ldp4 + l32];
            #pragma unroll
            for (int u = 0; u < 8; ++u) {
                ax += v[u].x; ay += v[u].y; az += v[u].z; aw += v[u].w;
            }
        }
        for (; j + 7 < s1; j += 8) {
            float4 v[4];
            #pragma unroll
            for (int u = 0; u < 4; ++u)
                v[u] = p4[(size_t)csrc[j + 2 * u + half] * ldp4 + l32];
            #pragma unroll
            for (int u = 0; u < 4; ++u) {
                ax += v[u].x; ay += v[u].y; az += v[u].z; aw += v[u].w;
            }
        }
        for (; j + 3 < s1; j += 4) {
            const float4 v0 = p4[(size_t)csrc[j + half] * ldp4 + l32];
            const float4 v1 = p4[(size_t)csrc[j + 2 + half] * ldp4 + l32];
            ax += v0.x + v1.x; ay += v0.y + v1.y;
            az += v0.z + v1.z; aw += v0.w + v1.w;
        }
        for (; j + 1 < s1; j += 2) {
            const float4 v0 = p4[(size_t)csrc[j + half] * ldp4 + l32];
            ax += v0.x; ay += v0.y; az += v0.z; aw += v0.w;
        }
        if (j < s1 && half == 0) {
            const float4 v0 = p4[(size_t)csrc[j] * ldp4 + l32];
            ax += v0.x; ay += v0.y; az += v0.z; aw += v0.w;
        }
        ax += __shfl_down(ax, 32, 64);
        ay += __shfl_down(ay, 32, 64);
        az += __shfl_down(az, 32, 64);
        aw += __shfl_down(aw, 32, 64);
        if (lane < 32) {
            const float4 self = p4[(size_t)wid * ldp4 + l32];
            float4 zv;
            zv.x = fmaf(e1, self.x, ax + bv.x);
            zv.y = fmaf(e1, self.y, ay + bv.y);
            zv.z = fmaf(e1, self.z, az + bv.z);
            zv.w = fmaf(e1, self.w, aw + bv.w);
            ((float4*)z)[(size_t)wid * 32 + l32] = zv;
            s[0] += zv.x; s[1] += zv.y; s[2] += zv.z; s[3] += zv.w;
            q[0] += zv.x * zv.x; q[1] += zv.y * zv.y;
            q[2] += zv.z * zv.z; q[3] += zv.w * zv.w;
        }
    }
    if (lane < 32) {
        const int d = l32 * 4;
        #pragma unroll
        for (int c = 0; c < 4; ++c) {
            atomicAdd(&red[d + c], s[c]);
            atomicAdd(&red[128 + d + c], q[c]);
        }
    }
    __syncthreads();
    atomicAdd(&statsB[(size_t)k * 512 + tid], red[tid]);
}

// ==== l>=1 aggregate + combine over fp16 h rows (half the gather bytes) ========
__global__ __launch_bounds__(256) void agg_h(
    const u16* __restrict__ Hh,
    const int* __restrict__ rowptrB, const u16* __restrict__ csrcB,
    const float* __restrict__ eps_arr, int epsBase,
    float* __restrict__ zB)
{
    const int k = blockIdx.y;
    const int* rowptr = rowptrB + (size_t)k * (NN + 1);
    const u16* csrc   = csrcB + (size_t)k * EE;
    float* z          = zB + (size_t)k * NN * 128;
    const int tid = threadIdx.x, lane = tid & 63, wave = tid >> 6;
    const float e1 = 1.f + eps_arr[epsBase + k];
    const u32* p = (const u32*)Hh;   // [NN][64]
    const int nbase = blockIdx.x * 16 + wave * 4;
    #pragma unroll
    for (int t = 0; t < 4; ++t) {
        const int wid = nbase + t;
        const int s0 = rowptr[wid], s1 = rowptr[wid + 1];
        float ax = 0.f, ay = 0.f;
        int j = s0;
        for (; j + 15 < s1; j += 16) {
            u32 v[16];
            #pragma unroll
            for (int u = 0; u < 16; ++u)
                v[u] = p[(size_t)csrc[j + u] * 64 + lane];
            #pragma unroll
            for (int u = 0; u < 16; ++u) {
                const float2 fv = __half22float2(*(const __half2*)&v[u]);
                ax += fv.x; ay += fv.y;
            }
        }
        for (; j + 7 < s1; j += 8) {
            u32 v[8];
            #pragma unroll
            for (int u = 0; u < 8; ++u)
                v[u] = p[(size_t)csrc[j + u] * 64 + lane];
            #pragma unroll
            for (int u = 0; u < 8; ++u) {
                const float2 fv = __half22float2(*(const __half2*)&v[u]);
                ax += fv.x; ay += fv.y;
            }
        }
        for (; j < s1; ++j) {
            const u32 v = p[(size_t)csrc[j] * 64 + lane];
            const float2 fv = __half22float2(*(const __half2*)&v);
            ax += fv.x; ay += fv.y;
        }
        const u32 sv = p[(size_t)wid * 64 + lane];
        const float2 sf = __half22float2(*(const __half2*)&sv);
        float2 zv;
        zv.x = fmaf(e1, sf.x, ax);
        zv.y = fmaf(e1, sf.y, ay);
        ((float2*)z)[(size_t)wid * 64 + lane] = zv;
    }
}

// ------- BN + ReLU -> fp16 rows for the gather ---------------------------------
__global__ __launch_bounds__(256) void bn_relu_h(
    const float* __restrict__ xin, const float* __restrict__ stats,
    const float* __restrict__ gamma, const float* __restrict__ beta,
    u16* __restrict__ out)
{
    const size_t i = (size_t)blockIdx.x * 256 + threadIdx.x;  // pair index
    if (i >= (size_t)NN * 64) return;
    const int d = (int)(i & 63) * 2;
    const float inv_n = 1.f / NN;
    const float mu0 = stats[d] * inv_n,     mu1 = stats[d + 1] * inv_n;
    const float v0 = fmaxf(stats[128 + d] * inv_n - mu0 * mu0, 0.f);
    const float v1 = fmaxf(stats[129 + d] * inv_n - mu1 * mu1, 0.f);
    const float s0 = gamma[d] * rsqrtf(v0 + 1e-5f);
    const float s1 = gamma[d + 1] * rsqrtf(v1 + 1e-5f);
    const float2 xv = ((const float2*)xin)[i];
    const float y0 = fmaxf(fmaf(s0, xv.x - mu0, beta[d]), 0.f);
    const float y1 = fmaxf(fmaf(s1, xv.y - mu1, beta[d + 1]), 0.f);
    const __half2 hv = __floats2half2_rn(y0, y1);
    ((u32*)out)[i] = *(const u32*)&hv;
}

// ------- BN + ReLU -> fp32 (final h only) --------------------------------------
__global__ __launch_bounds__(256) void bn_relu_f32(
    const float* __restrict__ xin, const float* __restrict__ stats,
    const float* __restrict__ gamma, const float* __restrict__ beta,
    float* __restrict__ out)
{
    const size_t i = (size_t)blockIdx.x * 256 + threadIdx.x;  // pair index
    if (i >= (size_t)NN * 64) return;
    const int d = (int)(i & 63) * 2;
    const float inv_n = 1.f / NN;
    const float mu0 = stats[d] * inv_n,     mu1 = stats[d + 1] * inv_n;
    const float v0 = fmaxf(stats[128 + d] * inv_n - mu0 * mu0, 0.f);
    const float v1 = fmaxf(stats[129 + d] * inv_n - mu1 * mu1, 0.f);
    const float s0 = gamma[d] * rsqrtf(v0 + 1e-5f);
    const float s1 = gamma[d + 1] * rsqrtf(v1 + 1e-5f);
    const float2 xv = ((const float2*)xin)[i];
    const float y0 = fmaxf(fmaf(s0, xv.x - mu0, beta[d]), 0.f);
    const float y1 = fmaxf(fmaf(s1, xv.y - mu1, beta[d + 1]), 0.f);
    ((float2*)out)[i] = make_float2(y0, y1);
}

// ---------------- per-graph segment starts (batch is sorted) -------------------
__global__ __launch_bounds__(256) void seg_starts(const int* __restrict__ batch,
                                                  int* __restrict__ gstart) {
    const int i = blockIdx.x * 256 + threadIdx.x;
    if (i >= NN) return;
    const int b = batch[i];
    if (i == 0) { for (int g = 0; g <= b; ++g) gstart[g] = 0; }
    else {
        const int pb = batch[i - 1];
        for (int g = pb + 1; g <= b; ++g) gstart[g] = i;
    }
    if (i == NN - 1) { for (int g = b + 1; g <= GG; ++g) gstart[g] = NN; }
}

// ---------------- Set2Set ------------------------------------------------------
__global__ __launch_bounds__(256) void pack_wcat(const float* __restrict__ Wih,
                                                 const float* __restrict__ Whh,
                                                 float* __restrict__ Wcat) {
    const int i = blockIdx.x * 256 + threadIdx.x;
    if (i >= 512 * 384) return;
    const int j = i / 384, k = i - j * 384;
    Wcat[i] = (k < 256) ? Wih[j * 256 + k] : Whh[j * 128 + (k - 256)];
}

__global__ __launch_bounds__(256) void lstm_kernel(
    const float* __restrict__ gates, const float* __restrict__ bih,
    const float* __restrict__ bhh, float* __restrict__ cc, float* __restrict__ S)
{
    const int i = blockIdx.x * 256 + threadIdx.x;
    if (i >= GG * 128) return;
    const int g = i >> 7, d = i & 127;
    const float* gr = gates + (size_t)g * 512;
    const float ig = gr[d]       + bih[d]       + bhh[d];
    const float fg = gr[128 + d] + bih[128 + d] + bhh[128 + d];
    const float gv = gr[256 + d] + bih[256 + d] + bhh[256 + d];
    const float og = gr[384 + d] + bih[384 + d] + bhh[384 + d];
    const float c  = sigmf(fg) * cc[i] + sigmf(ig) * tanhf(gv);
    const float hv = sigmf(og) * tanhf(c);
    cc[i] = c;
    S[(size_t)g * 384 + d] = hv;
    S[(size_t)g * 384 + 256 + d] = hv;
}

__global__ __launch_bounds__(256) void attend_kernel(
    const float* __restrict__ h, float* __restrict__ S,
    float* __restrict__ ews, const int* __restrict__ gstart)
{
    const int g = blockIdx.x;
    const int rs = gstart[g], re = gstart[g + 1];
    const int tid = threadIdx.x, lane = tid & 63, w = tid >> 6;
    __shared__ float q[128];
    __shared__ float red[8];
    __shared__ float racc[4][128];
    if (tid < 128) q[tid] = S[(size_t)g * 384 + 256 + tid];
    __syncthreads();
    const float2* h2 = (const float2*)h;
    float lmax = -1e30f;
    for (int n = rs + w; n < re; n += 4) {
        const float2 hv = h2[(size_t)n * 64 + lane];
        float p = hv.x * q[2 * lane] + hv.y * q[2 * lane + 1];
        #pragma unroll
        for (int o = 32; o; o >>= 1) p += __shfl_down(p, o, 64);
        if (lane == 0) { ews[n] = p; lmax = fmaxf(lmax, p); }
    }
    if (lane == 0) red[w] = lmax;
    __syncthreads();
    const float m = fmaxf(fmaxf(red[0], red[1]), fmaxf(red[2], red[3]));
    __syncthreads();
    float lsum = 0.f;
    for (int n = rs + tid; n < re; n += 256) {
        const float ex = expf(ews[n] - m);
        ews[n] = ex; lsum += ex;
    }
    #pragma unroll
    for (int o = 32; o; o >>= 1) lsum += __shfl_down(lsum, o, 64);
    if (lane == 0) red[w] = lsum;
    __syncthreads();
    const float denom = red[0] + red[1] + red[2] + red[3];
    // ---- r phase: all 4 waves accumulate partial weighted sums ----
    float rx = 0.f, ry = 0.f;
    for (int n = rs + w; n < re; n += 4) {
        const float a = ews[n];
        const float2 hv = h2[(size_t)n * 64 + lane];
        rx = fmaf(a, hv.x, rx);
        ry = fmaf(a, hv.y, ry);
    }
    racc[w][2 * lane] = rx;
    racc[w][2 * lane + 1] = ry;
    __syncthreads();
    if (tid < 128) {
        const float rsum = racc[0][tid] + racc[1][tid] + racc[2][tid] + racc[3][tid];
        S[(size_t)g * 384 + 128 + tid] = (denom > 0.f) ? rsum / denom : 0.f;
    }
}

__global__ __launch_bounds__(128) void fc1_kernel(const float* __restrict__ S,
                                                  const float* __restrict__ W,
                                                  const float* __restrict__ b,
                                                  float* __restrict__ out1) {
    const int g = blockIdx.x, d = threadIdx.x;
    __shared__ float qs[256];
    qs[d] = S[(size_t)g * 384 + d];
    qs[128 + d] = S[(size_t)g * 384 + 128 + d];
    __syncthreads();
    float acc = b[d];
    for (int k = 0; k < 256; ++k) acc = fmaf(qs[k], W[k * 128 + d], acc);
    out1[(size_t)g * 128 + d] = fmaxf(acc, 0.f);
}

__global__ __launch_bounds__(256) void fc4_kernel(const float* __restrict__ out1,
                                                  const float* __restrict__ W,
                                                  const float* __restrict__ b,
                                                  float* __restrict__ out) {
    const int i = blockIdx.x * 256 + threadIdx.x;
    if (i >= GG * 12) return;
    const int g = i / 12, j = i - g * 12;
    float acc = b[j];
    for (int d = 0; d < 128; ++d)
        acc = fmaf(out1[(size_t)g * 128 + d], W[d * 12 + j], acc);
    out[i] = acc;
}

// ================================================================================
extern "C" void kernel_launch(void* const* d_in, const int* in_sizes, int n_in,
                              void* d_out, int out_size, void* d_ws, size_t ws_size,
                              hipStream_t stream)
{
    const float* x        = (const float*)d_in[0];
    const int*   eidx[3]  = {(const int*)d_in[1], (const int*)d_in[2], (const int*)d_in[3]};
    const int*   batch    = (const int*)d_in[4];
    const float* conv1_W1     = (const float*)d_in[5];
    const float* conv1_b1     = (const float*)d_in[6];
    const float* conv_rest_W1 = (const float*)d_in[7];
    const float* conv_rest_b1 = (const float*)d_in[8];
    const float* conv_W2      = (const float*)d_in[9];
    const float* conv_b2      = (const float*)d_in[10];
    const float* conv_bn1_g   = (const float*)d_in[11];
    const float* conv_bn1_b   = (const float*)d_in[12];
    const float* conv_bn2_g   = (const float*)d_in[13];
    const float* conv_bn2_b   = (const float*)d_in[14];
    const float* conv_eps     = (const float*)d_in[15];
    const float* mlp_W1       = (const float*)d_in[16];
    const float* mlp_b1       = (const float*)d_in[17];
    const float* mlp_bn1_g    = (const float*)d_in[18];
    const float* mlp_bn1_b    = (const float*)d_in[19];
    const float* mlp_W2       = (const float*)d_in[20];
    const float* mlp_b2       = (const float*)d_in[21];
    const float* mlp_bn2_g    = (const float*)d_in[22];
    const float* mlp_bn2_b    = (const float*)d_in[23];
    const float* lstm_Wih     = (const float*)d_in[24];
    const float* lstm_Whh     = (const float*)d_in[25];
    const float* lstm_bih     = (const float*)d_in[26];
    const float* lstm_bhh     = (const float*)d_in[27];
    const float* fc1_W        = (const float*)d_in[28];
    const float* fc1_b        = (const float*)d_in[29];
    const float* fc4_W        = (const float*)d_in[30];
    const float* fc4_b        = (const float*)d_in[31];
    float* outp = (float*)d_out;

    // ---- workspace layout ----
    float* f = (float*)d_ws;
    size_t fo = 0;
    float* X     = f + fo; fo += (size_t)NN * 384;  // proj / z (l>=1) / mlp1-out / final h
    float* sb    = f + fo; fo += (size_t)NN * 384;  // agg out (stacked) / W2 out (l>=1)
    float* zm2   = f + fo; fo += (size_t)NN * 128;  // mlp2 out (layer state)
    float* ews   = f + fo; fo += NN;
    float* stats = f + fo; fo += 48 * 256;
    float* S     = f + fo; fo += (size_t)GG * 384;
    float* ccb   = f + fo; fo += (size_t)GG * 128;
    float* gates = f + fo; fo += (size_t)GG * 512;  // reused as fc1 output
    float* Wcat  = f + fo; fo += (size_t)512 * 384;
    fo = (fo + 7) & ~(size_t)7;   // 16B-align bf16 region
    u16* b = (u16*)(f + fo);
    size_t bo = 0;
    u16* h_h     = b + bo; bo += (size_t)NN * 128;  // fp16 h rows for the gather
    u16* csrc0   = b + bo; bo += (size_t)3 * EE;    // u16 src indices (NN < 65536)
    u16* c1_hi   = b + bo; bo += (size_t)3 * 128 * 1280;
    u16* c1_lo   = b + bo; bo += (size_t)3 * 128 * 1280;
    u16* rw1_hi  = b + bo; bo += (size_t)15 * 128 * 128;
    u16* rw1_lo  = b + bo; bo += (size_t)15 * 128 * 128;
    u16* w2_hi   = b + bo; bo += (size_t)18 * 128 * 128;
    u16* w2_lo   = b + bo; bo += (size_t)18 * 128 * 128;
    u16* mw1_hi  = b + bo; bo += (size_t)6 * 128 * 384;
    u16* mw1_lo  = b + bo; bo += (size_t)6 * 128 * 384;
    u16* mw2_hi  = b + bo; bo += (size_t)6 * 128 * 128;
    u16* mw2_lo  = b + bo; bo += (size_t)6 * 128 * 128;
    bo = (bo + 1) & ~(size_t)1;   // 4B-align int region
    int* ip = (int*)(b + bo);
    size_t io = 0;
    int* rowptr0 = ip + io; io += (size_t)3 * (NN + 1);
    int* deg3    = ip + io; io += (size_t)3 * NN;
    int* cursor3 = ip + io; io += (size_t)3 * NN;
    int* scan3d  = ip + io; io += (size_t)3 * NN;
    int* bsum3   = ip + io; io += 3 * 128;
    int* gstart  = ip + io; io += GG + 1;
    const size_t need = fo * 4 + bo * 2 + io * 4;
    if (ws_size < need) return;

    const int NBLK_SCAN = (NN + 511) / 512;

    // ---- weight transpose+split (K padded to x64) ----
    {
        int t;
        t = 3 * 128 * 1280;
        wt_cast2<<<(t + 255) / 256, 256, 0, stream>>>(conv1_W1, c1_hi, c1_lo, t, FIN, 1280);
        t = 15 * 128 * 128;
        wt_cast2<<<(t + 255) / 256, 256, 0, stream>>>(conv_rest_W1, rw1_hi, rw1_lo, t, 128, 128);
        t = 18 * 128 * 128;
        wt_cast2<<<(t + 255) / 256, 256, 0, stream>>>(conv_W2, w2_hi, w2_lo, t, 128, 128);
        t = 6 * 128 * 384;
        wt_cast2<<<(t + 255) / 256, 256, 0, stream>>>(mlp_W1, mw1_hi, mw1_lo, t, 384, 384);
        t = 6 * 128 * 128;
        wt_cast2<<<(t + 255) / 256, 256, 0, stream>>>(mlp_W2, mw2_hi, mw2_lo, t, 128, 128);
    }

    // ---- batched CSR build for the 3 edge sets (u16 src indices) ----
    hipMemsetAsync(deg3, 0, (size_t)3 * NN * sizeof(int), stream);
    count_deg3<<<dim3((EE + 255) / 256, 3), 256, 0, stream>>>(
        eidx[0], eidx[1], eidx[2], deg3);
    scan1<<<dim3(NBLK_SCAN, 3), 512, 0, stream>>>(deg3, scan3d, bsum3);
    scan2<<<dim3(1, 3), 128, 0, stream>>>(bsum3, NBLK_SCAN);
    scan3<<<dim3((NN + 255) / 256, 3), 256, 0, stream>>>(
        deg3, scan3d, bsum3, rowptr0, cursor3);
    fill_csr3<<<dim3((EE + 255) / 256, 3), 256, 0, stream>>>(
        eidx[0], eidx[1], eidx[2], cursor3, csrc0);

    seg_starts<<<(NN + 255) / 256, 256, 0, stream>>>(batch, gstart);
    hipMemsetAsync(stats, 0, 48 * 256 * sizeof(float), stream);
    hipMemsetAsync(S, 0, (size_t)GG * 384 * sizeof(float), stream);
    hipMemsetAsync(ccb, 0, (size_t)GG * 128 * sizeof(float), stream);

    const int G128 = (NN + 127) / 128;                 // 391 row tiles
    const int G3   = 24 * ((G128 + 7) / 8);            // 1176 (triplet remap grid)
    const int AGG_GRID = NN / 16;                      // 3125 x-blocks
    const int BN_GRID = (NN * 64 + 255) / 256;

    // ---- 6 GIN layers ----
    for (int l = 0; l < 6; ++l) {
        float* stL    = stats + (size_t)l * 8 * 256;
        float* slotF1 = stL + 6 * 256;
        float* slotF2 = stL + 7 * 256;
        float* mlp1in  = (l == 0) ? X : sb;     // [NN][384] W2 outputs
        float* mlp1out = (l == 0) ? sb : X;     // [NN][128] compact

        if (l == 0) {
            // proj-first: X[:, k*128..] = x @ W1_k
            gemm_l0<<<G3, 256, 0, stream>>>(
                x, FIN, 1280, FIN, c1_hi, c1_lo, (size_t)128 * 1280,
                X, 384, 128, NN, G128);
            // z_k = (1+eps)proj + agg + b1 (fp32 gather; stats -> slots 0/2/4)
            agg_combine<<<dim3(AGG_GRID, 3), 256, 0, stream>>>(
                X, 96, rowptr0, csrc0, conv1_b1, conv_eps, 0, sb, stL);
            // W2: X[:, k*128..] = BN1(z_k) @ W2_k + b2 (stats -> slots 1/3/5)
            gemm_dir<1><<<G3, 256, 0, stream>>>(
                sb, (size_t)NN * 128, 128, 128,
                stL, 0, 512,
                conv_bn1_g + l * 3 * 128, conv_bn1_b + l * 3 * 128, 0, 128,
                w2_hi + (size_t)l * 3 * 128 * 128,
                w2_lo + (size_t)l * 3 * 128 * 128, (size_t)128 * 128,
                conv_b2 + l * 3 * 128, 128,
                X, 384, 128, NN, 1, stL + 256, 512, 3, G128);
        } else {
            // h_h = fp16_rne(relu(bn(zm2)))  (12.8 MB gather table)
            bn_relu_h<<<BN_GRID, 256, 0, stream>>>(
                zm2, stats + (size_t)((l - 1) * 8 + 7) * 256,
                mlp_bn2_g + (l - 1) * 128, mlp_bn2_b + (l - 1) * 128, h_h);
            // sb_k = (1+eps_k) h + agg_k(h)   (fp16 gather, half the bytes)
            agg_h<<<dim3(AGG_GRID, 3), 256, 0, stream>>>(
                h_h, rowptr0, csrc0, conv_eps, l * 3, sb);
            // W1: X[:, k*128..] = sb_k @ W1_k + b1 (raw A; stats -> slots 0/2/4)
            gemm_dir<0><<<G3, 256, 0, stream>>>(
                sb, (size_t)NN * 128, 128, 128,
                nullptr, 0, 0, nullptr, nullptr, 0, 0,
                rw1_hi + (size_t)(l - 1) * 3 * 128 * 128,
                rw1_lo + (size_t)(l - 1) * 3 * 128 * 128, (size_t)128 * 128,
                conv_rest_b1 + (l - 1) * 3 * 128, 128,
                X, 384, 128, NN, 1, stL, 512, 3, G128);
            // W2: sb[:, k*128..] = BN1(X slice k) @ W2_k + b2 (stats -> 1/3/5)
            gemm_dir<1><<<G3, 256, 0, stream>>>(
                X, 128, 384, 128,
                stL, 0, 512,
                conv_bn1_g + l * 3 * 128, conv_bn1_b + l * 3 * 128, 0, 128,
                w2_hi + (size_t)l * 3 * 128 * 128,
                w2_lo + (size_t)l * 3 * 128 * 128, (size_t)128 * 128,
                conv_b2 + l * 3 * 128, 128,
                sb, 384, 128, NN, 1, stL + 256, 512, 3, G128);
        }

        // fusion MLP layer 1: BN2(3 slices) @ mlp_W1 -> mlp1out (compact 128)
        gemm_dir<1><<<G128, 256, 0, stream>>>(
            mlp1in, 0, 384, 384,
            stL + 256, 512, 0,
            conv_bn2_g + l * 3 * 128, conv_bn2_b + l * 3 * 128, 128, 0,
            mw1_hi + (size_t)l * 128 * 384, mw1_lo + (size_t)l * 128 * 384, 0,
            mlp_b1 + l * 128, 0, mlp1out, 128, 0, NN, 1, slotF1, 0, 1, G128);

        // fusion MLP layer 2: BN(mlp1out) @ mlp_W2 -> zm2
        gemm_dir<1><<<G128, 256, 0, stream>>>(
            mlp1out, 0, 128, 128,
            slotF1, 0, 0,
            mlp_bn1_g + l * 128, mlp_bn1_b + l * 128, 0, 0,
            mw2_hi + (size_t)l * 128 * 128, mw2_lo + (size_t)l * 128 * 128, 0,
            mlp_b2 + l * 128, 0, zm2, 128, 0, NN, 1, slotF2, 0, 1, G128);
    }
    // final h = bn_relu(zm2, layer-5 F2 stats) -> X (compact [NN][128])
    bn_relu_f32<<<BN_GRID, 256, 0, stream>>>(
        zm2, stats + (size_t)(5 * 8 + 7) * 256,
        mlp_bn2_g + 5 * 128, mlp_bn2_b + 5 * 128, X);

    // ---- Set2Set readout (fp32) ----
    pack_wcat<<<(512 * 384 + 255) / 256, 256, 0, stream>>>(lstm_Wih, lstm_Whh, Wcat);
    for (int t = 0; t < 6; ++t) {
        gemm_f32<true><<<dim3(8, 4), 256, 0, stream>>>(
            S, Wcat, nullptr, gates, GG, 384, 512);
        lstm_kernel<<<(GG * 128 + 255) / 256, 256, 0, stream>>>(
            gates, lstm_bih, lstm_bhh, ccb, S);
        attend_kernel<<<GG, 256, 0, stream>>>(X, S, ews, gstart);
    }
    fc1_kernel<<<GG, 128, 0, stream>>>(S, fc1_W, fc1_b, gates);
    fc4_kernel<<<(GG * 12 + 255) / 256, 256, 0, stream>>>(gates, fc4_W, fc4_b, outp);
}